// Round 1
// baseline (733.899 us; speedup 1.0000x reference)
//
#include <hip/hip_runtime.h>
#include <math.h>

#define N_PTS 2097152
// TAIL_CONST = log(exp(1-0.001)-1)
#define TAILC 0.53974324f

__device__ __forceinline__ float lrelu(float x){ return x > 0.0f ? x : 0.01f*x; }

__device__ __forceinline__ float softplus_(float x){
    // stable softplus: max(x,0) + log1p(exp(-|x|))
    return fmaxf(x, 0.0f) + log1pf(__expf(-fabsf(x)));
}

template<int OUT>
__device__ __forceinline__ void bias_init(const float* __restrict__ b, float* acc){
#pragma unroll
    for (int j=0;j<OUT;++j) acc[j] = b[j];
}

// acc[j] += s_in[ROW-local k][tid] * W[(ROW0+k)*OUT + j]
template<int KIN, int OUT, int ROW0, int NROW>
__device__ __forceinline__ void dense_from_lds(const float (*s_in)[256], int tid,
        const float* __restrict__ W, float* acc){
#pragma unroll 2
    for (int k=0;k<KIN;++k){
        float xk = s_in[k][tid];
        const float* wr = W + (ROW0 + k)*OUT;
#pragma unroll
        for (int j=0;j<OUT;++j) acc[j] = fmaf(xk, wr[j], acc[j]);
    }
    (void)0;
}

template<int KIN, int OUT>
__device__ __forceinline__ void dense_from_reg(const float* x, const float* __restrict__ W, float* acc){
#pragma unroll
    for (int k=0;k<KIN;++k){
#pragma unroll
        for (int j=0;j<OUT;++j) acc[j] = fmaf(x[k], W[k*OUT+j], acc[j]);
    }
}

// Rational-quadratic spline forward, K=20 bins, tails linear outside [-1,1].
// tp[0..19]=uw, tp[20..39]=uh, tp[40..58]=interior unnormalized derivs.
__device__ __forceinline__ void rqs(float x, const float* tp, float& yo, float& lado)
{
    float mw = tp[0];
#pragma unroll
    for (int i=1;i<20;++i) mw = fmaxf(mw, tp[i]);
    float sw = 0.f;
#pragma unroll
    for (int i=0;i<20;++i) sw += __expf(tp[i]-mw);
    float invw = 0.98f / sw;

    float mh = tp[20];
#pragma unroll
    for (int i=1;i<20;++i) mh = fmaxf(mh, tp[20+i]);
    float sh = 0.f;
#pragma unroll
    for (int i=0;i<20;++i) sh += __expf(tp[20+i]-mh);
    float invh = 0.98f / sh;

    float xc = fminf(fmaxf(x,-1.0f),1.0f);

    // walk x-knots: find bin idx (last knot <= xc), gather left knot + width
    float cum = 0.f; int idx = 0;
    float inCw = -1.0f, inW = 1.0f;
#pragma unroll
    for (int i=0;i<20;++i){
        float wv = fmaf(invw, __expf(tp[i]-mw), 0.001f);
        float cwL = (i==0) ? -1.0f : fmaf(2.0f, cum, -1.0f);
        float cumN = cum + wv;
        float cwR = (i==19) ? 1.0f : fmaf(2.0f, cumN, -1.0f);
        bool sel = (xc >= cwL);
        if (sel){ idx = i; inCw = cwL; inW = cwR - cwL; }
        cum = cumN;
    }
    // walk y-knots with known idx
    float hcum = 0.f; float inCh = -1.0f, inH = 1.0f;
#pragma unroll
    for (int i=0;i<20;++i){
        float hv = fmaf(invh, __expf(tp[20+i]-mh), 0.001f);
        float chL = (i==0) ? -1.0f : fmaf(2.0f, hcum, -1.0f);
        float hcumN = hcum + hv;
        float chR = (i==19) ? 1.0f : fmaf(2.0f, hcumN, -1.0f);
        if (i == idx){ inCh = chL; inH = chR - chL; }
        hcum = hcumN;
    }
    // derivative knots d[idx], d[idx+1]; boundary raw value = TAILC
    float udl = TAILC, udr = TAILC;
#pragma unroll
    for (int t=0;t<19;++t){
        if (idx == t+1) udl = tp[40+t];
        if (idx == t)   udr = tp[40+t];
    }
    float inD   = 0.001f + softplus_(udl);
    float inDp1 = 0.001f + softplus_(udr);
    float inDelta = inH / inW;
    float th  = (xc - inCw) / inW;
    float omt = 1.0f - th;
    float t1  = th * omt;
    float num = inH * (inDelta*th*th + inD*t1);
    float den = inDelta + (inD + inDp1 - 2.0f*inDelta)*t1;
    float y = inCh + num/den;
    float dnum = inDelta*inDelta*(inDp1*th*th + 2.0f*inDelta*t1 + inD*omt*omt);
    float lad = __logf(dnum) - 2.0f*__logf(den);
    bool inside = (x >= -1.0f) && (x <= 1.0f);
    yo   = inside ? y   : x;
    lado = inside ? lad : 0.0f;
}

__global__ __launch_bounds__(256,2) void nsf_kernel(
    const float* __restrict__ wi, const float* __restrict__ cond,
    const float* __restrict__ p0_w0, const float* __restrict__ p0_b0,
    const float* __restrict__ p0_w1, const float* __restrict__ p0_b1,
    const float* __restrict__ m1_w0, const float* __restrict__ m1_b0,
    const float* __restrict__ m1_w1, const float* __restrict__ m1_b1,
    const float* __restrict__ m1_w2, const float* __restrict__ m1_b2,
    const float* __restrict__ m0_w0, const float* __restrict__ m0_b0,
    const float* __restrict__ m0_w1, const float* __restrict__ m0_b1,
    const float* __restrict__ m0_w2, const float* __restrict__ m0_b2,
    float* __restrict__ out)
{
    // per-thread-private LDS columns (feature-major -> conflict-free, no barriers)
    __shared__ float s_ce[30][256];  // cond_e features 0..29 == W0 rows 9..38
    __shared__ float s_h[32][256];   // hidden staging
    const int tid = threadIdx.x;
    const int i = blockIdx.x*256 + tid;
    if (i >= N_PTS) return;

    float w0v = wi[2*(size_t)i];
    float w1v = wi[2*(size_t)i+1];
    const float* cp = cond + (size_t)i*10;
    float c[10];
#pragma unroll
    for (int k=0;k<10;++k) c[k] = cp[k];

    // cond_e = [c8, c9, sin/cos ladder (f=1,2,4,8,16), c0..c7]
    s_ce[0][tid] = c[8];
    s_ce[1][tid] = c[9];
    {
        float f = 1.0f;
#pragma unroll
        for (int fi=0; fi<5; ++fi){
            s_ce[2+4*fi+0][tid] = __sinf(c[8]*f);
            s_ce[2+4*fi+1][tid] = __sinf(c[9]*f);
            s_ce[2+4*fi+2][tid] = __cosf(c[8]*f);
            s_ce[2+4*fi+3][tid] = __cosf(c[9]*f);
            f *= 2.0f;
        }
    }
#pragma unroll
    for (int k=0;k<8;++k) s_ce[22+k][tid] = c[k];

    // one transform MLP: xin = [pe(t,4,linear) (9) | cond_e (30)] -> 32 -> 32 -> 59
    auto run_mlp = [&](float t, const float* __restrict__ W0, const float* __restrict__ B0,
                       const float* __restrict__ W1, const float* __restrict__ B1,
                       const float* __restrict__ W2, const float* __restrict__ B2,
                       float* tp){
        float pe9[9];
        pe9[0] = t;
        const float fr0=1.0f, fr1=3.3333333f, fr2=5.6666665f, fr3=8.0f;
        pe9[1] = __sinf(t*fr0); pe9[2] = __cosf(t*fr0);
        pe9[3] = __sinf(t*fr1); pe9[4] = __cosf(t*fr1);
        pe9[5] = __sinf(t*fr2); pe9[6] = __cosf(t*fr2);
        pe9[7] = __sinf(t*fr3); pe9[8] = __cosf(t*fr3);

        float h[32];
        bias_init<32>(B0, h);
        dense_from_reg<9,32>(pe9, W0, h);              // W0 rows 0..8
        dense_from_lds<30,32,9,30>(s_ce, tid, W0, h);  // W0 rows 9..38
#pragma unroll
        for (int j=0;j<32;++j) s_h[j][tid] = lrelu(h[j]);

        float g[32];
        bias_init<32>(B1, g);
        dense_from_lds<32,32,0,32>(s_h, tid, W1, g);
#pragma unroll
        for (int j=0;j<32;++j) s_h[j][tid] = lrelu(g[j]);

        bias_init<59>(B2, tp);
        dense_from_lds<32,59,0,32>(s_h, tid, W2, tp);
    };

    float tp[59];
    run_mlp(w1v, m1_w0, m1_b0, m1_w1, m1_b1, m1_w2, m1_b2, tp);
    float y0, ld0; rqs(w0v, tp, y0, ld0);

    run_mlp(y0, m0_w0, m0_b0, m0_w1, m0_b1, m0_w2, m0_b2, tp);
    float y1, ld1; rqs(w1v, tp, y1, ld1);

    // prior MLP p0: cond_e -> 32 (leaky) -> 4
    float ph[32];
    bias_init<32>(p0_b0, ph);
    dense_from_lds<30,32,0,30>(s_ce, tid, p0_w0, ph);
#pragma unroll
    for (int j=0;j<32;++j) s_h[j][tid] = lrelu(ph[j]);
    float r[4];
    bias_init<4>(p0_b1, r);
    dense_from_lds<32,4,0,32>(s_h, tid, p0_w1, r);

    float mu0=r[0], mu1=r[1], ls0=r[2], ls1=r[3];
    float is0 = __expf(-ls0), is1 = __expf(-ls1);
    float e0 = (y0-mu0)*is0, e1 = (y1-mu1)*is1;
    float rr = e0*e0 + e1*e1;
    // log(2*pi) = 1.8378770664093453
    float lp = -(ls0+ls1) - 1.8378770664093453f - 0.5f*rr + ld0 + ld1;

    reinterpret_cast<float2*>(out)[i] = make_float2(y0, y1);
    out[2*(size_t)N_PTS + i] = lp;
}

extern "C" void kernel_launch(void* const* d_in, const int* in_sizes, int n_in,
                              void* d_out, int out_size, void* d_ws, size_t ws_size,
                              hipStream_t stream)
{
    const float* wi    = (const float*)d_in[0];
    const float* cond  = (const float*)d_in[1];
    const float* p0_w0 = (const float*)d_in[2];
    const float* p0_b0 = (const float*)d_in[3];
    const float* p0_w1 = (const float*)d_in[4];
    const float* p0_b1 = (const float*)d_in[5];
    const float* m1_w0 = (const float*)d_in[6];
    const float* m1_b0 = (const float*)d_in[7];
    const float* m1_w1 = (const float*)d_in[8];
    const float* m1_b1 = (const float*)d_in[9];
    const float* m1_w2 = (const float*)d_in[10];
    const float* m1_b2 = (const float*)d_in[11];
    const float* m0_w0 = (const float*)d_in[12];
    const float* m0_b0 = (const float*)d_in[13];
    const float* m0_w1 = (const float*)d_in[14];
    const float* m0_b1 = (const float*)d_in[15];
    const float* m0_w2 = (const float*)d_in[16];
    const float* m0_b2 = (const float*)d_in[17];
    float* out = (float*)d_out;

    dim3 grid(N_PTS/256), block(256);
    hipLaunchKernelGGL(nsf_kernel, grid, block, 0, stream,
        wi, cond, p0_w0, p0_b0, p0_w1, p0_b1,
        m1_w0, m1_b0, m1_w1, m1_b1, m1_w2, m1_b2,
        m0_w0, m0_b0, m0_w1, m0_b1, m0_w2, m0_b2, out);
}

// Round 2
// 611.766 us; speedup vs baseline: 1.1996x; 1.1996x over previous
//
#include <hip/hip_runtime.h>
#include <math.h>

#define N_PTS 2097152
// TAIL_CONST = log(exp(1-0.001)-1)
#define TAILC 0.53974324f

__device__ __forceinline__ float lrelu(float x){ return x > 0.0f ? x : 0.01f*x; }

__device__ __forceinline__ float softplus_(float x){
    return fmaxf(x, 0.0f) + log1pf(__expf(-fabsf(x)));
}

// acc[j] += v * Wrow[j], fully unrolled (static reg indexing)
template<int OUTW>
__device__ __forceinline__ void addrow(float v, const float* __restrict__ Wrow, float* acc){
#pragma unroll
    for (int j=0;j<OUTW;++j) acc[j] = fmaf(v, Wrow[j], acc[j]);
}

// transform-MLP layer 0: xin = [pe(t,4,linear)(9) | cond_e(30)] @ W0(39x32) + B0, leaky-relu
__device__ __forceinline__ void mlp_layer0(float t, const float* c,
        const float* __restrict__ W0, const float* __restrict__ B0, float* h)
{
#pragma unroll
    for (int j=0;j<32;++j) h[j] = B0[j];
    // pe(t): t, then (sin,cos) at f = 1, 10/3, 17/3, 8   (linspace(1,8,4))
    addrow<32>(t, W0 + 0*32, h);
    float s, co;
    __sincosf(t*1.0f,       &s,&co); addrow<32>(s, W0+1*32, h); addrow<32>(co, W0+2*32, h);
    __sincosf(t*3.3333333f, &s,&co); addrow<32>(s, W0+3*32, h); addrow<32>(co, W0+4*32, h);
    __sincosf(t*5.6666665f, &s,&co); addrow<32>(s, W0+5*32, h); addrow<32>(co, W0+6*32, h);
    __sincosf(t*8.0f,       &s,&co); addrow<32>(s, W0+7*32, h); addrow<32>(co, W0+8*32, h);
    // cond_e rows 9..38: c8, c9, ladder(5 freqs x [s8,s9,c8,c9]), c0..c7
    addrow<32>(c[8], W0 + 9*32, h);
    addrow<32>(c[9], W0 +10*32, h);
    float f = 1.0f;
#pragma unroll
    for (int fi=0; fi<5; ++fi){
        float s8,c8v,s9,c9v;
        __sincosf(c[8]*f, &s8, &c8v);
        __sincosf(c[9]*f, &s9, &c9v);
        addrow<32>(s8,  W0 + (11+4*fi)*32, h);
        addrow<32>(s9,  W0 + (12+4*fi)*32, h);
        addrow<32>(c8v, W0 + (13+4*fi)*32, h);
        addrow<32>(c9v, W0 + (14+4*fi)*32, h);
        f *= 2.0f;
    }
#pragma unroll
    for (int k=0;k<8;++k) addrow<32>(c[k], W0 + (31+k)*32, h);
#pragma unroll
    for (int j=0;j<32;++j) h[j] = lrelu(h[j]);
}

template<int KIN, int OUT>
__device__ __forceinline__ void dense(const float* x, const float* __restrict__ W,
        const float* __restrict__ B, float* acc){
#pragma unroll
    for (int j=0;j<OUT;++j) acc[j] = B[j];
#pragma unroll
    for (int k=0;k<KIN;++k){
#pragma unroll
        for (int j=0;j<OUT;++j) acc[j] = fmaf(x[k], W[k*OUT+j], acc[j]);
    }
}

// Rational-quadratic spline, K=20. tp is clobbered (softmax exps stored in place).
__device__ __forceinline__ void rqs(float x, float* tp, float& yo, float& lado)
{
    float mw = tp[0];
#pragma unroll
    for (int i=1;i<20;++i) mw = fmaxf(mw, tp[i]);
    float sw = 0.f;
#pragma unroll
    for (int i=0;i<20;++i){ tp[i] = __expf(tp[i]-mw); sw += tp[i]; }
    float invw = 0.98f / sw;

    float mh = tp[20];
#pragma unroll
    for (int i=1;i<20;++i) mh = fmaxf(mh, tp[20+i]);
    float sh = 0.f;
#pragma unroll
    for (int i=0;i<20;++i){ tp[20+i] = __expf(tp[20+i]-mh); sh += tp[20+i]; }
    float invh = 0.98f / sh;

    float xc = fminf(fmaxf(x,-1.0f),1.0f);

    // walk x-knots: bin idx = last knot <= xc; gather left knot + width
    float cum = 0.f; int idx = 0;
    float inCw = -1.0f, inW = 1.0f;
#pragma unroll
    for (int i=0;i<20;++i){
        float wv = fmaf(invw, tp[i], 0.001f);
        float cwL = (i==0) ? -1.0f : fmaf(2.0f, cum, -1.0f);
        float cumN = cum + wv;
        float cwR = (i==19) ? 1.0f : fmaf(2.0f, cumN, -1.0f);
        if (xc >= cwL){ idx = i; inCw = cwL; inW = cwR - cwL; }
        cum = cumN;
    }
    // walk y-knots with known idx
    float hcum = 0.f; float inCh = -1.0f, inH = 1.0f;
#pragma unroll
    for (int i=0;i<20;++i){
        float hv = fmaf(invh, tp[20+i], 0.001f);
        float chL = (i==0) ? -1.0f : fmaf(2.0f, hcum, -1.0f);
        float hcumN = hcum + hv;
        float chR = (i==19) ? 1.0f : fmaf(2.0f, hcumN, -1.0f);
        if (i == idx){ inCh = chL; inH = chR - chL; }
        hcum = hcumN;
    }
    float udl = TAILC, udr = TAILC;
#pragma unroll
    for (int t=0;t<19;++t){
        if (idx == t+1) udl = tp[40+t];
        if (idx == t)   udr = tp[40+t];
    }
    float inD   = 0.001f + softplus_(udl);
    float inDp1 = 0.001f + softplus_(udr);
    float inDelta = inH / inW;
    float th  = (xc - inCw) / inW;
    float omt = 1.0f - th;
    float t1  = th * omt;
    float num = inH * (inDelta*th*th + inD*t1);
    float den = inDelta + (inD + inDp1 - 2.0f*inDelta)*t1;
    float y = inCh + num/den;
    float dnum = inDelta*inDelta*(inDp1*th*th + 2.0f*inDelta*t1 + inD*omt*omt);
    float lad = __logf(dnum) - 2.0f*__logf(den);
    bool inside = (x >= -1.0f) && (x <= 1.0f);
    yo   = inside ? y   : x;
    lado = inside ? lad : 0.0f;
}

__global__ __launch_bounds__(256,3) void nsf_kernel(
    const float* __restrict__ wi, const float* __restrict__ cond,
    const float* __restrict__ p0_w0, const float* __restrict__ p0_b0,
    const float* __restrict__ p0_w1, const float* __restrict__ p0_b1,
    const float* __restrict__ m1_w0, const float* __restrict__ m1_b0,
    const float* __restrict__ m1_w1, const float* __restrict__ m1_b1,
    const float* __restrict__ m1_w2, const float* __restrict__ m1_b2,
    const float* __restrict__ m0_w0, const float* __restrict__ m0_b0,
    const float* __restrict__ m0_w1, const float* __restrict__ m0_b1,
    const float* __restrict__ m0_w2, const float* __restrict__ m0_b2,
    float* __restrict__ out)
{
    const int i = blockIdx.x*256 + threadIdx.x;

    float2 wv2 = reinterpret_cast<const float2*>(wi)[i];
    float w0v = wv2.x, w1v = wv2.y;
    const float* cp = cond + (size_t)i*10;
    float c[10];
#pragma unroll
    for (int k=0;k<10;++k) c[k] = cp[k];

    // ---- transform MLP m1 (conditions on w1) -> spline on w0 ----
    float tp[59];
    {
        float h[32], g[32];
        mlp_layer0(w1v, c, m1_w0, m1_b0, h);
        dense<32,32>(h, m1_w1, m1_b1, g);
#pragma unroll
        for (int j=0;j<32;++j) g[j] = lrelu(g[j]);
        dense<32,59>(g, m1_w2, m1_b2, tp);
    }
    float y0, ld0; rqs(w0v, tp, y0, ld0);

    // ---- transform MLP m0 (conditions on y0) -> spline on w1 ----
    {
        float h[32], g[32];
        mlp_layer0(y0, c, m0_w0, m0_b0, h);
        dense<32,32>(h, m0_w1, m0_b1, g);
#pragma unroll
        for (int j=0;j<32;++j) g[j] = lrelu(g[j]);
        dense<32,59>(g, m0_w2, m0_b2, tp);
    }
    float y1, ld1; rqs(w1v, tp, y1, ld1);

    // ---- prior MLP p0: cond_e(30) -> 32 (leaky) -> 4 ----
    float r[4];
    {
        float ph[32];
#pragma unroll
        for (int j=0;j<32;++j) ph[j] = p0_b0[j];
        addrow<32>(c[8], p0_w0 + 0*32, ph);
        addrow<32>(c[9], p0_w0 + 1*32, ph);
        float f = 1.0f;
#pragma unroll
        for (int fi=0; fi<5; ++fi){
            float s8,c8v,s9,c9v;
            __sincosf(c[8]*f, &s8, &c8v);
            __sincosf(c[9]*f, &s9, &c9v);
            addrow<32>(s8,  p0_w0 + (2+4*fi)*32, ph);
            addrow<32>(s9,  p0_w0 + (3+4*fi)*32, ph);
            addrow<32>(c8v, p0_w0 + (4+4*fi)*32, ph);
            addrow<32>(c9v, p0_w0 + (5+4*fi)*32, ph);
            f *= 2.0f;
        }
#pragma unroll
        for (int k=0;k<8;++k) addrow<32>(c[k], p0_w0 + (22+k)*32, ph);
#pragma unroll
        for (int j=0;j<32;++j) ph[j] = lrelu(ph[j]);
        dense<32,4>(ph, p0_w1, p0_b1, r);
    }

    float mu0=r[0], mu1=r[1], ls0=r[2], ls1=r[3];
    float is0 = __expf(-ls0), is1 = __expf(-ls1);
    float e0 = (y0-mu0)*is0, e1 = (y1-mu1)*is1;
    float rr = e0*e0 + e1*e1;
    float lp = -(ls0+ls1) - 1.8378770664093453f - 0.5f*rr + ld0 + ld1;

    reinterpret_cast<float2*>(out)[i] = make_float2(y0, y1);
    out[2*(size_t)N_PTS + i] = lp;
}

extern "C" void kernel_launch(void* const* d_in, const int* in_sizes, int n_in,
                              void* d_out, int out_size, void* d_ws, size_t ws_size,
                              hipStream_t stream)
{
    const float* wi    = (const float*)d_in[0];
    const float* cond  = (const float*)d_in[1];
    const float* p0_w0 = (const float*)d_in[2];
    const float* p0_b0 = (const float*)d_in[3];
    const float* p0_w1 = (const float*)d_in[4];
    const float* p0_b1 = (const float*)d_in[5];
    const float* m1_w0 = (const float*)d_in[6];
    const float* m1_b0 = (const float*)d_in[7];
    const float* m1_w1 = (const float*)d_in[8];
    const float* m1_b1 = (const float*)d_in[9];
    const float* m1_w2 = (const float*)d_in[10];
    const float* m1_b2 = (const float*)d_in[11];
    const float* m0_w0 = (const float*)d_in[12];
    const float* m0_b0 = (const float*)d_in[13];
    const float* m0_w1 = (const float*)d_in[14];
    const float* m0_b1 = (const float*)d_in[15];
    const float* m0_w2 = (const float*)d_in[16];
    const float* m0_b2 = (const float*)d_in[17];
    float* out = (float*)d_out;

    dim3 grid(N_PTS/256), block(256);
    hipLaunchKernelGGL(nsf_kernel, grid, block, 0, stream,
        wi, cond, p0_w0, p0_b0, p0_w1, p0_b1,
        m1_w0, m1_b0, m1_w1, m1_b1, m1_w2, m1_b2,
        m0_w0, m0_b0, m0_w1, m0_b1, m0_w2, m0_b2, out);
}

// Round 3
// 461.631 us; speedup vs baseline: 1.5898x; 1.3252x over previous
//
#include <hip/hip_runtime.h>
#include <math.h>

#define N_PTS 2097152
#define TAILC 0.53974324f   // log(exp(1-0.001)-1)

typedef unsigned int u32;
typedef _Float16 h2 __attribute__((ext_vector_type(2)));

__device__ __forceinline__ float lrelu(float x){ return x > 0.0f ? x : 0.01f*x; }
__device__ __forceinline__ float softplus_(float x){
    return fmaxf(x, 0.0f) + log1pf(__expf(-fabsf(x)));
}
__device__ __forceinline__ h2 u2h2(u32 u){ union{u32 a; h2 b;} x; x.a=u; return x.b; }
__device__ __forceinline__ h2 mkh2(float a, float b){ h2 v; v.x=(_Float16)a; v.y=(_Float16)b; return v; }

__device__ __forceinline__ float fdot2(h2 a, h2 b, float c){
#if __has_builtin(__builtin_amdgcn_fdot2)
    return __builtin_amdgcn_fdot2(a, b, c, false);
#else
    return fmaf((float)a.x,(float)b.x, fmaf((float)a.y,(float)b.y, c));
#endif
}

// acc[OUT] = B + sum_k2 dot2(xp[k2], Wp[k2*OUT+j])
template<int K2, int OUT>
__device__ __forceinline__ void dense2(const h2* xp, const u32* __restrict__ Wp,
        const float* __restrict__ B, float* acc){
#pragma unroll
    for (int j=0;j<OUT;++j) acc[j] = B[j];
#pragma unroll
    for (int k2=0;k2<K2;++k2){
        h2 x = xp[k2];
#pragma unroll
        for (int j=0;j<OUT;++j) acc[j] = fdot2(x, u2h2(Wp[k2*OUT+j]), acc[j]);
    }
}

// Rational-quadratic spline, K=20. tp clobbered (softmax exps in place).
__device__ __forceinline__ void rqs(float x, float* tp, float& yo, float& lado)
{
    float mw = tp[0];
#pragma unroll
    for (int i=1;i<20;++i) mw = fmaxf(mw, tp[i]);
    float sw = 0.f;
#pragma unroll
    for (int i=0;i<20;++i){ tp[i] = __expf(tp[i]-mw); sw += tp[i]; }
    float invw = 0.98f / sw;

    float mh = tp[20];
#pragma unroll
    for (int i=1;i<20;++i) mh = fmaxf(mh, tp[20+i]);
    float sh = 0.f;
#pragma unroll
    for (int i=0;i<20;++i){ tp[20+i] = __expf(tp[20+i]-mh); sh += tp[20+i]; }
    float invh = 0.98f / sh;

    float xc = fminf(fmaxf(x,-1.0f),1.0f);

    float cum = 0.f; int idx = 0;
    float inCw = -1.0f, inW = 1.0f;
#pragma unroll
    for (int i=0;i<20;++i){
        float wv = fmaf(invw, tp[i], 0.001f);
        float cwL = (i==0) ? -1.0f : fmaf(2.0f, cum, -1.0f);
        float cumN = cum + wv;
        float cwR = (i==19) ? 1.0f : fmaf(2.0f, cumN, -1.0f);
        if (xc >= cwL){ idx = i; inCw = cwL; inW = cwR - cwL; }
        cum = cumN;
    }
    float hcum = 0.f; float inCh = -1.0f, inH = 1.0f;
#pragma unroll
    for (int i=0;i<20;++i){
        float hv = fmaf(invh, tp[20+i], 0.001f);
        float chL = (i==0) ? -1.0f : fmaf(2.0f, hcum, -1.0f);
        float hcumN = hcum + hv;
        float chR = (i==19) ? 1.0f : fmaf(2.0f, hcumN, -1.0f);
        if (i == idx){ inCh = chL; inH = chR - chL; }
        hcum = hcumN;
    }
    float udl = TAILC, udr = TAILC;
#pragma unroll
    for (int t=0;t<19;++t){
        if (idx == t+1) udl = tp[40+t];
        if (idx == t)   udr = tp[40+t];
    }
    float inD   = 0.001f + softplus_(udl);
    float inDp1 = 0.001f + softplus_(udr);
    float inDelta = inH / inW;
    float th  = (xc - inCw) / inW;
    float omt = 1.0f - th;
    float t1  = th * omt;
    float num = inH * (inDelta*th*th + inD*t1);
    float den = inDelta + (inD + inDp1 - 2.0f*inDelta)*t1;
    float y = inCh + num/den;
    float dnum = inDelta*inDelta*(inDp1*th*th + 2.0f*inDelta*t1 + inD*omt*omt);
    float lad = __logf(dnum) - 2.0f*__logf(den);
    bool inside = (x >= -1.0f) && (x <= 1.0f);
    yo   = inside ? y   : x;
    lado = inside ? lad : 0.0f;
}

// ---- packed-weight layout in d_ws (u32 units) ----
// m1: L0 [20][32]@0  L1 [16][32]@640  L2 [16][59]@1152
// m0: L0 @2096       L1 @2736        L2 @3248
// p0: L0 [15][32]@4192  L1 [16][4]@4672   total 4736 u32
#define WS_U32 4736

__device__ __forceinline__ void pack_seg(const float* __restrict__ W, int K, int OUT,
                                         u32* __restrict__ dst, int idx){
    int k2 = idx / OUT, j = idx - k2*OUT;
    float lo = W[(2*k2)*OUT + j];
    float hi = (2*k2+1 < K) ? W[(2*k2+1)*OUT + j] : 0.0f;
    union{ _Float16 h; unsigned short s; } a, b;
    a.h = (_Float16)lo; b.h = (_Float16)hi;
    dst[idx] = (u32)a.s | ((u32)b.s << 16);
}

__global__ void pack_weights(const float* __restrict__ m1_w0, const float* __restrict__ m1_w1,
                             const float* __restrict__ m1_w2, const float* __restrict__ m0_w0,
                             const float* __restrict__ m0_w1, const float* __restrict__ m0_w2,
                             const float* __restrict__ p0_w0, const float* __restrict__ p0_w1,
                             u32* __restrict__ ws)
{
    int idx = blockIdx.x*256 + threadIdx.x;
    if (idx >= WS_U32) return;
    if      (idx < 640)  pack_seg(m1_w0, 39, 32, ws + 0,    idx - 0);
    else if (idx < 1152) pack_seg(m1_w1, 32, 32, ws + 640,  idx - 640);
    else if (idx < 2096) pack_seg(m1_w2, 32, 59, ws + 1152, idx - 1152);
    else if (idx < 2736) pack_seg(m0_w0, 39, 32, ws + 2096, idx - 2096);
    else if (idx < 3248) pack_seg(m0_w1, 32, 32, ws + 2736, idx - 2736);
    else if (idx < 4192) pack_seg(m0_w2, 32, 59, ws + 3248, idx - 3248);
    else if (idx < 4672) pack_seg(p0_w0, 30, 32, ws + 4192, idx - 4192);
    else                 pack_seg(p0_w1, 32, 4,  ws + 4672, idx - 4672);
}

// ---------------- main kernel (dot2 path) ----------------
__global__ __launch_bounds__(256,3) void nsf_kernel_dot2(
    const float* __restrict__ wi, const float* __restrict__ cond,
    const u32*  __restrict__ wsp,
    const float* __restrict__ p0_b0, const float* __restrict__ p0_b1,
    const float* __restrict__ m1_b0, const float* __restrict__ m1_b1, const float* __restrict__ m1_b2,
    const float* __restrict__ m0_b0, const float* __restrict__ m0_b1, const float* __restrict__ m0_b2,
    float* __restrict__ out)
{
    const int i = blockIdx.x*256 + threadIdx.x;

    float2 wv2 = reinterpret_cast<const float2*>(wi)[i];
    float w0v = wv2.x, w1v = wv2.y;
    const float* cp = cond + (size_t)i*10;
    float c[10];
#pragma unroll
    for (int k=0;k<10;++k) c[k] = cp[k];

    // cond_e (f32) -> f16, both pairings
    _Float16 ceh[30];
    ceh[0] = (_Float16)c[8];
    ceh[1] = (_Float16)c[9];
    {
        float f = 1.0f;
#pragma unroll
        for (int fi=0; fi<5; ++fi){
            float s8,c8v,s9,c9v;
            __sincosf(c[8]*f, &s8, &c8v);
            __sincosf(c[9]*f, &s9, &c9v);
            ceh[2+4*fi+0]=(_Float16)s8;  ceh[2+4*fi+1]=(_Float16)s9;
            ceh[2+4*fi+2]=(_Float16)c8v; ceh[2+4*fi+3]=(_Float16)c9v;
            f *= 2.0f;
        }
    }
#pragma unroll
    for (int k=0;k<8;++k) ceh[22+k] = (_Float16)c[k];

    h2 cep_m[15];   // xin pairs (ce1,ce2),(ce3,ce4)...(ce27,ce28),(ce29,0)
#pragma unroll
    for (int m=0;m<14;++m){ h2 v; v.x=ceh[1+2*m]; v.y=ceh[2+2*m]; cep_m[m]=v; }
    { h2 v; v.x=ceh[29]; v.y=(_Float16)0.f; cep_m[14]=v; }
    h2 cep_p[15];   // p0 pairs (ce0,ce1)...(ce28,ce29)
#pragma unroll
    for (int m=0;m<15;++m){ h2 v; v.x=ceh[2*m]; v.y=ceh[2*m+1]; cep_p[m]=v; }

    // one transform MLP via dot2
    auto run_mlp = [&](float t, const u32* W0p, const float* B0,
                       const u32* W1p, const float* B1,
                       const u32* W2p, const float* B2, float* tp){
        float s1,c1v,s2,c2v,s3,c3v,s4,c4v;
        __sincosf(t*1.0f,       &s1,&c1v);
        __sincosf(t*3.3333333f, &s2,&c2v);
        __sincosf(t*5.6666665f, &s3,&c3v);
        __sincosf(t*8.0f,       &s4,&c4v);
        h2 xp[20];
        xp[0]=mkh2(t, s1); xp[1]=mkh2(c1v, s2); xp[2]=mkh2(c2v, s3); xp[3]=mkh2(c3v, s4);
        { h2 v; v.x=(_Float16)c4v; v.y=ceh[0]; xp[4]=v; }
#pragma unroll
        for (int m=0;m<15;++m) xp[5+m] = cep_m[m];

        float h[32];
        dense2<20,32>(xp, W0p, B0, h);
        h2 hp[16];
#pragma unroll
        for (int k2=0;k2<16;++k2) hp[k2] = mkh2(lrelu(h[2*k2]), lrelu(h[2*k2+1]));
        float g[32];
        dense2<16,32>(hp, W1p, B1, g);
#pragma unroll
        for (int k2=0;k2<16;++k2) hp[k2] = mkh2(lrelu(g[2*k2]), lrelu(g[2*k2+1]));
        dense2<16,59>(hp, W2p, B2, tp);
    };

    float tp[59];
    run_mlp(w1v, wsp+0,    m1_b0, wsp+640,  m1_b1, wsp+1152, m1_b2, tp);
    float y0, ld0; rqs(w0v, tp, y0, ld0);

    run_mlp(y0,  wsp+2096, m0_b0, wsp+2736, m0_b1, wsp+3248, m0_b2, tp);
    float y1, ld1; rqs(w1v, tp, y1, ld1);

    // prior MLP p0: cond_e(30) -> 32 (leaky) -> 4
    float r[4];
    {
        float ph[32];
        dense2<15,32>(cep_p, wsp+4192, p0_b0, ph);
        h2 pp[16];
#pragma unroll
        for (int k2=0;k2<16;++k2) pp[k2] = mkh2(lrelu(ph[2*k2]), lrelu(ph[2*k2+1]));
        dense2<16,4>(pp, wsp+4672, p0_b1, r);
    }

    float mu0=r[0], mu1=r[1], ls0=r[2], ls1=r[3];
    float is0 = __expf(-ls0), is1 = __expf(-ls1);
    float e0 = (y0-mu0)*is0, e1 = (y1-mu1)*is1;
    float rr = e0*e0 + e1*e1;
    float lp = -(ls0+ls1) - 1.8378770664093453f - 0.5f*rr + ld0 + ld1;

    reinterpret_cast<float2*>(out)[i] = make_float2(y0, y1);
    out[2*(size_t)N_PTS + i] = lp;
}

// ---------------- fallback all-f32 kernel (R1, known-good) ----------------
template<int OUTW>
__device__ __forceinline__ void addrow(float v, const float* __restrict__ Wrow, float* acc){
#pragma unroll
    for (int j=0;j<OUTW;++j) acc[j] = fmaf(v, Wrow[j], acc[j]);
}
template<int KIN, int OUT>
__device__ __forceinline__ void dense(const float* x, const float* __restrict__ W,
        const float* __restrict__ B, float* acc){
#pragma unroll
    for (int j=0;j<OUT;++j) acc[j] = B[j];
#pragma unroll
    for (int k=0;k<KIN;++k){
#pragma unroll
        for (int j=0;j<OUT;++j) acc[j] = fmaf(x[k], W[k*OUT+j], acc[j]);
    }
}
__device__ __forceinline__ void mlp_layer0(float t, const float* c,
        const float* __restrict__ W0, const float* __restrict__ B0, float* h)
{
#pragma unroll
    for (int j=0;j<32;++j) h[j] = B0[j];
    addrow<32>(t, W0 + 0*32, h);
    float s, co;
    __sincosf(t*1.0f,       &s,&co); addrow<32>(s, W0+1*32, h); addrow<32>(co, W0+2*32, h);
    __sincosf(t*3.3333333f, &s,&co); addrow<32>(s, W0+3*32, h); addrow<32>(co, W0+4*32, h);
    __sincosf(t*5.6666665f, &s,&co); addrow<32>(s, W0+5*32, h); addrow<32>(co, W0+6*32, h);
    __sincosf(t*8.0f,       &s,&co); addrow<32>(s, W0+7*32, h); addrow<32>(co, W0+8*32, h);
    addrow<32>(c[8], W0 + 9*32, h);
    addrow<32>(c[9], W0 +10*32, h);
    float f = 1.0f;
#pragma unroll
    for (int fi=0; fi<5; ++fi){
        float s8,c8v,s9,c9v;
        __sincosf(c[8]*f, &s8, &c8v);
        __sincosf(c[9]*f, &s9, &c9v);
        addrow<32>(s8,  W0 + (11+4*fi)*32, h);
        addrow<32>(s9,  W0 + (12+4*fi)*32, h);
        addrow<32>(c8v, W0 + (13+4*fi)*32, h);
        addrow<32>(c9v, W0 + (14+4*fi)*32, h);
        f *= 2.0f;
    }
#pragma unroll
    for (int k=0;k<8;++k) addrow<32>(c[k], W0 + (31+k)*32, h);
#pragma unroll
    for (int j=0;j<32;++j) h[j] = lrelu(h[j]);
}
__global__ __launch_bounds__(256,3) void nsf_kernel_f32(
    const float* __restrict__ wi, const float* __restrict__ cond,
    const float* __restrict__ p0_w0, const float* __restrict__ p0_b0,
    const float* __restrict__ p0_w1, const float* __restrict__ p0_b1,
    const float* __restrict__ m1_w0, const float* __restrict__ m1_b0,
    const float* __restrict__ m1_w1, const float* __restrict__ m1_b1,
    const float* __restrict__ m1_w2, const float* __restrict__ m1_b2,
    const float* __restrict__ m0_w0, const float* __restrict__ m0_b0,
    const float* __restrict__ m0_w1, const float* __restrict__ m0_b1,
    const float* __restrict__ m0_w2, const float* __restrict__ m0_b2,
    float* __restrict__ out)
{
    const int i = blockIdx.x*256 + threadIdx.x;
    float2 wv2 = reinterpret_cast<const float2*>(wi)[i];
    float w0v = wv2.x, w1v = wv2.y;
    const float* cp = cond + (size_t)i*10;
    float c[10];
#pragma unroll
    for (int k=0;k<10;++k) c[k] = cp[k];

    float tp[59];
    {
        float h[32], g[32];
        mlp_layer0(w1v, c, m1_w0, m1_b0, h);
        dense<32,32>(h, m1_w1, m1_b1, g);
#pragma unroll
        for (int j=0;j<32;++j) g[j] = lrelu(g[j]);
        dense<32,59>(g, m1_w2, m1_b2, tp);
    }
    float y0, ld0; rqs(w0v, tp, y0, ld0);
    {
        float h[32], g[32];
        mlp_layer0(y0, c, m0_w0, m0_b0, h);
        dense<32,32>(h, m0_w1, m0_b1, g);
#pragma unroll
        for (int j=0;j<32;++j) g[j] = lrelu(g[j]);
        dense<32,59>(g, m0_w2, m0_b2, tp);
    }
    float y1, ld1; rqs(w1v, tp, y1, ld1);

    float r[4];
    {
        float ph[32];
#pragma unroll
        for (int j=0;j<32;++j) ph[j] = p0_b0[j];
        addrow<32>(c[8], p0_w0 + 0*32, ph);
        addrow<32>(c[9], p0_w0 + 1*32, ph);
        float f = 1.0f;
#pragma unroll
        for (int fi=0; fi<5; ++fi){
            float s8,c8v,s9,c9v;
            __sincosf(c[8]*f, &s8, &c8v);
            __sincosf(c[9]*f, &s9, &c9v);
            addrow<32>(s8,  p0_w0 + (2+4*fi)*32, ph);
            addrow<32>(s9,  p0_w0 + (3+4*fi)*32, ph);
            addrow<32>(c8v, p0_w0 + (4+4*fi)*32, ph);
            addrow<32>(c9v, p0_w0 + (5+4*fi)*32, ph);
            f *= 2.0f;
        }
#pragma unroll
        for (int k=0;k<8;++k) addrow<32>(c[k], p0_w0 + (22+k)*32, ph);
#pragma unroll
        for (int j=0;j<32;++j) ph[j] = lrelu(ph[j]);
        dense<32,4>(ph, p0_w1, p0_b1, r);
    }

    float mu0=r[0], mu1=r[1], ls0=r[2], ls1=r[3];
    float is0 = __expf(-ls0), is1 = __expf(-ls1);
    float e0 = (y0-mu0)*is0, e1 = (y1-mu1)*is1;
    float rr = e0*e0 + e1*e1;
    float lp = -(ls0+ls1) - 1.8378770664093453f - 0.5f*rr + ld0 + ld1;

    reinterpret_cast<float2*>(out)[i] = make_float2(y0, y1);
    out[2*(size_t)N_PTS + i] = lp;
}

extern "C" void kernel_launch(void* const* d_in, const int* in_sizes, int n_in,
                              void* d_out, int out_size, void* d_ws, size_t ws_size,
                              hipStream_t stream)
{
    const float* wi    = (const float*)d_in[0];
    const float* cond  = (const float*)d_in[1];
    const float* p0_w0 = (const float*)d_in[2];
    const float* p0_b0 = (const float*)d_in[3];
    const float* p0_w1 = (const float*)d_in[4];
    const float* p0_b1 = (const float*)d_in[5];
    const float* m1_w0 = (const float*)d_in[6];
    const float* m1_b0 = (const float*)d_in[7];
    const float* m1_w1 = (const float*)d_in[8];
    const float* m1_b1 = (const float*)d_in[9];
    const float* m1_w2 = (const float*)d_in[10];
    const float* m1_b2 = (const float*)d_in[11];
    const float* m0_w0 = (const float*)d_in[12];
    const float* m0_b0 = (const float*)d_in[13];
    const float* m0_w1 = (const float*)d_in[14];
    const float* m0_b1 = (const float*)d_in[15];
    const float* m0_w2 = (const float*)d_in[16];
    const float* m0_b2 = (const float*)d_in[17];
    float* out = (float*)d_out;

    dim3 grid(N_PTS/256), block(256);
    if (ws_size >= (size_t)WS_U32*4) {
        u32* wsp = (u32*)d_ws;
        hipLaunchKernelGGL(pack_weights, dim3((WS_U32+255)/256), block, 0, stream,
            m1_w0, m1_w1, m1_w2, m0_w0, m0_w1, m0_w2, p0_w0, p0_w1, wsp);
        hipLaunchKernelGGL(nsf_kernel_dot2, grid, block, 0, stream,
            wi, cond, wsp, p0_b0, p0_b1, m1_b0, m1_b1, m1_b2, m0_b0, m0_b1, m0_b2, out);
    } else {
        hipLaunchKernelGGL(nsf_kernel_f32, grid, block, 0, stream,
            wi, cond, p0_w0, p0_b0, p0_w1, p0_b1,
            m1_w0, m1_b0, m1_w1, m1_b1, m1_w2, m1_b2,
            m0_w0, m0_b0, m0_w1, m0_b1, m0_w2, m0_b2, out);
    }
}

// Round 4
// 443.271 us; speedup vs baseline: 1.6556x; 1.0414x over previous
//
#include <hip/hip_runtime.h>
#include <math.h>

#define N_PTS 2097152
#define TAILC 0.53974324f   // log(exp(1-0.001)-1)

typedef unsigned int u32;
typedef _Float16 half8 __attribute__((ext_vector_type(8)));
typedef float float4v __attribute__((ext_vector_type(4)));

__device__ __forceinline__ float lrelu(float x){ return x > 0.0f ? x : 0.01f*x; }
__device__ __forceinline__ float softplus_(float x){
    return fmaxf(x, 0.0f) + log1pf(__expf(-fabsf(x)));
}

// ---------------- rational-quadratic spline (per-thread, f32) ----------------
__device__ __forceinline__ void rqs(float x, float* tp, float& yo, float& lado)
{
    float mw = tp[0];
#pragma unroll
    for (int i=1;i<20;++i) mw = fmaxf(mw, tp[i]);
    float sw = 0.f;
#pragma unroll
    for (int i=0;i<20;++i){ tp[i] = __expf(tp[i]-mw); sw += tp[i]; }
    float invw = 0.98f / sw;

    float mh = tp[20];
#pragma unroll
    for (int i=1;i<20;++i) mh = fmaxf(mh, tp[20+i]);
    float sh = 0.f;
#pragma unroll
    for (int i=0;i<20;++i){ tp[20+i] = __expf(tp[20+i]-mh); sh += tp[20+i]; }
    float invh = 0.98f / sh;

    float xc = fminf(fmaxf(x,-1.0f),1.0f);

    float cum = 0.f; int idx = 0;
    float inCw = -1.0f, inW = 1.0f;
#pragma unroll
    for (int i=0;i<20;++i){
        float wv = fmaf(invw, tp[i], 0.001f);
        float cwL = (i==0) ? -1.0f : fmaf(2.0f, cum, -1.0f);
        float cumN = cum + wv;
        float cwR = (i==19) ? 1.0f : fmaf(2.0f, cumN, -1.0f);
        if (xc >= cwL){ idx = i; inCw = cwL; inW = cwR - cwL; }
        cum = cumN;
    }
    float hcum = 0.f; float inCh = -1.0f, inH = 1.0f;
#pragma unroll
    for (int i=0;i<20;++i){
        float hv = fmaf(invh, tp[20+i], 0.001f);
        float chL = (i==0) ? -1.0f : fmaf(2.0f, hcum, -1.0f);
        float hcumN = hcum + hv;
        float chR = (i==19) ? 1.0f : fmaf(2.0f, hcumN, -1.0f);
        if (i == idx){ inCh = chL; inH = chR - chL; }
        hcum = hcumN;
    }
    float udl = TAILC, udr = TAILC;
#pragma unroll
    for (int t=0;t<19;++t){
        if (idx == t+1) udl = tp[40+t];
        if (idx == t)   udr = tp[40+t];
    }
    float inD   = 0.001f + softplus_(udl);
    float inDp1 = 0.001f + softplus_(udr);
    float inDelta = inH / inW;
    float th  = (xc - inCw) / inW;
    float omt = 1.0f - th;
    float t1  = th * omt;
    float num = inH * (inDelta*th*th + inD*t1);
    float den = inDelta + (inD + inDp1 - 2.0f*inDelta)*t1;
    float y = inCh + num/den;
    float dnum = inDelta*inDelta*(inDp1*th*th + 2.0f*inDelta*t1 + inD*omt*omt);
    float lad = __logf(dnum) - 2.0f*__logf(den);
    bool inside = (x >= -1.0f) && (x <= 1.0f);
    yo   = inside ? y   : x;
    lado = inside ? lad : 0.0f;
}

// ---- packed transposed f16 weights in d_ws ----
// WT[out][K] zero-padded; A-col mapping: cols 0..29 = cond_e, 30..31 = 0,
// cols 32..40 = PE(t), 41..63 = 0.
#define OFF_M1_W0T 0        // [32][64]
#define OFF_M1_W1T 2048     // [32][32]
#define OFF_M1_W2T 3072     // [64][32]
#define OFF_M0_W0T 5120
#define OFF_M0_W1T 7168
#define OFF_M0_W2T 8192
#define OFF_P0_W0T 10240    // [32][32]
#define WS_F16     11264

__global__ void pack_weights(const float* __restrict__ m1_w0, const float* __restrict__ m1_w1,
                             const float* __restrict__ m1_w2, const float* __restrict__ m0_w0,
                             const float* __restrict__ m0_w1, const float* __restrict__ m0_w2,
                             const float* __restrict__ p0_w0, _Float16* __restrict__ ws)
{
    int idx = blockIdx.x*256 + threadIdx.x;
    if (idx >= WS_F16) return;
    float v = 0.0f;
    if (idx < 2048 || (idx >= 5120 && idx < 7168)) {          // W0T [32][64]
        const float* W = (idx < 2048) ? m1_w0 : m0_w0;
        int r = (idx < 2048) ? idx : idx - 5120;
        int o = r >> 6, k = r & 63;
        if (k < 30)                 v = W[(9+k)*32 + o];
        else if (k >= 32 && k < 41) v = W[(k-32)*32 + o];
    } else if (idx < 3072 || (idx >= 7168 && idx < 8192)) {   // W1T [32][32]
        const float* W = (idx < 3072) ? m1_w1 : m0_w1;
        int r = (idx < 3072) ? idx - 2048 : idx - 7168;
        int o = r >> 5, k = r & 31;
        v = W[k*32 + o];
    } else if (idx < 5120 || (idx >= 8192 && idx < 10240)) {  // W2T [64][32]
        const float* W = (idx < 5120) ? m1_w2 : m0_w2;
        int r = (idx < 5120) ? idx - 3072 : idx - 8192;
        int o = r >> 5, k = r & 31;
        if (o < 59) v = W[k*59 + o];
    } else {                                                  // p0 W0T [32][32]
        int r = idx - 10240;
        int o = r >> 5, k = r & 31;
        if (k < 30) v = p0_w0[k*32 + o];
    }
    ws[idx] = (_Float16)v;
}

// one transform MLP: A-buf (xin) already staged; leaves tp[59] in regs
__device__ __forceinline__ void mfma_mlp(_Float16* Sw, int l,
    const _Float16* __restrict__ wsp, int offW0, int offW1, int offW2,
    const float* __restrict__ B0, const float* __restrict__ B1,
    const float* __restrict__ B2, float* tp)
{
    const int mrow = l & 15, g = l >> 4;
    // ---- L0: K=64 (2 ksteps), N=32 ----
    half8 a[4][2], b[2][2];
#pragma unroll
    for (int t=0;t<4;++t){
        int r = 16*t + mrow;
#pragma unroll
        for (int s=0;s<2;++s)
            a[t][s] = *(const half8*)(Sw + r*64 + (((4*s+g) ^ (r&7))<<3));
    }
#pragma unroll
    for (int n=0;n<2;++n)
#pragma unroll
        for (int s=0;s<2;++s)
            b[n][s] = *(const half8*)(wsp + offW0 + (16*n+mrow)*64 + 32*s + 8*g);
    float bv0 = B0[mrow], bv1 = B0[16+mrow];
#pragma unroll
    for (int n=0;n<2;++n){
        float bb = n ? bv1 : bv0;
        int cc = 16*n + mrow;
#pragma unroll
        for (int t=0;t<4;++t){
            float4v acc = {bb,bb,bb,bb};
            acc = __builtin_amdgcn_mfma_f32_16x16x32_f16(a[t][0], b[n][0], acc, 0,0,0);
            acc = __builtin_amdgcn_mfma_f32_16x16x32_f16(a[t][1], b[n][1], acc, 0,0,0);
#pragma unroll
            for (int j=0;j<4;++j){
                int r = 16*t + 4*g + j;
                Sw[r*64 + (((cc>>3) ^ (r&7))<<3) + (cc&7)] = (_Float16)lrelu(acc[j]);
            }
        }
    }
    __threadfence_block();
    // ---- L1: K=32, N=32 ----
    half8 a1[4], b1f[2];
#pragma unroll
    for (int t=0;t<4;++t){ int r = 16*t + mrow; a1[t] = *(const half8*)(Sw + r*64 + ((g ^ (r&7))<<3)); }
#pragma unroll
    for (int n=0;n<2;++n) b1f[n] = *(const half8*)(wsp + offW1 + (16*n+mrow)*32 + 8*g);
    float cv0 = B1[mrow], cv1 = B1[16+mrow];
#pragma unroll
    for (int n=0;n<2;++n){
        float bb = n ? cv1 : cv0;
        int cc = 16*n + mrow;
#pragma unroll
        for (int t=0;t<4;++t){
            float4v acc = {bb,bb,bb,bb};
            acc = __builtin_amdgcn_mfma_f32_16x16x32_f16(a1[t], b1f[n], acc, 0,0,0);
#pragma unroll
            for (int j=0;j<4;++j){
                int r = 16*t + 4*g + j;
                Sw[r*64 + (((cc>>3) ^ (r&7))<<3) + (cc&7)] = (_Float16)lrelu(acc[j]);
            }
        }
    }
    __threadfence_block();
    // ---- L2: K=32, N=64 (59 real) ----
    half8 a2[4], b2f[4];
#pragma unroll
    for (int t=0;t<4;++t){ int r = 16*t + mrow; a2[t] = *(const half8*)(Sw + r*64 + ((g ^ (r&7))<<3)); }
#pragma unroll
    for (int n=0;n<4;++n) b2f[n] = *(const half8*)(wsp + offW2 + (16*n+mrow)*32 + 8*g);
#pragma unroll
    for (int n=0;n<4;++n){
        int cc = 16*n + mrow;
        float bb = (cc < 59) ? B2[cc] : 0.0f;
#pragma unroll
        for (int t=0;t<4;++t){
            float4v acc = {bb,bb,bb,bb};
            acc = __builtin_amdgcn_mfma_f32_16x16x32_f16(a2[t], b2f[n], acc, 0,0,0);
#pragma unroll
            for (int j=0;j<4;++j){
                int r = 16*t + 4*g + j;
                Sw[r*64 + (((cc>>3) ^ (r&7))<<3) + (cc&7)] = (_Float16)acc[j];
            }
        }
    }
    __threadfence_block();
    // ---- gather tp row l ----
    half8 T[8];
#pragma unroll
    for (int u=0;u<8;++u) T[u] = *(const half8*)(Sw + l*64 + ((u ^ (l&7))<<3));
#pragma unroll
    for (int k=0;k<59;++k) tp[k] = (float)T[k>>3][k&7];
}

__global__ __launch_bounds__(256,4) void nsf_mfma(
    const float* __restrict__ wi, const float* __restrict__ cond,
    const _Float16* __restrict__ wsp,
    const float* __restrict__ p0_w1, const float* __restrict__ p0_b0, const float* __restrict__ p0_b1,
    const float* __restrict__ m1_b0, const float* __restrict__ m1_b1, const float* __restrict__ m1_b2,
    const float* __restrict__ m0_b0, const float* __restrict__ m0_b1, const float* __restrict__ m0_b2,
    float* __restrict__ out)
{
    __shared__ __align__(16) _Float16 S[4][4096];   // per-wave [64 rows][64 f16], swizzled
    const int tid = threadIdx.x;
    const int l = tid & 63, wid = tid >> 6;
    const int i = blockIdx.x*256 + wid*64 + l;
    _Float16* Sw = S[wid];
    const int mrow = l & 15, g = l >> 4;

    auto stu = [&](int row, int u, half8 v){
        *(half8*)(Sw + row*64 + ((u ^ (row&7))<<3)) = v;
    };

    float2 wv2 = reinterpret_cast<const float2*>(wi)[i];
    float w0v = wv2.x, w1v = wv2.y;
    const float* cp = cond + (size_t)i*10;
    float c[10];
#pragma unroll
    for (int k=0;k<10;++k) c[k] = cp[k];

    // cond_e -> f16 chunks A0..A3 (cols 0..31, incl. 2 zero pads)
    half8 A0, A1, A2, A3, Z;
#pragma unroll
    for (int j=0;j<8;++j) Z[j] = (_Float16)0.0f;
    {
        _Float16 ce[30];
        ce[0] = (_Float16)c[8];
        ce[1] = (_Float16)c[9];
        float f = 1.0f;
#pragma unroll
        for (int fi=0; fi<5; ++fi){
            float s8,c8v,s9,c9v;
            __sincosf(c[8]*f, &s8, &c8v);
            __sincosf(c[9]*f, &s9, &c9v);
            ce[2+4*fi+0]=(_Float16)s8;  ce[2+4*fi+1]=(_Float16)s9;
            ce[2+4*fi+2]=(_Float16)c8v; ce[2+4*fi+3]=(_Float16)c9v;
            f *= 2.0f;
        }
#pragma unroll
        for (int k=0;k<8;++k) ce[22+k] = (_Float16)c[k];
#pragma unroll
        for (int j=0;j<8;++j){ A0[j]=ce[j]; A1[j]=ce[8+j]; A2[j]=ce[16+j]; }
#pragma unroll
        for (int j=0;j<8;++j) A3[j] = (j<6) ? ce[24+j] : (_Float16)0.0f;
    }

    auto mkPE = [&](float t, half8& P0, half8& P1){
        float s1,c1v,s2,c2v,s3,c3v,s4,c4v;
        __sincosf(t*1.0f,       &s1,&c1v);
        __sincosf(t*3.3333333f, &s2,&c2v);
        __sincosf(t*5.6666665f, &s3,&c3v);
        __sincosf(t*8.0f,       &s4,&c4v);
        P0[0]=(_Float16)t;   P0[1]=(_Float16)s1; P0[2]=(_Float16)c1v; P0[3]=(_Float16)s2;
        P0[4]=(_Float16)c2v; P0[5]=(_Float16)s3; P0[6]=(_Float16)c3v; P0[7]=(_Float16)s4;
        P1 = Z; P1[0] = (_Float16)c4v;
    };

    // ---- m1: stage xin(w1v), MLP, spline on w0 ----
    half8 P0, P1;
    mkPE(w1v, P0, P1);
    stu(l,0,A0); stu(l,1,A1); stu(l,2,A2); stu(l,3,A3);
    stu(l,4,P0); stu(l,5,P1); stu(l,6,Z);  stu(l,7,Z);
    __threadfence_block();

    float tp[59];
    mfma_mlp(Sw, l, wsp, OFF_M1_W0T, OFF_M1_W1T, OFF_M1_W2T, m1_b0, m1_b1, m1_b2, tp);
    float y0, ld0; rqs(w0v, tp, y0, ld0);

    // ---- m0: stage xin(y0), MLP, spline on w1 ----
    mkPE(y0, P0, P1);
    stu(l,0,A0); stu(l,1,A1); stu(l,2,A2); stu(l,3,A3);
    stu(l,4,P0); stu(l,5,P1); stu(l,6,Z);  stu(l,7,Z);
    __threadfence_block();

    mfma_mlp(Sw, l, wsp, OFF_M0_W0T, OFF_M0_W1T, OFF_M0_W2T, m0_b0, m0_b1, m0_b2, tp);
    float y1, ld1; rqs(w1v, tp, y1, ld1);

    // ---- p0: cond_e(30,+2pad) -> 32 (lrelu) via MFMA, then per-thread 32->4 ----
    stu(l,0,A0); stu(l,1,A1); stu(l,2,A2); stu(l,3,A3);
    __threadfence_block();
    {
        half8 ap[4], bp[2];
#pragma unroll
        for (int t=0;t<4;++t){ int r = 16*t + mrow; ap[t] = *(const half8*)(Sw + r*64 + ((g ^ (r&7))<<3)); }
#pragma unroll
        for (int n=0;n<2;++n) bp[n] = *(const half8*)(wsp + OFF_P0_W0T + (16*n+mrow)*32 + 8*g);
        float pb0 = p0_b0[mrow], pb1 = p0_b0[16+mrow];
#pragma unroll
        for (int n=0;n<2;++n){
            float bb = n ? pb1 : pb0;
            int cc = 16*n + mrow;
#pragma unroll
            for (int t=0;t<4;++t){
                float4v acc = {bb,bb,bb,bb};
                acc = __builtin_amdgcn_mfma_f32_16x16x32_f16(ap[t], bp[n], acc, 0,0,0);
#pragma unroll
                for (int j=0;j<4;++j){
                    int r = 16*t + 4*g + j;
                    Sw[r*64 + (((cc>>3) ^ (r&7))<<3) + (cc&7)] = (_Float16)lrelu(acc[j]);
                }
            }
        }
    }
    __threadfence_block();

    float r4[4] = {p0_b1[0], p0_b1[1], p0_b1[2], p0_b1[3]};
    {
        half8 T[4];
#pragma unroll
        for (int u=0;u<4;++u) T[u] = *(const half8*)(Sw + l*64 + ((u ^ (l&7))<<3));
#pragma unroll
        for (int k=0;k<32;++k){
            float pv = (float)T[k>>3][k&7];
#pragma unroll
            for (int j=0;j<4;++j) r4[j] = fmaf(pv, p0_w1[k*4+j], r4[j]);
        }
    }

    float mu0=r4[0], mu1=r4[1], ls0=r4[2], ls1=r4[3];
    float is0 = __expf(-ls0), is1 = __expf(-ls1);
    float e0 = (y0-mu0)*is0, e1 = (y1-mu1)*is1;
    float rr = e0*e0 + e1*e1;
    float lp = -(ls0+ls1) - 1.8378770664093453f - 0.5f*rr + ld0 + ld1;

    reinterpret_cast<float2*>(out)[i] = make_float2(y0, y1);
    out[2*(size_t)N_PTS + i] = lp;
}

// ---------------- fallback all-f32 kernel (known-good R1) ----------------
template<int OUTW>
__device__ __forceinline__ void addrow(float v, const float* __restrict__ Wrow, float* acc){
#pragma unroll
    for (int j=0;j<OUTW;++j) acc[j] = fmaf(v, Wrow[j], acc[j]);
}
template<int KIN, int OUT>
__device__ __forceinline__ void dense(const float* x, const float* __restrict__ W,
        const float* __restrict__ B, float* acc){
#pragma unroll
    for (int j=0;j<OUT;++j) acc[j] = B[j];
#pragma unroll
    for (int k=0;k<KIN;++k){
#pragma unroll
        for (int j=0;j<OUT;++j) acc[j] = fmaf(x[k], W[k*OUT+j], acc[j]);
    }
}
__device__ __forceinline__ void mlp_layer0(float t, const float* c,
        const float* __restrict__ W0, const float* __restrict__ B0, float* h)
{
#pragma unroll
    for (int j=0;j<32;++j) h[j] = B0[j];
    addrow<32>(t, W0 + 0*32, h);
    float s, co;
    __sincosf(t*1.0f,       &s,&co); addrow<32>(s, W0+1*32, h); addrow<32>(co, W0+2*32, h);
    __sincosf(t*3.3333333f, &s,&co); addrow<32>(s, W0+3*32, h); addrow<32>(co, W0+4*32, h);
    __sincosf(t*5.6666665f, &s,&co); addrow<32>(s, W0+5*32, h); addrow<32>(co, W0+6*32, h);
    __sincosf(t*8.0f,       &s,&co); addrow<32>(s, W0+7*32, h); addrow<32>(co, W0+8*32, h);
    addrow<32>(c[8], W0 + 9*32, h);
    addrow<32>(c[9], W0 +10*32, h);
    float f = 1.0f;
#pragma unroll
    for (int fi=0; fi<5; ++fi){
        float s8,c8v,s9,c9v;
        __sincosf(c[8]*f, &s8, &c8v);
        __sincosf(c[9]*f, &s9, &c9v);
        addrow<32>(s8,  W0 + (11+4*fi)*32, h);
        addrow<32>(s9,  W0 + (12+4*fi)*32, h);
        addrow<32>(c8v, W0 + (13+4*fi)*32, h);
        addrow<32>(c9v, W0 + (14+4*fi)*32, h);
        f *= 2.0f;
    }
#pragma unroll
    for (int k=0;k<8;++k) addrow<32>(c[k], W0 + (31+k)*32, h);
#pragma unroll
    for (int j=0;j<32;++j) h[j] = lrelu(h[j]);
}
__global__ __launch_bounds__(256,3) void nsf_kernel_f32(
    const float* __restrict__ wi, const float* __restrict__ cond,
    const float* __restrict__ p0_w0, const float* __restrict__ p0_b0,
    const float* __restrict__ p0_w1, const float* __restrict__ p0_b1,
    const float* __restrict__ m1_w0, const float* __restrict__ m1_b0,
    const float* __restrict__ m1_w1, const float* __restrict__ m1_b1,
    const float* __restrict__ m1_w2, const float* __restrict__ m1_b2,
    const float* __restrict__ m0_w0, const float* __restrict__ m0_b0,
    const float* __restrict__ m0_w1, const float* __restrict__ m0_b1,
    const float* __restrict__ m0_w2, const float* __restrict__ m0_b2,
    float* __restrict__ out)
{
    const int i = blockIdx.x*256 + threadIdx.x;
    float2 wv2 = reinterpret_cast<const float2*>(wi)[i];
    float w0v = wv2.x, w1v = wv2.y;
    const float* cp = cond + (size_t)i*10;
    float c[10];
#pragma unroll
    for (int k=0;k<10;++k) c[k] = cp[k];

    float tp[59];
    {
        float h[32], gg[32];
        mlp_layer0(w1v, c, m1_w0, m1_b0, h);
        dense<32,32>(h, m1_w1, m1_b1, gg);
#pragma unroll
        for (int j=0;j<32;++j) gg[j] = lrelu(gg[j]);
        dense<32,59>(gg, m1_w2, m1_b2, tp);
    }
    float y0, ld0; rqs(w0v, tp, y0, ld0);
    {
        float h[32], gg[32];
        mlp_layer0(y0, c, m0_w0, m0_b0, h);
        dense<32,32>(h, m0_w1, m0_b1, gg);
#pragma unroll
        for (int j=0;j<32;++j) gg[j] = lrelu(gg[j]);
        dense<32,59>(gg, m0_w2, m0_b2, tp);
    }
    float y1, ld1; rqs(w1v, tp, y1, ld1);

    float r[4];
    {
        float ph[32];
#pragma unroll
        for (int j=0;j<32;++j) ph[j] = p0_b0[j];
        addrow<32>(c[8], p0_w0 + 0*32, ph);
        addrow<32>(c[9], p0_w0 + 1*32, ph);
        float f = 1.0f;
#pragma unroll
        for (int fi=0; fi<5; ++fi){
            float s8,c8v,s9,c9v;
            __sincosf(c[8]*f, &s8, &c8v);
            __sincosf(c[9]*f, &s9, &c9v);
            addrow<32>(s8,  p0_w0 + (2+4*fi)*32, ph);
            addrow<32>(s9,  p0_w0 + (3+4*fi)*32, ph);
            addrow<32>(c8v, p0_w0 + (4+4*fi)*32, ph);
            addrow<32>(c9v, p0_w0 + (5+4*fi)*32, ph);
            f *= 2.0f;
        }
#pragma unroll
        for (int k=0;k<8;++k) addrow<32>(c[k], p0_w0 + (22+k)*32, ph);
#pragma unroll
        for (int j=0;j<32;++j) ph[j] = lrelu(ph[j]);
        dense<32,4>(ph, p0_w1, p0_b1, r);
    }

    float mu0=r[0], mu1=r[1], ls0=r[2], ls1=r[3];
    float is0 = __expf(-ls0), is1 = __expf(-ls1);
    float e0 = (y0-mu0)*is0, e1 = (y1-mu1)*is1;
    float rr = e0*e0 + e1*e1;
    float lp = -(ls0+ls1) - 1.8378770664093453f - 0.5f*rr + ld0 + ld1;

    reinterpret_cast<float2*>(out)[i] = make_float2(y0, y1);
    out[2*(size_t)N_PTS + i] = lp;
}

extern "C" void kernel_launch(void* const* d_in, const int* in_sizes, int n_in,
                              void* d_out, int out_size, void* d_ws, size_t ws_size,
                              hipStream_t stream)
{
    const float* wi    = (const float*)d_in[0];
    const float* cond  = (const float*)d_in[1];
    const float* p0_w0 = (const float*)d_in[2];
    const float* p0_b0 = (const float*)d_in[3];
    const float* p0_w1 = (const float*)d_in[4];
    const float* p0_b1 = (const float*)d_in[5];
    const float* m1_w0 = (const float*)d_in[6];
    const float* m1_b0 = (const float*)d_in[7];
    const float* m1_w1 = (const float*)d_in[8];
    const float* m1_b1 = (const float*)d_in[9];
    const float* m1_w2 = (const float*)d_in[10];
    const float* m1_b2 = (const float*)d_in[11];
    const float* m0_w0 = (const float*)d_in[12];
    const float* m0_b0 = (const float*)d_in[13];
    const float* m0_w1 = (const float*)d_in[14];
    const float* m0_b1 = (const float*)d_in[15];
    const float* m0_w2 = (const float*)d_in[16];
    const float* m0_b2 = (const float*)d_in[17];
    float* out = (float*)d_out;

    dim3 block(256);
    if (ws_size >= (size_t)WS_F16 * sizeof(_Float16)) {
        _Float16* wsp = (_Float16*)d_ws;
        hipLaunchKernelGGL(pack_weights, dim3((WS_F16+255)/256), block, 0, stream,
            m1_w0, m1_w1, m1_w2, m0_w0, m0_w1, m0_w2, p0_w0, wsp);
        hipLaunchKernelGGL(nsf_mfma, dim3(N_PTS/256), block, 0, stream,
            wi, cond, wsp, p0_w1, p0_b0, p0_b1,
            m1_b0, m1_b1, m1_b2, m0_b0, m0_b1, m0_b2, out);
    } else {
        hipLaunchKernelGGL(nsf_kernel_f32, dim3(N_PTS/256), block, 0, stream,
            wi, cond, p0_w0, p0_b0, p0_w1, p0_b1,
            m1_w0, m1_b0, m1_w1, m1_b1, m1_w2, m1_b2,
            m0_w0, m0_b0, m0_w1, m0_b1, m0_w2, m0_b2, out);
    }
}

// Round 5
// 360.303 us; speedup vs baseline: 2.0369x; 1.2303x over previous
//
#include <hip/hip_runtime.h>
#include <math.h>

#define N_PTS 2097152
#define TAILC 0.53974324f   // log(exp(1-0.001)-1)

typedef unsigned int u32;
typedef _Float16 half8 __attribute__((ext_vector_type(8)));
typedef float float4v __attribute__((ext_vector_type(4)));

__device__ __forceinline__ float lrelu(float x){ return x > 0.0f ? x : 0.01f*x; }
__device__ __forceinline__ float softplus_(float x){
    return fmaxf(x, 0.0f) + log1pf(__expf(-fabsf(x)));
}

// ---------------- rational-quadratic spline on PACKED params ----------------
// T[8] half8: lanes 0..19 = uw, 20..39 = uh, 40..58 = interior derivs.
// Unpacks phase-locally to keep register pressure low (no f32 tp[59] array).
__device__ __forceinline__ void rqs_p(float x, const half8* T, float& yo, float& lado)
{
    float xc = fminf(fmaxf(x,-1.0f),1.0f);
    int idx = 0;
    float inCw = -1.0f, inW = 1.0f;
    {
        float w[20];
#pragma unroll
        for (int i=0;i<20;++i) w[i] = (float)T[i>>3][i&7];
        float mw = w[0];
#pragma unroll
        for (int i=1;i<20;++i) mw = fmaxf(mw, w[i]);
        float sw = 0.f;
#pragma unroll
        for (int i=0;i<20;++i){ w[i] = __expf(w[i]-mw); sw += w[i]; }
        float invw = 0.98f / sw;
        float cum = 0.f;
#pragma unroll
        for (int i=0;i<20;++i){
            float wv = fmaf(invw, w[i], 0.001f);
            float cwL = (i==0) ? -1.0f : fmaf(2.0f, cum, -1.0f);
            float cumN = cum + wv;
            float cwR = (i==19) ? 1.0f : fmaf(2.0f, cumN, -1.0f);
            if (xc >= cwL){ idx = i; inCw = cwL; inW = cwR - cwL; }
            cum = cumN;
        }
    }
    float inCh = -1.0f, inH = 1.0f;
    {
        float h[20];
#pragma unroll
        for (int i=0;i<20;++i) h[i] = (float)T[(20+i)>>3][(20+i)&7];
        float mh = h[0];
#pragma unroll
        for (int i=1;i<20;++i) mh = fmaxf(mh, h[i]);
        float sh = 0.f;
#pragma unroll
        for (int i=0;i<20;++i){ h[i] = __expf(h[i]-mh); sh += h[i]; }
        float invh = 0.98f / sh;
        float hcum = 0.f;
#pragma unroll
        for (int i=0;i<20;++i){
            float hv = fmaf(invh, h[i], 0.001f);
            float chL = (i==0) ? -1.0f : fmaf(2.0f, hcum, -1.0f);
            float hcumN = hcum + hv;
            float chR = (i==19) ? 1.0f : fmaf(2.0f, hcumN, -1.0f);
            if (i == idx){ inCh = chL; inH = chR - chL; }
            hcum = hcumN;
        }
    }
    float udl = TAILC, udr = TAILC;
#pragma unroll
    for (int t=0;t<19;++t){
        float v = (float)T[(40+t)>>3][(40+t)&7];
        if (idx == t+1) udl = v;
        if (idx == t)   udr = v;
    }
    float inD   = 0.001f + softplus_(udl);
    float inDp1 = 0.001f + softplus_(udr);
    float inDelta = inH / inW;
    float th  = (xc - inCw) / inW;
    float omt = 1.0f - th;
    float t1  = th * omt;
    float num = inH * (inDelta*th*th + inD*t1);
    float den = inDelta + (inD + inDp1 - 2.0f*inDelta)*t1;
    float y = inCh + num/den;
    float dnum = inDelta*inDelta*(inDp1*th*th + 2.0f*inDelta*t1 + inD*omt*omt);
    float lad = __logf(dnum) - 2.0f*__logf(den);
    bool inside = (x >= -1.0f) && (x <= 1.0f);
    yo   = inside ? y   : x;
    lado = inside ? lad : 0.0f;
}

// ---- packed transposed f16 weights in d_ws ----
// WT[out][K] zero-padded; A-col mapping: cols 0..29 = cond_e, 30..31 = 0,
// cols 32..40 = PE(t), 41..63 = 0.
#define OFF_M1_W0T 0        // [32][64]
#define OFF_M1_W1T 2048     // [32][32]
#define OFF_M1_W2T 3072     // [64][32]
#define OFF_M0_W0T 5120
#define OFF_M0_W1T 7168
#define OFF_M0_W2T 8192
#define OFF_P0_W0T 10240    // [32][32]
#define WS_F16     11264

__global__ void pack_weights(const float* __restrict__ m1_w0, const float* __restrict__ m1_w1,
                             const float* __restrict__ m1_w2, const float* __restrict__ m0_w0,
                             const float* __restrict__ m0_w1, const float* __restrict__ m0_w2,
                             const float* __restrict__ p0_w0, _Float16* __restrict__ ws)
{
    int idx = blockIdx.x*256 + threadIdx.x;
    if (idx >= WS_F16) return;
    float v = 0.0f;
    if (idx < 2048 || (idx >= 5120 && idx < 7168)) {          // W0T [32][64]
        const float* W = (idx < 2048) ? m1_w0 : m0_w0;
        int r = (idx < 2048) ? idx : idx - 5120;
        int o = r >> 6, k = r & 63;
        if (k < 30)                 v = W[(9+k)*32 + o];
        else if (k >= 32 && k < 41) v = W[(k-32)*32 + o];
    } else if (idx < 3072 || (idx >= 7168 && idx < 8192)) {   // W1T [32][32]
        const float* W = (idx < 3072) ? m1_w1 : m0_w1;
        int r = (idx < 3072) ? idx - 2048 : idx - 7168;
        int o = r >> 5, k = r & 31;
        v = W[k*32 + o];
    } else if (idx < 5120 || (idx >= 8192 && idx < 10240)) {  // W2T [64][32]
        const float* W = (idx < 5120) ? m1_w2 : m0_w2;
        int r = (idx < 5120) ? idx - 3072 : idx - 8192;
        int o = r >> 5, k = r & 31;
        if (o < 59) v = W[k*59 + o];
    } else {                                                  // p0 W0T [32][32]
        int r = idx - 10240;
        int o = r >> 5, k = r & 31;
        if (k < 30) v = p0_w0[k*32 + o];
    }
    ws[idx] = (_Float16)v;
}

// one transform MLP: A-buf (xin) already staged in Sw; leaves packed tp in T[8]
__device__ __forceinline__ void mfma_mlp(_Float16* Sw, int l,
    const _Float16* __restrict__ wsp, int offW0, int offW1, int offW2,
    const float* __restrict__ B0, const float* __restrict__ B1,
    const float* __restrict__ B2, half8* T)
{
    const int mrow = l & 15, g = l >> 4;
    // ---- L0: K=64 (2 ksteps), N=32 ----
    {
        half8 a[4][2], b[2][2];
#pragma unroll
        for (int t=0;t<4;++t){
            int r = 16*t + mrow;
#pragma unroll
            for (int s=0;s<2;++s)
                a[t][s] = *(const half8*)(Sw + r*64 + (((4*s+g) ^ (r&7))<<3));
        }
#pragma unroll
        for (int n=0;n<2;++n)
#pragma unroll
            for (int s=0;s<2;++s)
                b[n][s] = *(const half8*)(wsp + offW0 + (16*n+mrow)*64 + 32*s + 8*g);
        float bv0 = B0[mrow], bv1 = B0[16+mrow];
#pragma unroll
        for (int n=0;n<2;++n){
            float bb = n ? bv1 : bv0;
            int cc = 16*n + mrow;
#pragma unroll
            for (int t=0;t<4;++t){
                float4v acc = {bb,bb,bb,bb};
                acc = __builtin_amdgcn_mfma_f32_16x16x32_f16(a[t][0], b[n][0], acc, 0,0,0);
                acc = __builtin_amdgcn_mfma_f32_16x16x32_f16(a[t][1], b[n][1], acc, 0,0,0);
#pragma unroll
                for (int j=0;j<4;++j){
                    int r = 16*t + 4*g + j;
                    Sw[r*64 + (((cc>>3) ^ (r&7))<<3) + (cc&7)] = (_Float16)lrelu(acc[j]);
                }
            }
        }
    }
    __threadfence_block();
    // ---- L1: K=32, N=32 ----
    {
        half8 a1[4], b1f[2];
#pragma unroll
        for (int t=0;t<4;++t){ int r = 16*t + mrow; a1[t] = *(const half8*)(Sw + r*64 + ((g ^ (r&7))<<3)); }
#pragma unroll
        for (int n=0;n<2;++n) b1f[n] = *(const half8*)(wsp + offW1 + (16*n+mrow)*32 + 8*g);
        float cv0 = B1[mrow], cv1 = B1[16+mrow];
#pragma unroll
        for (int n=0;n<2;++n){
            float bb = n ? cv1 : cv0;
            int cc = 16*n + mrow;
#pragma unroll
            for (int t=0;t<4;++t){
                float4v acc = {bb,bb,bb,bb};
                acc = __builtin_amdgcn_mfma_f32_16x16x32_f16(a1[t], b1f[n], acc, 0,0,0);
#pragma unroll
                for (int j=0;j<4;++j){
                    int r = 16*t + 4*g + j;
                    Sw[r*64 + (((cc>>3) ^ (r&7))<<3) + (cc&7)] = (_Float16)lrelu(acc[j]);
                }
            }
        }
    }
    __threadfence_block();
    // ---- L2: K=32, N=64 (59 real) ----
    {
        half8 a2[4], b2f[4];
#pragma unroll
        for (int t=0;t<4;++t){ int r = 16*t + mrow; a2[t] = *(const half8*)(Sw + r*64 + ((g ^ (r&7))<<3)); }
#pragma unroll
        for (int n=0;n<4;++n) b2f[n] = *(const half8*)(wsp + offW2 + (16*n+mrow)*32 + 8*g);
#pragma unroll
        for (int n=0;n<4;++n){
            int cc = 16*n + mrow;
            float bb = (cc < 59) ? B2[cc] : 0.0f;
#pragma unroll
            for (int t=0;t<4;++t){
                float4v acc = {bb,bb,bb,bb};
                acc = __builtin_amdgcn_mfma_f32_16x16x32_f16(a2[t], b2f[n], acc, 0,0,0);
#pragma unroll
                for (int j=0;j<4;++j){
                    int r = 16*t + 4*g + j;
                    Sw[r*64 + (((cc>>3) ^ (r&7))<<3) + (cc&7)] = (_Float16)acc[j];
                }
            }
        }
    }
    __threadfence_block();
    // ---- gather packed tp row l (stays f16-packed; rqs_p unpacks lazily) ----
#pragma unroll
    for (int u=0;u<8;++u) T[u] = *(const half8*)(Sw + l*64 + ((u ^ (l&7))<<3));
}

__global__ __launch_bounds__(256,3) void nsf_mfma(
    const float* __restrict__ wi, const float* __restrict__ cond,
    const _Float16* __restrict__ wsp,
    const float* __restrict__ p0_w1, const float* __restrict__ p0_b0, const float* __restrict__ p0_b1,
    const float* __restrict__ m1_b0, const float* __restrict__ m1_b1, const float* __restrict__ m1_b2,
    const float* __restrict__ m0_b0, const float* __restrict__ m0_b1, const float* __restrict__ m0_b2,
    float* __restrict__ out)
{
    __shared__ __align__(16) _Float16 S[4][4096];   // per-wave [64 rows][64 f16], swizzled
    const int tid = threadIdx.x;
    const int l = tid & 63, wid = tid >> 6;
    const int i = blockIdx.x*256 + wid*64 + l;
    _Float16* Sw = S[wid];
    const int mrow = l & 15, g = l >> 4;

    auto stu = [&](int row, int u, half8 v){
        *(half8*)(Sw + row*64 + ((u ^ (row&7))<<3)) = v;
    };

    float2 wv2 = reinterpret_cast<const float2*>(wi)[i];
    float w0v = wv2.x, w1v = wv2.y;
    const float* cp = cond + (size_t)i*10;
    float c[10];
#pragma unroll
    for (int k=0;k<10;++k) c[k] = cp[k];

    // cond_e -> f16 chunks A0..A3 (cols 0..31, incl. 2 zero pads)
    half8 A0, A1, A2, A3, Z;
#pragma unroll
    for (int j=0;j<8;++j) Z[j] = (_Float16)0.0f;
    {
        _Float16 ce[30];
        ce[0] = (_Float16)c[8];
        ce[1] = (_Float16)c[9];
        float f = 1.0f;
#pragma unroll
        for (int fi=0; fi<5; ++fi){
            float s8,c8v,s9,c9v;
            __sincosf(c[8]*f, &s8, &c8v);
            __sincosf(c[9]*f, &s9, &c9v);
            ce[2+4*fi+0]=(_Float16)s8;  ce[2+4*fi+1]=(_Float16)s9;
            ce[2+4*fi+2]=(_Float16)c8v; ce[2+4*fi+3]=(_Float16)c9v;
            f *= 2.0f;
        }
#pragma unroll
        for (int k=0;k<8;++k) ce[22+k] = (_Float16)c[k];
#pragma unroll
        for (int j=0;j<8;++j){ A0[j]=ce[j]; A1[j]=ce[8+j]; A2[j]=ce[16+j]; }
#pragma unroll
        for (int j=0;j<8;++j) A3[j] = (j<6) ? ce[24+j] : (_Float16)0.0f;
    }

    auto mkPE = [&](float t, half8& P0, half8& P1){
        float s1,c1v,s2,c2v,s3,c3v,s4,c4v;
        __sincosf(t*1.0f,       &s1,&c1v);
        __sincosf(t*3.3333333f, &s2,&c2v);
        __sincosf(t*5.6666665f, &s3,&c3v);
        __sincosf(t*8.0f,       &s4,&c4v);
        P0[0]=(_Float16)t;   P0[1]=(_Float16)s1; P0[2]=(_Float16)c1v; P0[3]=(_Float16)s2;
        P0[4]=(_Float16)c2v; P0[5]=(_Float16)s3; P0[6]=(_Float16)c3v; P0[7]=(_Float16)s4;
        P1 = Z; P1[0] = (_Float16)c4v;
    };

    // ---- m1: stage xin(w1v), MLP, spline on w0 ----
    half8 P0, P1;
    mkPE(w1v, P0, P1);
    stu(l,0,A0); stu(l,1,A1); stu(l,2,A2); stu(l,3,A3);
    stu(l,4,P0); stu(l,5,P1); stu(l,6,Z);  stu(l,7,Z);
    __threadfence_block();

    half8 T[8];
    mfma_mlp(Sw, l, wsp, OFF_M1_W0T, OFF_M1_W1T, OFF_M1_W2T, m1_b0, m1_b1, m1_b2, T);
    float y0, ld0; rqs_p(w0v, T, y0, ld0);

    // ---- m0: stage xin(y0), MLP, spline on w1 ----
    mkPE(y0, P0, P1);
    stu(l,0,A0); stu(l,1,A1); stu(l,2,A2); stu(l,3,A3);
    stu(l,4,P0); stu(l,5,P1); stu(l,6,Z);  stu(l,7,Z);
    __threadfence_block();

    mfma_mlp(Sw, l, wsp, OFF_M0_W0T, OFF_M0_W1T, OFF_M0_W2T, m0_b0, m0_b1, m0_b2, T);
    float y1, ld1; rqs_p(w1v, T, y1, ld1);

    // ---- p0: cond_e(30,+2pad) -> 32 (lrelu) via MFMA, then per-thread 32->4 ----
    stu(l,0,A0); stu(l,1,A1); stu(l,2,A2); stu(l,3,A3);
    __threadfence_block();
    {
        half8 ap[4], bp[2];
#pragma unroll
        for (int t=0;t<4;++t){ int r = 16*t + mrow; ap[t] = *(const half8*)(Sw + r*64 + ((g ^ (r&7))<<3)); }
#pragma unroll
        for (int n=0;n<2;++n) bp[n] = *(const half8*)(wsp + OFF_P0_W0T + (16*n+mrow)*32 + 8*g);
        float pb0 = p0_b0[mrow], pb1 = p0_b0[16+mrow];
#pragma unroll
        for (int n=0;n<2;++n){
            float bb = n ? pb1 : pb0;
            int cc = 16*n + mrow;
#pragma unroll
            for (int t=0;t<4;++t){
                float4v acc = {bb,bb,bb,bb};
                acc = __builtin_amdgcn_mfma_f32_16x16x32_f16(ap[t], bp[n], acc, 0,0,0);
#pragma unroll
                for (int j=0;j<4;++j){
                    int r = 16*t + 4*g + j;
                    Sw[r*64 + (((cc>>3) ^ (r&7))<<3) + (cc&7)] = (_Float16)lrelu(acc[j]);
                }
            }
        }
    }
    __threadfence_block();

    float r4[4] = {p0_b1[0], p0_b1[1], p0_b1[2], p0_b1[3]};
    {
        half8 Tq[4];
#pragma unroll
        for (int u=0;u<4;++u) Tq[u] = *(const half8*)(Sw + l*64 + ((u ^ (l&7))<<3));
#pragma unroll
        for (int k=0;k<32;++k){
            float pv = (float)Tq[k>>3][k&7];
#pragma unroll
            for (int j=0;j<4;++j) r4[j] = fmaf(pv, p0_w1[k*4+j], r4[j]);
        }
    }

    float mu0=r4[0], mu1=r4[1], ls0=r4[2], ls1=r4[3];
    float is0 = __expf(-ls0), is1 = __expf(-ls1);
    float e0 = (y0-mu0)*is0, e1 = (y1-mu1)*is1;
    float rr = e0*e0 + e1*e1;
    float lp = -(ls0+ls1) - 1.8378770664093453f - 0.5f*rr + ld0 + ld1;

    reinterpret_cast<float2*>(out)[i] = make_float2(y0, y1);
    out[2*(size_t)N_PTS + i] = lp;
}

// ---------------- fallback all-f32 kernel (known-good R1) ----------------
__device__ __forceinline__ void rqs_f32(float x, float* tp, float& yo, float& lado)
{
    float mw = tp[0];
#pragma unroll
    for (int i=1;i<20;++i) mw = fmaxf(mw, tp[i]);
    float sw = 0.f;
#pragma unroll
    for (int i=0;i<20;++i){ tp[i] = __expf(tp[i]-mw); sw += tp[i]; }
    float invw = 0.98f / sw;
    float mh = tp[20];
#pragma unroll
    for (int i=1;i<20;++i) mh = fmaxf(mh, tp[20+i]);
    float sh = 0.f;
#pragma unroll
    for (int i=0;i<20;++i){ tp[20+i] = __expf(tp[20+i]-mh); sh += tp[20+i]; }
    float invh = 0.98f / sh;
    float xc = fminf(fmaxf(x,-1.0f),1.0f);
    float cum = 0.f; int idx = 0;
    float inCw = -1.0f, inW = 1.0f;
#pragma unroll
    for (int i=0;i<20;++i){
        float wv = fmaf(invw, tp[i], 0.001f);
        float cwL = (i==0) ? -1.0f : fmaf(2.0f, cum, -1.0f);
        float cumN = cum + wv;
        float cwR = (i==19) ? 1.0f : fmaf(2.0f, cumN, -1.0f);
        if (xc >= cwL){ idx = i; inCw = cwL; inW = cwR - cwL; }
        cum = cumN;
    }
    float hcum = 0.f; float inCh = -1.0f, inH = 1.0f;
#pragma unroll
    for (int i=0;i<20;++i){
        float hv = fmaf(invh, tp[20+i], 0.001f);
        float chL = (i==0) ? -1.0f : fmaf(2.0f, hcum, -1.0f);
        float hcumN = hcum + hv;
        float chR = (i==19) ? 1.0f : fmaf(2.0f, hcumN, -1.0f);
        if (i == idx){ inCh = chL; inH = chR - chL; }
        hcum = hcumN;
    }
    float udl = TAILC, udr = TAILC;
#pragma unroll
    for (int t=0;t<19;++t){
        if (idx == t+1) udl = tp[40+t];
        if (idx == t)   udr = tp[40+t];
    }
    float inD   = 0.001f + softplus_(udl);
    float inDp1 = 0.001f + softplus_(udr);
    float inDelta = inH / inW;
    float th  = (xc - inCw) / inW;
    float omt = 1.0f - th;
    float t1  = th * omt;
    float num = inH * (inDelta*th*th + inD*t1);
    float den = inDelta + (inD + inDp1 - 2.0f*inDelta)*t1;
    float y = inCh + num/den;
    float dnum = inDelta*inDelta*(inDp1*th*th + 2.0f*inDelta*t1 + inD*omt*omt);
    float lad = __logf(dnum) - 2.0f*__logf(den);
    bool inside = (x >= -1.0f) && (x <= 1.0f);
    yo   = inside ? y   : x;
    lado = inside ? lad : 0.0f;
}
template<int OUTW>
__device__ __forceinline__ void addrow(float v, const float* __restrict__ Wrow, float* acc){
#pragma unroll
    for (int j=0;j<OUTW;++j) acc[j] = fmaf(v, Wrow[j], acc[j]);
}
template<int KIN, int OUT>
__device__ __forceinline__ void dense(const float* x, const float* __restrict__ W,
        const float* __restrict__ B, float* acc){
#pragma unroll
    for (int j=0;j<OUT;++j) acc[j] = B[j];
#pragma unroll
    for (int k=0;k<KIN;++k){
#pragma unroll
        for (int j=0;j<OUT;++j) acc[j] = fmaf(x[k], W[k*OUT+j], acc[j]);
    }
}
__device__ __forceinline__ void mlp_layer0(float t, const float* c,
        const float* __restrict__ W0, const float* __restrict__ B0, float* h)
{
#pragma unroll
    for (int j=0;j<32;++j) h[j] = B0[j];
    addrow<32>(t, W0 + 0*32, h);
    float s, co;
    __sincosf(t*1.0f,       &s,&co); addrow<32>(s, W0+1*32, h); addrow<32>(co, W0+2*32, h);
    __sincosf(t*3.3333333f, &s,&co); addrow<32>(s, W0+3*32, h); addrow<32>(co, W0+4*32, h);
    __sincosf(t*5.6666665f, &s,&co); addrow<32>(s, W0+5*32, h); addrow<32>(co, W0+6*32, h);
    __sincosf(t*8.0f,       &s,&co); addrow<32>(s, W0+7*32, h); addrow<32>(co, W0+8*32, h);
    addrow<32>(c[8], W0 + 9*32, h);
    addrow<32>(c[9], W0 +10*32, h);
    float f = 1.0f;
#pragma unroll
    for (int fi=0; fi<5; ++fi){
        float s8,c8v,s9,c9v;
        __sincosf(c[8]*f, &s8, &c8v);
        __sincosf(c[9]*f, &s9, &c9v);
        addrow<32>(s8,  W0 + (11+4*fi)*32, h);
        addrow<32>(s9,  W0 + (12+4*fi)*32, h);
        addrow<32>(c8v, W0 + (13+4*fi)*32, h);
        addrow<32>(c9v, W0 + (14+4*fi)*32, h);
        f *= 2.0f;
    }
#pragma unroll
    for (int k=0;k<8;++k) addrow<32>(c[k], W0 + (31+k)*32, h);
#pragma unroll
    for (int j=0;j<32;++j) h[j] = lrelu(h[j]);
}
__global__ __launch_bounds__(256,3) void nsf_kernel_f32(
    const float* __restrict__ wi, const float* __restrict__ cond,
    const float* __restrict__ p0_w0, const float* __restrict__ p0_b0,
    const float* __restrict__ p0_w1, const float* __restrict__ p0_b1,
    const float* __restrict__ m1_w0, const float* __restrict__ m1_b0,
    const float* __restrict__ m1_w1, const float* __restrict__ m1_b1,
    const float* __restrict__ m1_w2, const float* __restrict__ m1_b2,
    const float* __restrict__ m0_w0, const float* __restrict__ m0_b0,
    const float* __restrict__ m0_w1, const float* __restrict__ m0_b1,
    const float* __restrict__ m0_w2, const float* __restrict__ m0_b2,
    float* __restrict__ out)
{
    const int i = blockIdx.x*256 + threadIdx.x;
    float2 wv2 = reinterpret_cast<const float2*>(wi)[i];
    float w0v = wv2.x, w1v = wv2.y;
    const float* cp = cond + (size_t)i*10;
    float c[10];
#pragma unroll
    for (int k=0;k<10;++k) c[k] = cp[k];

    float tp[59];
    {
        float h[32], gg[32];
        mlp_layer0(w1v, c, m1_w0, m1_b0, h);
        dense<32,32>(h, m1_w1, m1_b1, gg);
#pragma unroll
        for (int j=0;j<32;++j) gg[j] = lrelu(gg[j]);
        dense<32,59>(gg, m1_w2, m1_b2, tp);
    }
    float y0, ld0; rqs_f32(w0v, tp, y0, ld0);
    {
        float h[32], gg[32];
        mlp_layer0(y0, c, m0_w0, m0_b0, h);
        dense<32,32>(h, m0_w1, m0_b1, gg);
#pragma unroll
        for (int j=0;j<32;++j) gg[j] = lrelu(gg[j]);
        dense<32,59>(gg, m0_w2, m0_b2, tp);
    }
    float y1, ld1; rqs_f32(w1v, tp, y1, ld1);

    float r[4];
    {
        float ph[32];
#pragma unroll
        for (int j=0;j<32;++j) ph[j] = p0_b0[j];
        addrow<32>(c[8], p0_w0 + 0*32, ph);
        addrow<32>(c[9], p0_w0 + 1*32, ph);
        float f = 1.0f;
#pragma unroll
        for (int fi=0; fi<5; ++fi){
            float s8,c8v,s9,c9v;
            __sincosf(c[8]*f, &s8, &c8v);
            __sincosf(c[9]*f, &s9, &c9v);
            addrow<32>(s8,  p0_w0 + (2+4*fi)*32, ph);
            addrow<32>(s9,  p0_w0 + (3+4*fi)*32, ph);
            addrow<32>(c8v, p0_w0 + (4+4*fi)*32, ph);
            addrow<32>(c9v, p0_w0 + (5+4*fi)*32, ph);
            f *= 2.0f;
        }
#pragma unroll
        for (int k=0;k<8;++k) addrow<32>(c[k], p0_w0 + (22+k)*32, ph);
#pragma unroll
        for (int j=0;j<32;++j) ph[j] = lrelu(ph[j]);
        dense<32,4>(ph, p0_w1, p0_b1, r);
    }

    float mu0=r[0], mu1=r[1], ls0=r[2], ls1=r[3];
    float is0 = __expf(-ls0), is1 = __expf(-ls1);
    float e0 = (y0-mu0)*is0, e1 = (y1-mu1)*is1;
    float rr = e0*e0 + e1*e1;
    float lp = -(ls0+ls1) - 1.8378770664093453f - 0.5f*rr + ld0 + ld1;

    reinterpret_cast<float2*>(out)[i] = make_float2(y0, y1);
    out[2*(size_t)N_PTS + i] = lp;
}

extern "C" void kernel_launch(void* const* d_in, const int* in_sizes, int n_in,
                              void* d_out, int out_size, void* d_ws, size_t ws_size,
                              hipStream_t stream)
{
    const float* wi    = (const float*)d_in[0];
    const float* cond  = (const float*)d_in[1];
    const float* p0_w0 = (const float*)d_in[2];
    const float* p0_b0 = (const float*)d_in[3];
    const float* p0_w1 = (const float*)d_in[4];
    const float* p0_b1 = (const float*)d_in[5];
    const float* m1_w0 = (const float*)d_in[6];
    const float* m1_b0 = (const float*)d_in[7];
    const float* m1_w1 = (const float*)d_in[8];
    const float* m1_b1 = (const float*)d_in[9];
    const float* m1_w2 = (const float*)d_in[10];
    const float* m1_b2 = (const float*)d_in[11];
    const float* m0_w0 = (const float*)d_in[12];
    const float* m0_b0 = (const float*)d_in[13];
    const float* m0_w1 = (const float*)d_in[14];
    const float* m0_b1 = (const float*)d_in[15];
    const float* m0_w2 = (const float*)d_in[16];
    const float* m0_b2 = (const float*)d_in[17];
    float* out = (float*)d_out;

    dim3 block(256);
    if (ws_size >= (size_t)WS_F16 * sizeof(_Float16)) {
        _Float16* wsp = (_Float16*)d_ws;
        hipLaunchKernelGGL(pack_weights, dim3((WS_F16+255)/256), block, 0, stream,
            m1_w0, m1_w1, m1_w2, m0_w0, m0_w1, m0_w2, p0_w0, wsp);
        hipLaunchKernelGGL(nsf_mfma, dim3(N_PTS/256), block, 0, stream,
            wi, cond, wsp, p0_w1, p0_b0, p0_b1,
            m1_b0, m1_b1, m1_b2, m0_b0, m0_b1, m0_b2, out);
    } else {
        hipLaunchKernelGGL(nsf_kernel_f32, dim3(N_PTS/256), block, 0, stream,
            wi, cond, p0_w0, p0_b0, p0_w1, p0_b1,
            m1_w0, m1_b0, m1_w1, m1_b1, m1_w2, m1_b2,
            m0_w0, m0_b0, m0_w1, m0_b1, m0_w2, m0_b2, out);
    }
}

// Round 6
// 233.962 us; speedup vs baseline: 3.1368x; 1.5400x over previous
//
#include <hip/hip_runtime.h>
#include <math.h>

#define N_PTS 2097152
#define TAILC 0.53974324f   // log(exp(1-0.001)-1)

typedef unsigned int u32;
typedef _Float16 half8 __attribute__((ext_vector_type(8)));
typedef float float4v __attribute__((ext_vector_type(4)));

__device__ __forceinline__ float lrelu(float x){ return x > 0.0f ? x : 0.01f*x; }
__device__ __forceinline__ float softplus_(float x){
    return fmaxf(x, 0.0f) + log1pf(__expf(-fabsf(x)));
}

// Single shared allocation reachable from kernel AND noinline callees so the
// compiler keeps addrspace(3) provenance (ds ops, not flat).
__device__ __forceinline__ _Float16* waveS(){
    __shared__ _Float16 S[4][4096];    // per-wave [64 rows][64 f16], swizzled
    return &S[0][0];
}

// ---- packed transposed f16 weights in d_ws ----
// WT[out][K] zero-padded; A-col mapping: cols 0..29 = cond_e, 30..31 = 0,
// cols 32..40 = PE(t), 41..63 = 0.
#define OFF_M1_W0T 0        // [32][64]
#define OFF_M1_W1T 2048     // [32][32]
#define OFF_M1_W2T 3072     // [64][32]
#define OFF_M0_W0T 5120
#define OFF_M0_W1T 7168
#define OFF_M0_W2T 8192
#define OFF_P0_W0T 10240    // [32][32]
#define WS_F16     11264

__global__ void pack_weights(const float* __restrict__ m1_w0, const float* __restrict__ m1_w1,
                             const float* __restrict__ m1_w2, const float* __restrict__ m0_w0,
                             const float* __restrict__ m0_w1, const float* __restrict__ m0_w2,
                             const float* __restrict__ p0_w0, _Float16* __restrict__ ws)
{
    int idx = blockIdx.x*256 + threadIdx.x;
    if (idx >= WS_F16) return;
    float v = 0.0f;
    if (idx < 2048 || (idx >= 5120 && idx < 7168)) {          // W0T [32][64]
        const float* W = (idx < 2048) ? m1_w0 : m0_w0;
        int r = (idx < 2048) ? idx : idx - 5120;
        int o = r >> 6, k = r & 63;
        if (k < 30)                 v = W[(9+k)*32 + o];
        else if (k >= 32 && k < 41) v = W[(k-32)*32 + o];
    } else if (idx < 3072 || (idx >= 7168 && idx < 8192)) {   // W1T [32][32]
        const float* W = (idx < 3072) ? m1_w1 : m0_w1;
        int r = (idx < 3072) ? idx - 2048 : idx - 7168;
        int o = r >> 5, k = r & 31;
        v = W[k*32 + o];
    } else if (idx < 5120 || (idx >= 8192 && idx < 10240)) {  // W2T [64][32]
        const float* W = (idx < 5120) ? m1_w2 : m0_w2;
        int r = (idx < 5120) ? idx - 3072 : idx - 8192;
        int o = r >> 5, k = r & 31;
        if (o < 59) v = W[k*59 + o];
    } else {                                                  // p0 W0T [32][32]
        int r = idx - 10240;
        int o = r >> 5, k = r & 31;
        if (k < 30) v = p0_w0[k*32 + o];
    }
    ws[idx] = (_Float16)v;
}

// ---------- one transform MLP, emitted ONCE (noinline), output stays in LDS ----------
__device__ __noinline__ void mlp_lds(int tid,
    const _Float16* __restrict__ W0, const _Float16* __restrict__ W1,
    const _Float16* __restrict__ W2,
    const float* __restrict__ B0, const float* __restrict__ B1,
    const float* __restrict__ B2)
{
    _Float16* Sw = waveS() + (tid>>6)*4096;
    const int l = tid & 63, mrow = l & 15, g = (l >> 4) & 3;

    // ---- L0: K=64 (2 ksteps), N=32 ----
    {
        half8 a[4][2], b[2][2];
#pragma unroll
        for (int t=0;t<4;++t){
            int r = 16*t + mrow;
#pragma unroll
            for (int s=0;s<2;++s)
                a[t][s] = *(const half8*)(Sw + r*64 + (((4*s+g) ^ (r&7))<<3));
        }
#pragma unroll
        for (int n=0;n<2;++n)
#pragma unroll
            for (int s=0;s<2;++s)
                b[n][s] = *(const half8*)(W0 + (16*n+mrow)*64 + 32*s + 8*g);
        float bv0 = B0[mrow], bv1 = B0[16+mrow];
#pragma unroll
        for (int n=0;n<2;++n){
            float bb = n ? bv1 : bv0;
            int cc = 16*n + mrow;
#pragma unroll
            for (int t=0;t<4;++t){
                float4v acc = {bb,bb,bb,bb};
                acc = __builtin_amdgcn_mfma_f32_16x16x32_f16(a[t][0], b[n][0], acc, 0,0,0);
                acc = __builtin_amdgcn_mfma_f32_16x16x32_f16(a[t][1], b[n][1], acc, 0,0,0);
#pragma unroll
                for (int j=0;j<4;++j){
                    int r = 16*t + 4*g + j;
                    Sw[r*64 + (((cc>>3) ^ (r&7))<<3) + (cc&7)] = (_Float16)lrelu(acc[j]);
                }
            }
        }
    }
    __threadfence_block();
    // ---- L1: K=32, N=32 ----
    {
        half8 a1[4], b1f[2];
#pragma unroll
        for (int t=0;t<4;++t){ int r = 16*t + mrow; a1[t] = *(const half8*)(Sw + r*64 + ((g ^ (r&7))<<3)); }
#pragma unroll
        for (int n=0;n<2;++n) b1f[n] = *(const half8*)(W1 + (16*n+mrow)*32 + 8*g);
        float cv0 = B1[mrow], cv1 = B1[16+mrow];
#pragma unroll
        for (int n=0;n<2;++n){
            float bb = n ? cv1 : cv0;
            int cc = 16*n + mrow;
#pragma unroll
            for (int t=0;t<4;++t){
                float4v acc = {bb,bb,bb,bb};
                acc = __builtin_amdgcn_mfma_f32_16x16x32_f16(a1[t], b1f[n], acc, 0,0,0);
#pragma unroll
                for (int j=0;j<4;++j){
                    int r = 16*t + 4*g + j;
                    Sw[r*64 + (((cc>>3) ^ (r&7))<<3) + (cc&7)] = (_Float16)lrelu(acc[j]);
                }
            }
        }
    }
    __threadfence_block();
    // ---- L2: K=32, N=64 (59 real) ----
    {
        half8 a2[4], b2f[4];
#pragma unroll
        for (int t=0;t<4;++t){ int r = 16*t + mrow; a2[t] = *(const half8*)(Sw + r*64 + ((g ^ (r&7))<<3)); }
#pragma unroll
        for (int n=0;n<4;++n) b2f[n] = *(const half8*)(W2 + (16*n+mrow)*32 + 8*g);
#pragma unroll
        for (int n=0;n<4;++n){
            int cc = 16*n + mrow;
            float bb = (cc < 59) ? B2[cc] : 0.0f;
#pragma unroll
            for (int t=0;t<4;++t){
                float4v acc = {bb,bb,bb,bb};
                acc = __builtin_amdgcn_mfma_f32_16x16x32_f16(a2[t], b2f[n], acc, 0,0,0);
#pragma unroll
                for (int j=0;j<4;++j){
                    int r = 16*t + 4*g + j;
                    Sw[r*64 + (((cc>>3) ^ (r&7))<<3) + (cc&7)] = (_Float16)acc[j];
                }
            }
        }
    }
    __threadfence_block();
}

// ---------- spline, emitted ONCE (noinline), reads params straight from LDS ----------
__device__ __noinline__ float2 rqs_lds(float x, int tid)
{
    const int l = tid & 63;
    const _Float16* rowp = waveS() + (tid>>6)*4096 + l*64;
    const int swz = l & 7;
    #define RD(u) (*(const half8*)(rowp + (((u)^swz)<<3)))

    float xc = fminf(fmaxf(x,-1.0f),1.0f);
    int idx = 0;
    float inCw = -1.0f, inW = 1.0f;
    {   // widths: elems 0..19
        half8 U0 = RD(0), U1 = RD(1), U2 = RD(2);
        float w[20];
#pragma unroll
        for (int i=0;i<8;++i) w[i]    = (float)U0[i];
#pragma unroll
        for (int i=0;i<8;++i) w[8+i]  = (float)U1[i];
#pragma unroll
        for (int i=0;i<4;++i) w[16+i] = (float)U2[i];
        float mw = w[0];
#pragma unroll
        for (int i=1;i<20;++i) mw = fmaxf(mw, w[i]);
        float sw = 0.f;
#pragma unroll
        for (int i=0;i<20;++i){ w[i] = __expf(w[i]-mw); sw += w[i]; }
        float invw = 0.98f / sw;
        float cum = 0.f;
#pragma unroll
        for (int i=0;i<20;++i){
            float wv = fmaf(invw, w[i], 0.001f);
            float cwL = (i==0) ? -1.0f : fmaf(2.0f, cum, -1.0f);
            float cumN = cum + wv;
            float cwR = (i==19) ? 1.0f : fmaf(2.0f, cumN, -1.0f);
            if (xc >= cwL){ idx = i; inCw = cwL; inW = cwR - cwL; }
            cum = cumN;
        }
    }
    float inCh = -1.0f, inH = 1.0f;
    {   // heights: elems 20..39
        half8 U2 = RD(2), U3 = RD(3), U4 = RD(4);
        float h[20];
#pragma unroll
        for (int i=0;i<4;++i) h[i]    = (float)U2[4+i];
#pragma unroll
        for (int i=0;i<8;++i) h[4+i]  = (float)U3[i];
#pragma unroll
        for (int i=0;i<8;++i) h[12+i] = (float)U4[i];
        float mh = h[0];
#pragma unroll
        for (int i=1;i<20;++i) mh = fmaxf(mh, h[i]);
        float sh = 0.f;
#pragma unroll
        for (int i=0;i<20;++i){ h[i] = __expf(h[i]-mh); sh += h[i]; }
        float invh = 0.98f / sh;
        float hcum = 0.f;
#pragma unroll
        for (int i=0;i<20;++i){
            float hv = fmaf(invh, h[i], 0.001f);
            float chL = (i==0) ? -1.0f : fmaf(2.0f, hcum, -1.0f);
            float hcumN = hcum + hv;
            float chR = (i==19) ? 1.0f : fmaf(2.0f, hcumN, -1.0f);
            if (i == idx){ inCh = chL; inH = chR - chL; }
            hcum = hcumN;
        }
    }
    float udl = TAILC, udr = TAILC;
    {   // derivatives: elems 40..58
        half8 U5 = RD(5), U6 = RD(6), U7 = RD(7);
#pragma unroll
        for (int t=0;t<19;++t){
            float v = (t<8) ? (float)U5[t] : (t<16) ? (float)U6[t-8] : (float)U7[t-16];
            if (idx == t+1) udl = v;
            if (idx == t)   udr = v;
        }
    }
    #undef RD
    float inD   = 0.001f + softplus_(udl);
    float inDp1 = 0.001f + softplus_(udr);
    float inDelta = inH / inW;
    float th  = (xc - inCw) / inW;
    float omt = 1.0f - th;
    float t1  = th * omt;
    float num = inH * (inDelta*th*th + inD*t1);
    float den = inDelta + (inD + inDp1 - 2.0f*inDelta)*t1;
    float y = inCh + num/den;
    float dnum = inDelta*inDelta*(inDp1*th*th + 2.0f*inDelta*t1 + inD*omt*omt);
    float lad = __logf(dnum) - 2.0f*__logf(den);
    bool inside = (x >= -1.0f) && (x <= 1.0f);
    return make_float2(inside ? y : x, inside ? lad : 0.0f);
}

__global__ __launch_bounds__(256,3) void nsf_mfma(
    const float* __restrict__ wi, const float* __restrict__ cond,
    const _Float16* __restrict__ wsp,
    const float* __restrict__ p0_w1, const float* __restrict__ p0_b0, const float* __restrict__ p0_b1,
    const float* __restrict__ m1_b0, const float* __restrict__ m1_b1, const float* __restrict__ m1_b2,
    const float* __restrict__ m0_b0, const float* __restrict__ m0_b1, const float* __restrict__ m0_b2,
    float* __restrict__ out)
{
    const int tid = threadIdx.x;
    const int l = tid & 63, wid = tid >> 6;
    const int i = blockIdx.x*256 + wid*64 + l;
    _Float16* Sw = waveS() + wid*4096;
    const int mrow = l & 15, g = (l >> 4) & 3;

    auto stu = [&](int u, half8 v){
        *(half8*)(Sw + l*64 + ((u ^ (l&7))<<3)) = v;
    };

    float2 wv2 = reinterpret_cast<const float2*>(wi)[i];
    float w0v = wv2.x, w1v = wv2.y;
    float c[10];
    {
        const float2* cp2 = reinterpret_cast<const float2*>(cond + (size_t)i*10);
#pragma unroll
        for (int k=0;k<5;++k){ float2 t2 = cp2[k]; c[2*k]=t2.x; c[2*k+1]=t2.y; }
    }

    // cond_e -> f16 chunks A0..A3 (cols 0..31, incl. 2 zero pads)
    half8 A0, A1, A2, A3, Z;
#pragma unroll
    for (int j=0;j<8;++j) Z[j] = (_Float16)0.0f;
    {
        _Float16 ce[30];
        ce[0] = (_Float16)c[8];
        ce[1] = (_Float16)c[9];
        float f = 1.0f;
#pragma unroll
        for (int fi=0; fi<5; ++fi){
            float s8,c8v,s9,c9v;
            __sincosf(c[8]*f, &s8, &c8v);
            __sincosf(c[9]*f, &s9, &c9v);
            ce[2+4*fi+0]=(_Float16)s8;  ce[2+4*fi+1]=(_Float16)s9;
            ce[2+4*fi+2]=(_Float16)c8v; ce[2+4*fi+3]=(_Float16)c9v;
            f *= 2.0f;
        }
#pragma unroll
        for (int k=0;k<8;++k) ce[22+k] = (_Float16)c[k];
#pragma unroll
        for (int j=0;j<8;++j){ A0[j]=ce[j]; A1[j]=ce[8+j]; A2[j]=ce[16+j]; }
#pragma unroll
        for (int j=0;j<8;++j) A3[j] = (j<6) ? ce[24+j] : (_Float16)0.0f;
    }

    auto mkPE = [&](float t, half8& P0, half8& P1){
        float s1,c1v,s2,c2v,s3,c3v,s4,c4v;
        __sincosf(t*1.0f,       &s1,&c1v);
        __sincosf(t*3.3333333f, &s2,&c2v);
        __sincosf(t*5.6666665f, &s3,&c3v);
        __sincosf(t*8.0f,       &s4,&c4v);
        P0[0]=(_Float16)t;   P0[1]=(_Float16)s1; P0[2]=(_Float16)c1v; P0[3]=(_Float16)s2;
        P0[4]=(_Float16)c2v; P0[5]=(_Float16)s3; P0[6]=(_Float16)c3v; P0[7]=(_Float16)s4;
        P1 = Z; P1[0] = (_Float16)c4v;
    };

    // ---- m1: stage xin(w1v), MLP, spline on w0 ----
    half8 P0, P1;
    mkPE(w1v, P0, P1);
    stu(0,A0); stu(1,A1); stu(2,A2); stu(3,A3);
    stu(4,P0); stu(5,P1); stu(6,Z);  stu(7,Z);
    __threadfence_block();
    mlp_lds(tid, wsp+OFF_M1_W0T, wsp+OFF_M1_W1T, wsp+OFF_M1_W2T, m1_b0, m1_b1, m1_b2);
    float2 r0 = rqs_lds(w0v, tid);
    float y0 = r0.x, ld0 = r0.y;

    // ---- m0: stage xin(y0), MLP, spline on w1 ----
    mkPE(y0, P0, P1);
    stu(0,A0); stu(1,A1); stu(2,A2); stu(3,A3);
    stu(4,P0); stu(5,P1); stu(6,Z);  stu(7,Z);
    __threadfence_block();
    mlp_lds(tid, wsp+OFF_M0_W0T, wsp+OFF_M0_W1T, wsp+OFF_M0_W2T, m0_b0, m0_b1, m0_b2);
    float2 r1 = rqs_lds(w1v, tid);
    float y1 = r1.x, ld1 = r1.y;

    // ---- p0: cond_e(30,+2pad) -> 32 (lrelu) via MFMA, then per-thread 32->4 ----
    stu(0,A0); stu(1,A1); stu(2,A2); stu(3,A3);
    __threadfence_block();
    {
        half8 ap[4], bp[2];
#pragma unroll
        for (int t=0;t<4;++t){ int r = 16*t + mrow; ap[t] = *(const half8*)(Sw + r*64 + ((g ^ (r&7))<<3)); }
#pragma unroll
        for (int n=0;n<2;++n) bp[n] = *(const half8*)(wsp + OFF_P0_W0T + (16*n+mrow)*32 + 8*g);
        float pb0 = p0_b0[mrow], pb1 = p0_b0[16+mrow];
#pragma unroll
        for (int n=0;n<2;++n){
            float bb = n ? pb1 : pb0;
            int cc = 16*n + mrow;
#pragma unroll
            for (int t=0;t<4;++t){
                float4v acc = {bb,bb,bb,bb};
                acc = __builtin_amdgcn_mfma_f32_16x16x32_f16(ap[t], bp[n], acc, 0,0,0);
#pragma unroll
                for (int j=0;j<4;++j){
                    int r = 16*t + 4*g + j;
                    Sw[r*64 + (((cc>>3) ^ (r&7))<<3) + (cc&7)] = (_Float16)lrelu(acc[j]);
                }
            }
        }
    }
    __threadfence_block();

    float r4[4] = {p0_b1[0], p0_b1[1], p0_b1[2], p0_b1[3]};
    {
        half8 Tq[4];
#pragma unroll
        for (int u=0;u<4;++u) Tq[u] = *(const half8*)(Sw + l*64 + ((u ^ (l&7))<<3));
#pragma unroll
        for (int k=0;k<32;++k){
            float pv = (float)Tq[k>>3][k&7];
#pragma unroll
            for (int j=0;j<4;++j) r4[j] = fmaf(pv, p0_w1[k*4+j], r4[j]);
        }
    }

    float mu0=r4[0], mu1=r4[1], ls0=r4[2], ls1=r4[3];
    float is0 = __expf(-ls0), is1 = __expf(-ls1);
    float e0 = (y0-mu0)*is0, e1 = (y1-mu1)*is1;
    float rr = e0*e0 + e1*e1;
    float lp = -(ls0+ls1) - 1.8378770664093453f - 0.5f*rr + ld0 + ld1;

    reinterpret_cast<float2*>(out)[i] = make_float2(y0, y1);
    out[2*(size_t)N_PTS + i] = lp;
}

// ---------------- fallback all-f32 kernel (known-good R1) ----------------
__device__ __forceinline__ void rqs_f32(float x, float* tp, float& yo, float& lado)
{
    float mw = tp[0];
#pragma unroll
    for (int i=1;i<20;++i) mw = fmaxf(mw, tp[i]);
    float sw = 0.f;
#pragma unroll
    for (int i=0;i<20;++i){ tp[i] = __expf(tp[i]-mw); sw += tp[i]; }
    float invw = 0.98f / sw;
    float mh = tp[20];
#pragma unroll
    for (int i=1;i<20;++i) mh = fmaxf(mh, tp[20+i]);
    float sh = 0.f;
#pragma unroll
    for (int i=0;i<20;++i){ tp[20+i] = __expf(tp[20+i]-mh); sh += tp[20+i]; }
    float invh = 0.98f / sh;
    float xc = fminf(fmaxf(x,-1.0f),1.0f);
    float cum = 0.f; int idx = 0;
    float inCw = -1.0f, inW = 1.0f;
#pragma unroll
    for (int i=0;i<20;++i){
        float wv = fmaf(invw, tp[i], 0.001f);
        float cwL = (i==0) ? -1.0f : fmaf(2.0f, cum, -1.0f);
        float cumN = cum + wv;
        float cwR = (i==19) ? 1.0f : fmaf(2.0f, cumN, -1.0f);
        if (xc >= cwL){ idx = i; inCw = cwL; inW = cwR - cwL; }
        cum = cumN;
    }
    float hcum = 0.f; float inCh = -1.0f, inH = 1.0f;
#pragma unroll
    for (int i=0;i<20;++i){
        float hv = fmaf(invh, tp[20+i], 0.001f);
        float chL = (i==0) ? -1.0f : fmaf(2.0f, hcum, -1.0f);
        float hcumN = hcum + hv;
        float chR = (i==19) ? 1.0f : fmaf(2.0f, hcumN, -1.0f);
        if (i == idx){ inCh = chL; inH = chR - chL; }
        hcum = hcumN;
    }
    float udl = TAILC, udr = TAILC;
#pragma unroll
    for (int t=0;t<19;++t){
        if (idx == t+1) udl = tp[40+t];
        if (idx == t)   udr = tp[40+t];
    }
    float inD   = 0.001f + softplus_(udl);
    float inDp1 = 0.001f + softplus_(udr);
    float inDelta = inH / inW;
    float th  = (xc - inCw) / inW;
    float omt = 1.0f - th;
    float t1  = th * omt;
    float num = inH * (inDelta*th*th + inD*t1);
    float den = inDelta + (inD + inDp1 - 2.0f*inDelta)*t1;
    float y = inCh + num/den;
    float dnum = inDelta*inDelta*(inDp1*th*th + 2.0f*inDelta*t1 + inD*omt*omt);
    float lad = __logf(dnum) - 2.0f*__logf(den);
    bool inside = (x >= -1.0f) && (x <= 1.0f);
    yo   = inside ? y   : x;
    lado = inside ? lad : 0.0f;
}
template<int OUTW>
__device__ __forceinline__ void addrow(float v, const float* __restrict__ Wrow, float* acc){
#pragma unroll
    for (int j=0;j<OUTW;++j) acc[j] = fmaf(v, Wrow[j], acc[j]);
}
template<int KIN, int OUT>
__device__ __forceinline__ void dense(const float* x, const float* __restrict__ W,
        const float* __restrict__ B, float* acc){
#pragma unroll
    for (int j=0;j<OUT;++j) acc[j] = B[j];
#pragma unroll
    for (int k=0;k<KIN;++k){
#pragma unroll
        for (int j=0;j<OUT;++j) acc[j] = fmaf(x[k], W[k*OUT+j], acc[j]);
    }
}
__device__ __forceinline__ void mlp_layer0(float t, const float* c,
        const float* __restrict__ W0, const float* __restrict__ B0, float* h)
{
#pragma unroll
    for (int j=0;j<32;++j) h[j] = B0[j];
    addrow<32>(t, W0 + 0*32, h);
    float s, co;
    __sincosf(t*1.0f,       &s,&co); addrow<32>(s, W0+1*32, h); addrow<32>(co, W0+2*32, h);
    __sincosf(t*3.3333333f, &s,&co); addrow<32>(s, W0+3*32, h); addrow<32>(co, W0+4*32, h);
    __sincosf(t*5.6666665f, &s,&co); addrow<32>(s, W0+5*32, h); addrow<32>(co, W0+6*32, h);
    __sincosf(t*8.0f,       &s,&co); addrow<32>(s, W0+7*32, h); addrow<32>(co, W0+8*32, h);
    addrow<32>(c[8], W0 + 9*32, h);
    addrow<32>(c[9], W0 +10*32, h);
    float f = 1.0f;
#pragma unroll
    for (int fi=0; fi<5; ++fi){
        float s8,c8v,s9,c9v;
        __sincosf(c[8]*f, &s8, &c8v);
        __sincosf(c[9]*f, &s9, &c9v);
        addrow<32>(s8,  W0 + (11+4*fi)*32, h);
        addrow<32>(s9,  W0 + (12+4*fi)*32, h);
        addrow<32>(c8v, W0 + (13+4*fi)*32, h);
        addrow<32>(c9v, W0 + (14+4*fi)*32, h);
        f *= 2.0f;
    }
#pragma unroll
    for (int k=0;k<8;++k) addrow<32>(c[k], W0 + (31+k)*32, h);
#pragma unroll
    for (int j=0;j<32;++j) h[j] = lrelu(h[j]);
}
__global__ __launch_bounds__(256,3) void nsf_kernel_f32(
    const float* __restrict__ wi, const float* __restrict__ cond,
    const float* __restrict__ p0_w0, const float* __restrict__ p0_b0,
    const float* __restrict__ p0_w1, const float* __restrict__ p0_b1,
    const float* __restrict__ m1_w0, const float* __restrict__ m1_b0,
    const float* __restrict__ m1_w1, const float* __restrict__ m1_b1,
    const float* __restrict__ m1_w2, const float* __restrict__ m1_b2,
    const float* __restrict__ m0_w0, const float* __restrict__ m0_b0,
    const float* __restrict__ m0_w1, const float* __restrict__ m0_b1,
    const float* __restrict__ m0_w2, const float* __restrict__ m0_b2,
    float* __restrict__ out)
{
    const int i = blockIdx.x*256 + threadIdx.x;
    float2 wv2 = reinterpret_cast<const float2*>(wi)[i];
    float w0v = wv2.x, w1v = wv2.y;
    const float* cp = cond + (size_t)i*10;
    float c[10];
#pragma unroll
    for (int k=0;k<10;++k) c[k] = cp[k];

    float tp[59];
    {
        float h[32], gg[32];
        mlp_layer0(w1v, c, m1_w0, m1_b0, h);
        dense<32,32>(h, m1_w1, m1_b1, gg);
#pragma unroll
        for (int j=0;j<32;++j) gg[j] = lrelu(gg[j]);
        dense<32,59>(gg, m1_w2, m1_b2, tp);
    }
    float y0, ld0; rqs_f32(w0v, tp, y0, ld0);
    {
        float h[32], gg[32];
        mlp_layer0(y0, c, m0_w0, m0_b0, h);
        dense<32,32>(h, m0_w1, m0_b1, gg);
#pragma unroll
        for (int j=0;j<32;++j) gg[j] = lrelu(gg[j]);
        dense<32,59>(gg, m0_w2, m0_b2, tp);
    }
    float y1, ld1; rqs_f32(w1v, tp, y1, ld1);

    float r[4];
    {
        float ph[32];
#pragma unroll
        for (int j=0;j<32;++j) ph[j] = p0_b0[j];
        addrow<32>(c[8], p0_w0 + 0*32, ph);
        addrow<32>(c[9], p0_w0 + 1*32, ph);
        float f = 1.0f;
#pragma unroll
        for (int fi=0; fi<5; ++fi){
            float s8,c8v,s9,c9v;
            __sincosf(c[8]*f, &s8, &c8v);
            __sincosf(c[9]*f, &s9, &c9v);
            addrow<32>(s8,  p0_w0 + (2+4*fi)*32, ph);
            addrow<32>(s9,  p0_w0 + (3+4*fi)*32, ph);
            addrow<32>(c8v, p0_w0 + (4+4*fi)*32, ph);
            addrow<32>(c9v, p0_w0 + (5+4*fi)*32, ph);
            f *= 2.0f;
        }
#pragma unroll
        for (int k=0;k<8;++k) addrow<32>(c[k], p0_w0 + (22+k)*32, ph);
#pragma unroll
        for (int j=0;j<32;++j) ph[j] = lrelu(ph[j]);
        dense<32,4>(ph, p0_w1, p0_b1, r);
    }

    float mu0=r[0], mu1=r[1], ls0=r[2], ls1=r[3];
    float is0 = __expf(-ls0), is1 = __expf(-ls1);
    float e0 = (y0-mu0)*is0, e1 = (y1-mu1)*is1;
    float rr = e0*e0 + e1*e1;
    float lp = -(ls0+ls1) - 1.8378770664093453f - 0.5f*rr + ld0 + ld1;

    reinterpret_cast<float2*>(out)[i] = make_float2(y0, y1);
    out[2*(size_t)N_PTS + i] = lp;
}

extern "C" void kernel_launch(void* const* d_in, const int* in_sizes, int n_in,
                              void* d_out, int out_size, void* d_ws, size_t ws_size,
                              hipStream_t stream)
{
    const float* wi    = (const float*)d_in[0];
    const float* cond  = (const float*)d_in[1];
    const float* p0_w0 = (const float*)d_in[2];
    const float* p0_b0 = (const float*)d_in[3];
    const float* p0_w1 = (const float*)d_in[4];
    const float* p0_b1 = (const float*)d_in[5];
    const float* m1_w0 = (const float*)d_in[6];
    const float* m1_b0 = (const float*)d_in[7];
    const float* m1_w1 = (const float*)d_in[8];
    const float* m1_b1 = (const float*)d_in[9];
    const float* m1_w2 = (const float*)d_in[10];
    const float* m1_b2 = (const float*)d_in[11];
    const float* m0_w0 = (const float*)d_in[12];
    const float* m0_b0 = (const float*)d_in[13];
    const float* m0_w1 = (const float*)d_in[14];
    const float* m0_b1 = (const float*)d_in[15];
    const float* m0_w2 = (const float*)d_in[16];
    const float* m0_b2 = (const float*)d_in[17];
    float* out = (float*)d_out;

    dim3 block(256);
    if (ws_size >= (size_t)WS_F16 * sizeof(_Float16)) {
        _Float16* wsp = (_Float16*)d_ws;
        hipLaunchKernelGGL(pack_weights, dim3((WS_F16+255)/256), block, 0, stream,
            m1_w0, m1_w1, m1_w2, m0_w0, m0_w1, m0_w2, p0_w0, wsp);
        hipLaunchKernelGGL(nsf_mfma, dim3(N_PTS/256), block, 0, stream,
            wi, cond, wsp, p0_w1, p0_b0, p0_b1,
            m1_b0, m1_b1, m1_b2, m0_b0, m0_b1, m0_b2, out);
    } else {
        hipLaunchKernelGGL(nsf_kernel_f32, dim3(N_PTS/256), block, 0, stream,
            wi, cond, p0_w0, p0_b0, p0_w1, p0_b1,
            m1_w0, m1_b0, m1_w1, m1_b1, m1_w2, m1_b2,
            m0_w0, m0_b0, m0_w1, m0_b1, m0_w2, m0_b2, out);
    }
}

// Round 8
// 166.781 us; speedup vs baseline: 4.4004x; 1.4028x over previous
//
#include <hip/hip_runtime.h>
#include <math.h>

#define N_PTS 2097152
#define TAILC 0.53974324f   // log(exp(1-0.001)-1)

typedef unsigned int u32;
typedef _Float16 half8 __attribute__((ext_vector_type(8)));
typedef _Float16 half4 __attribute__((ext_vector_type(4)));
typedef _Float16 h2    __attribute__((ext_vector_type(2)));
typedef __fp16   fp16x2 __attribute__((ext_vector_type(2)));
typedef float float4v  __attribute__((ext_vector_type(4)));

#define MFMA16 __builtin_amdgcn_mfma_f32_16x16x32_f16

__device__ __forceinline__ float lrelu(float x){ return x > 0.0f ? x : 0.01f*x; }
__device__ __forceinline__ float softplus_(float x){
    return fmaxf(x, 0.0f) + log1pf(__expf(-fabsf(x)));
}
__device__ __forceinline__ half4 pack4(float a0, float a1, float a2, float a3){
#if __has_builtin(__builtin_amdgcn_cvt_pkrtz)
    union { fp16x2 f; h2 h; u32 u; } lo, hi;
    lo.f = __builtin_amdgcn_cvt_pkrtz(a0, a1);
    hi.f = __builtin_amdgcn_cvt_pkrtz(a2, a3);
    half4 r; r[0]=lo.h[0]; r[1]=lo.h[1]; r[2]=hi.h[0]; r[3]=hi.h[1];
    return r;
#else
    half4 r; r[0]=(_Float16)a0; r[1]=(_Float16)a1; r[2]=(_Float16)a2; r[3]=(_Float16)a3;
    return r;
#endif
}
__device__ __forceinline__ float fdot2(h2 a, h2 b, float c){
#if __has_builtin(__builtin_amdgcn_fdot2)
    return __builtin_amdgcn_fdot2(a, b, c, false);
#else
    return fmaf((float)a[0],(float)b[0], fmaf((float)a[1],(float)b[1], c));
#endif
}
__device__ __forceinline__ h2 u2h2(u32 u){ union{u32 a; h2 b;} x; x.a=u; return x.b; }

// Single shared allocation reachable from kernel AND noinline callees.
__device__ __forceinline__ _Float16* waveS(){
    __shared__ _Float16 S[4][4096];    // per-wave [64 rows][64 f16], swizzled
    return &S[0][0];
}
// 16B-unit swizzled b128 read; 8B-unit swizzled b64 write (consistent pair).
__device__ __forceinline__ half8 rd16(const _Float16* Sw, int row, int u){
    return *(const half8*)(Sw + row*64 + ((u ^ (row&7))<<3));
}
__device__ __forceinline__ void wr16(_Float16* Sw, int row, int u, half8 v){
    *(half8*)(Sw + row*64 + ((u ^ (row&7))<<3)) = v;
}
__device__ __forceinline__ void wr8(_Float16* Sw, int row, int v8, half4 v){
    *(half4*)(Sw + row*64 + ((v8 ^ ((row&7)<<1))<<2)) = v;
}

// ---- packed weights/biases in d_ws ----
// f16 region (transposed, zero-padded): WT[out][K].
// A-col mapping for L0: cols 0..29 = cond_e, 30..31 = 0, 32..40 = PE(t), 41..63 = 0.
#define OFF_M1_W0T 0        // [32][64]
#define OFF_M1_W1T 2048     // [32][32]
#define OFF_M1_W2T 3072     // [64][32]
#define OFF_M0_W0T 5120
#define OFF_M0_W1T 7168
#define OFF_M0_W2T 8192
#define OFF_P0_W0T 10240    // [32][32]
#define WS_F16     11264
// f32 region (starts at f16 offset WS_F16, byte 22528, 16B aligned)
#define FB_M1_B0   0
#define FB_M1_B1   32
#define FB_M1_B2   64       // padded to 64
#define FB_M0_B0   128
#define FB_M0_B1   160
#define FB_M0_B2   192      // padded to 64
#define FB_P0_B0   256
#define FB_PW1     288      // 64 u32: p0_w1 packed h2 pairs
#define WS_BYTES   (22528 + 288*4 + 64*4)
#define PACK_ITEMS (WS_F16 + 288 + 64)

__global__ void pack_weights(const float* __restrict__ m1_w0, const float* __restrict__ m1_w1,
                             const float* __restrict__ m1_w2, const float* __restrict__ m0_w0,
                             const float* __restrict__ m0_w1, const float* __restrict__ m0_w2,
                             const float* __restrict__ p0_w0, const float* __restrict__ p0_w1,
                             const float* __restrict__ m1_b0, const float* __restrict__ m1_b1,
                             const float* __restrict__ m1_b2, const float* __restrict__ m0_b0,
                             const float* __restrict__ m0_b1, const float* __restrict__ m0_b2,
                             const float* __restrict__ p0_b0, _Float16* __restrict__ ws)
{
    int idx = blockIdx.x*256 + threadIdx.x;
    if (idx >= PACK_ITEMS) return;
    if (idx < WS_F16) {
        float v = 0.0f;
        if (idx < 2048 || (idx >= 5120 && idx < 7168)) {          // W0T [32][64]
            const float* W = (idx < 2048) ? m1_w0 : m0_w0;
            int r = (idx < 2048) ? idx : idx - 5120;
            int o = r >> 6, k = r & 63;
            if (k < 30)                 v = W[(9+k)*32 + o];
            else if (k >= 32 && k < 41) v = W[(k-32)*32 + o];
        } else if (idx < 3072 || (idx >= 7168 && idx < 8192)) {   // W1T [32][32]
            const float* W = (idx < 3072) ? m1_w1 : m0_w1;
            int r = (idx < 3072) ? idx - 2048 : idx - 7168;
            int o = r >> 5, k = r & 31;
            v = W[k*32 + o];
        } else if (idx < 5120 || (idx >= 8192 && idx < 10240)) {  // W2T [64][32]
            const float* W = (idx < 5120) ? m1_w2 : m0_w2;
            int r = (idx < 5120) ? idx - 3072 : idx - 8192;
            int o = r >> 5, k = r & 31;
            if (o < 59) v = W[k*59 + o];
        } else {                                                  // p0 W0T [32][32]
            int r = idx - 10240;
            int o = r >> 5, k = r & 31;
            if (k < 30) v = p0_w0[k*32 + o];
        }
        ws[idx] = (_Float16)v;
        return;
    }
    float* wsf = (float*)(ws + WS_F16);
    int bi = idx - WS_F16;
    if (bi < 288) {
        float v = 0.0f;
        if      (bi < 32)  v = m1_b0[bi];
        else if (bi < 64)  v = m1_b1[bi-32];
        else if (bi < 128) { int o = bi-64;  if (o < 59) v = m1_b2[o]; }
        else if (bi < 160) v = m0_b0[bi-128];
        else if (bi < 192) v = m0_b1[bi-160];
        else if (bi < 256) { int o = bi-192; if (o < 59) v = m0_b2[o]; }
        else               v = p0_b0[bi-256];
        wsf[bi] = v;
        return;
    }
    int pi = bi - 288;            // 0..63 : p0_w1 packed pairs
    int k2 = pi >> 2, j = pi & 3;
    union{ _Float16 h; unsigned short s; } a, b;
    a.h = (_Float16)p0_w1[(2*k2)*4 + j];
    b.h = (_Float16)p0_w1[(2*k2+1)*4 + j];
    ((u32*)(wsf + FB_PW1))[pi] = (u32)a.s | ((u32)b.s << 16);
}

// ---------- one transform MLP (noinline, emitted once), swapped-operand MFMA ----------
// D = W^T x H : A = weight fragments (global), B = activation tile (LDS),
// C/D: col = point (l&15), row = output (4g+j)  ->  b64 vectorized C-writes.
__device__ __noinline__ void mlp_lds(int tid,
    const _Float16* __restrict__ W0, const _Float16* __restrict__ W1,
    const _Float16* __restrict__ W2,
    const float* __restrict__ B0p, const float* __restrict__ B1p,
    const float* __restrict__ B2p)
{
    _Float16* Sw = waveS() + (tid>>6)*4096;
    const int l = tid & 63, mrow = l & 15, g = (l >> 4) & 3;

    // ---- L0: K=64 (2 ksteps), OUT=32 ----
    {
        half8 aW[2][2], bX[4][2];
#pragma unroll
        for (int n=0;n<2;++n)
#pragma unroll
            for (int s=0;s<2;++s)
                aW[n][s] = *(const half8*)(W0 + (16*n+mrow)*64 + 32*s + 8*g);
#pragma unroll
        for (int t=0;t<4;++t){
            int pt = 16*t + mrow;
#pragma unroll
            for (int s=0;s<2;++s) bX[t][s] = rd16(Sw, pt, 4*s+g);
        }
#pragma unroll
        for (int n=0;n<2;++n){
            float4v bb = *(const float4v*)(B0p + 16*n + 4*g);
#pragma unroll
            for (int t=0;t<4;++t){
                float4v acc = bb;
                acc = MFMA16(aW[n][0], bX[t][0], acc, 0,0,0);
                acc = MFMA16(aW[n][1], bX[t][1], acc, 0,0,0);
                wr8(Sw, 16*t+mrow, 4*n+g,
                    pack4(lrelu(acc[0]), lrelu(acc[1]), lrelu(acc[2]), lrelu(acc[3])));
            }
        }
    }
    __threadfence_block();
    // ---- L1: K=32, OUT=32 ----
    {
        half8 aW[2], bH[4];
#pragma unroll
        for (int n=0;n<2;++n) aW[n] = *(const half8*)(W1 + (16*n+mrow)*32 + 8*g);
#pragma unroll
        for (int t=0;t<4;++t) bH[t] = rd16(Sw, 16*t+mrow, g);
#pragma unroll
        for (int n=0;n<2;++n){
            float4v bb = *(const float4v*)(B1p + 16*n + 4*g);
#pragma unroll
            for (int t=0;t<4;++t){
                float4v acc = bb;
                acc = MFMA16(aW[n], bH[t], acc, 0,0,0);
                wr8(Sw, 16*t+mrow, 4*n+g,
                    pack4(lrelu(acc[0]), lrelu(acc[1]), lrelu(acc[2]), lrelu(acc[3])));
            }
        }
    }
    __threadfence_block();
    // ---- L2: K=32, OUT=64 (59 real), no activation ----
    {
        half8 aW[4], bH[4];
#pragma unroll
        for (int n=0;n<4;++n) aW[n] = *(const half8*)(W2 + (16*n+mrow)*32 + 8*g);
#pragma unroll
        for (int t=0;t<4;++t) bH[t] = rd16(Sw, 16*t+mrow, g);
#pragma unroll
        for (int n=0;n<4;++n){
            float4v bb = *(const float4v*)(B2p + 16*n + 4*g);
#pragma unroll
            for (int t=0;t<4;++t){
                float4v acc = bb;
                acc = MFMA16(aW[n], bH[t], acc, 0,0,0);
                wr8(Sw, 16*t+mrow, 4*n+g, pack4(acc[0], acc[1], acc[2], acc[3]));
            }
        }
    }
    __threadfence_block();
}

// ---------- spline (noinline, emitted once), reads params straight from LDS ----------
__device__ __noinline__ float2 rqs_lds(float x, int tid)
{
    const int l = tid & 63;
    const _Float16* Sw = waveS() + (tid>>6)*4096;

    float xc = fminf(fmaxf(x,-1.0f),1.0f);
    int idx = 0;
    float inCw = -1.0f, inW = 1.0f;
    {   // widths: elems 0..19
        half8 U0 = rd16(Sw,l,0), U1 = rd16(Sw,l,1), U2 = rd16(Sw,l,2);
        float w[20];
#pragma unroll
        for (int i=0;i<8;++i) w[i]    = (float)U0[i];
#pragma unroll
        for (int i=0;i<8;++i) w[8+i]  = (float)U1[i];
#pragma unroll
        for (int i=0;i<4;++i) w[16+i] = (float)U2[i];
        float mw = w[0];
#pragma unroll
        for (int i=1;i<20;++i) mw = fmaxf(mw, w[i]);
        float sw = 0.f;
#pragma unroll
        for (int i=0;i<20;++i){ w[i] = __expf(w[i]-mw); sw += w[i]; }
        float invw = 0.98f / sw;
        float cum = 0.f;
#pragma unroll
        for (int i=0;i<20;++i){
            float wv = fmaf(invw, w[i], 0.001f);
            float cwL = (i==0) ? -1.0f : fmaf(2.0f, cum, -1.0f);
            float cumN = cum + wv;
            float cwR = (i==19) ? 1.0f : fmaf(2.0f, cumN, -1.0f);
            if (xc >= cwL){ idx = i; inCw = cwL; inW = cwR - cwL; }
            cum = cumN;
        }
    }
    float inCh = -1.0f, inH = 1.0f;
    {   // heights: elems 20..39
        half8 U2 = rd16(Sw,l,2), U3 = rd16(Sw,l,3), U4 = rd16(Sw,l,4);
        float h[20];
#pragma unroll
        for (int i=0;i<4;++i) h[i]    = (float)U2[4+i];
#pragma unroll
        for (int i=0;i<8;++i) h[4+i]  = (float)U3[i];
#pragma unroll
        for (int i=0;i<8;++i) h[12+i] = (float)U4[i];
        float mh = h[0];
#pragma unroll
        for (int i=1;i<20;++i) mh = fmaxf(mh, h[i]);
        float sh = 0.f;
#pragma unroll
        for (int i=0;i<20;++i){ h[i] = __expf(h[i]-mh); sh += h[i]; }
        float invh = 0.98f / sh;
        float hcum = 0.f;
#pragma unroll
        for (int i=0;i<20;++i){
            float hv = fmaf(invh, h[i], 0.001f);
            float chL = (i==0) ? -1.0f : fmaf(2.0f, hcum, -1.0f);
            float hcumN = hcum + hv;
            float chR = (i==19) ? 1.0f : fmaf(2.0f, hcumN, -1.0f);
            if (i == idx){ inCh = chL; inH = chR - chL; }
            hcum = hcumN;
        }
    }
    float udl = TAILC, udr = TAILC;
    {   // derivatives: elems 40..58
        half8 U5 = rd16(Sw,l,5), U6 = rd16(Sw,l,6), U7 = rd16(Sw,l,7);
#pragma unroll
        for (int t=0;t<19;++t){
            float v = (t<8) ? (float)U5[t] : (t<16) ? (float)U6[t-8] : (float)U7[t-16];
            if (idx == t+1) udl = v;
            if (idx == t)   udr = v;
        }
    }
    float inD   = 0.001f + softplus_(udl);
    float inDp1 = 0.001f + softplus_(udr);
    float inDelta = inH / inW;
    float th  = (xc - inCw) / inW;
    float omt = 1.0f - th;
    float t1  = th * omt;
    float num = inH * (inDelta*th*th + inD*t1);
    float den = inDelta + (inD + inDp1 - 2.0f*inDelta)*t1;
    float y = inCh + num/den;
    float dnum = inDelta*inDelta*(inDp1*th*th + 2.0f*inDelta*t1 + inD*omt*omt);
    float lad = __logf(dnum) - 2.0f*__logf(den);
    bool inside = (x >= -1.0f) && (x <= 1.0f);
    return make_float2(inside ? y : x, inside ? lad : 0.0f);
}

__global__ __launch_bounds__(256,4) void nsf_mfma(
    const float* __restrict__ wi, const float* __restrict__ cond,
    const _Float16* __restrict__ wsp,
    const float* __restrict__ p0_b1,
    float* __restrict__ out)
{
    const int tid = threadIdx.x;
    const int l = tid & 63, wid = tid >> 6;
    const int i = blockIdx.x*256 + wid*64 + l;
    _Float16* Sw = waveS() + wid*4096;
    const int mrow = l & 15, g = (l >> 4) & 3;
    const float* wsf = (const float*)(wsp + WS_F16);

    float2 wv2 = reinterpret_cast<const float2*>(wi)[i];
    float w0v = wv2.x, w1v = wv2.y;
    float c[10];
    {
        const float2* cp2 = reinterpret_cast<const float2*>(cond + (size_t)i*10);
#pragma unroll
        for (int k=0;k<5;++k){ float2 t2 = cp2[k]; c[2*k]=t2.x; c[2*k+1]=t2.y; }
    }

    // cond_e -> f16 chunks A0..A3 (cols 0..31, incl. 2 zero pads)
    half8 A0, A1, A2, A3, Z;
#pragma unroll
    for (int j=0;j<8;++j) Z[j] = (_Float16)0.0f;
    {
        _Float16 ce[30];
        ce[0] = (_Float16)c[8];
        ce[1] = (_Float16)c[9];
        float f = 1.0f;
#pragma unroll
        for (int fi=0; fi<5; ++fi){
            float s8,c8v,s9,c9v;
            __sincosf(c[8]*f, &s8, &c8v);
            __sincosf(c[9]*f, &s9, &c9v);
            ce[2+4*fi+0]=(_Float16)s8;  ce[2+4*fi+1]=(_Float16)s9;
            ce[2+4*fi+2]=(_Float16)c8v; ce[2+4*fi+3]=(_Float16)c9v;
            f *= 2.0f;
        }
#pragma unroll
        for (int k=0;k<8;++k) ce[22+k] = (_Float16)c[k];
#pragma unroll
        for (int j=0;j<8;++j){ A0[j]=ce[j]; A1[j]=ce[8+j]; A2[j]=ce[16+j]; }
#pragma unroll
        for (int j=0;j<8;++j) A3[j] = (j<6) ? ce[24+j] : (_Float16)0.0f;
    }

    auto mkPE = [&](float t, half8& P0, half8& P1){
        float s1,c1v,s2,c2v,s3,c3v,s4,c4v;
        __sincosf(t*1.0f,       &s1,&c1v);
        __sincosf(t*3.3333333f, &s2,&c2v);
        __sincosf(t*5.6666665f, &s3,&c3v);
        __sincosf(t*8.0f,       &s4,&c4v);
        P0[0]=(_Float16)t;   P0[1]=(_Float16)s1; P0[2]=(_Float16)c1v; P0[3]=(_Float16)s2;
        P0[4]=(_Float16)c2v; P0[5]=(_Float16)s3; P0[6]=(_Float16)c3v; P0[7]=(_Float16)s4;
        P1 = Z; P1[0] = (_Float16)c4v;
    };

    // ---- m1: stage xin(w1v), MLP, spline on w0 ----
    half8 P0, P1;
    mkPE(w1v, P0, P1);
    wr16(Sw,l,0,A0); wr16(Sw,l,1,A1); wr16(Sw,l,2,A2); wr16(Sw,l,3,A3);
    wr16(Sw,l,4,P0); wr16(Sw,l,5,P1); wr16(Sw,l,6,Z);  wr16(Sw,l,7,Z);
    __threadfence_block();
    mlp_lds(tid, wsp+OFF_M1_W0T, wsp+OFF_M1_W1T, wsp+OFF_M1_W2T,
            wsf+FB_M1_B0, wsf+FB_M1_B1, wsf+FB_M1_B2);
    float2 r0 = rqs_lds(w0v, tid);
    float y0 = r0.x, ld0 = r0.y;

    // ---- m0: stage xin(y0), MLP, spline on w1 ----
    mkPE(y0, P0, P1);
    wr16(Sw,l,0,A0); wr16(Sw,l,1,A1); wr16(Sw,l,2,A2); wr16(Sw,l,3,A3);
    wr16(Sw,l,4,P0); wr16(Sw,l,5,P1); wr16(Sw,l,6,Z);  wr16(Sw,l,7,Z);
    __threadfence_block();
    mlp_lds(tid, wsp+OFF_M0_W0T, wsp+OFF_M0_W1T, wsp+OFF_M0_W2T,
            wsf+FB_M0_B0, wsf+FB_M0_B1, wsf+FB_M0_B2);
    float2 r1 = rqs_lds(w1v, tid);
    float y1 = r1.x, ld1 = r1.y;

    // ---- p0: cond_e(30,+2pad) -> 32 (lrelu) via swapped MFMA ----
    wr16(Sw,l,0,A0); wr16(Sw,l,1,A1); wr16(Sw,l,2,A2); wr16(Sw,l,3,A3);
    __threadfence_block();
    {
        half8 aW[2], bC[4];
#pragma unroll
        for (int n=0;n<2;++n) aW[n] = *(const half8*)(wsp + OFF_P0_W0T + (16*n+mrow)*32 + 8*g);
#pragma unroll
        for (int t=0;t<4;++t) bC[t] = rd16(Sw, 16*t+mrow, g);
        const float* PB = wsf + FB_P0_B0;
#pragma unroll
        for (int n=0;n<2;++n){
            float4v bb = *(const float4v*)(PB + 16*n + 4*g);
#pragma unroll
            for (int t=0;t<4;++t){
                float4v acc = bb;
                acc = MFMA16(aW[n], bC[t], acc, 0,0,0);
                wr8(Sw, 16*t+mrow, 4*n+g,
                    pack4(lrelu(acc[0]), lrelu(acc[1]), lrelu(acc[2]), lrelu(acc[3])));
            }
        }
    }
    __threadfence_block();

    // ---- tail: per-thread 32 -> 4 via fdot2 on packed p0_w1 ----
    float r4[4] = {p0_b1[0], p0_b1[1], p0_b1[2], p0_b1[3]};
    {
        half8 Tq[4];
#pragma unroll
        for (int u=0;u<4;++u) Tq[u] = rd16(Sw, l, u);
        const u32* pw = (const u32*)(wsf + FB_PW1);
#pragma unroll
        for (int k2=0;k2<16;++k2){
            h2 x; x[0] = Tq[k2>>2][2*(k2&3)]; x[1] = Tq[k2>>2][2*(k2&3)+1];
#pragma unroll
            for (int j=0;j<4;++j) r4[j] = fdot2(x, u2h2(pw[k2*4+j]), r4[j]);
        }
    }

    float mu0=r4[0], mu1=r4[1], ls0=r4[2], ls1=r4[3];
    float is0 = __expf(-ls0), is1 = __expf(-ls1);
    float e0 = (y0-mu0)*is0, e1 = (y1-mu1)*is1;
    float rr = e0*e0 + e1*e1;
    float lp = -(ls0+ls1) - 1.8378770664093453f - 0.5f*rr + ld0 + ld1;

    reinterpret_cast<float2*>(out)[i] = make_float2(y0, y1);
    out[2*(size_t)N_PTS + i] = lp;
}

// ---------------- fallback all-f32 kernel (known-good R1) ----------------
__device__ __forceinline__ void rqs_f32(float x, float* tp, float& yo, float& lado)
{
    float mw = tp[0];
#pragma unroll
    for (int i=1;i<20;++i) mw = fmaxf(mw, tp[i]);
    float sw = 0.f;
#pragma unroll
    for (int i=0;i<20;++i){ tp[i] = __expf(tp[i]-mw); sw += tp[i]; }
    float invw = 0.98f / sw;
    float mh = tp[20];
#pragma unroll
    for (int i=1;i<20;++i) mh = fmaxf(mh, tp[20+i]);
    float sh = 0.f;
#pragma unroll
    for (int i=0;i<20;++i){ tp[20+i] = __expf(tp[20+i]-mh); sh += tp[20+i]; }
    float invh = 0.98f / sh;
    float xc = fminf(fmaxf(x,-1.0f),1.0f);
    float cum = 0.f; int idx = 0;
    float inCw = -1.0f, inW = 1.0f;
#pragma unroll
    for (int i=0;i<20;++i){
        float wv = fmaf(invw, tp[i], 0.001f);
        float cwL = (i==0) ? -1.0f : fmaf(2.0f, cum, -1.0f);
        float cumN = cum + wv;
        float cwR = (i==19) ? 1.0f : fmaf(2.0f, cumN, -1.0f);
        if (xc >= cwL){ idx = i; inCw = cwL; inW = cwR - cwL; }
        cum = cumN;
    }
    float hcum = 0.f; float inCh = -1.0f, inH = 1.0f;
#pragma unroll
    for (int i=0;i<20;++i){
        float hv = fmaf(invh, tp[20+i], 0.001f);
        float chL = (i==0) ? -1.0f : fmaf(2.0f, hcum, -1.0f);
        float hcumN = hcum + hv;
        float chR = (i==19) ? 1.0f : fmaf(2.0f, hcumN, -1.0f);
        if (i == idx){ inCh = chL; inH = chR - chL; }
        hcum = hcumN;
    }
    float udl = TAILC, udr = TAILC;
#pragma unroll
    for (int t=0;t<19;++t){
        if (idx == t+1) udl = tp[40+t];
        if (idx == t)   udr = tp[40+t];
    }
    float inD   = 0.001f + softplus_(udl);
    float inDp1 = 0.001f + softplus_(udr);
    float inDelta = inH / inW;
    float th  = (xc - inCw) / inW;
    float omt = 1.0f - th;
    float t1  = th * omt;
    float num = inH * (inDelta*th*th + inD*t1);
    float den = inDelta + (inD + inDp1 - 2.0f*inDelta)*t1;
    float y = inCh + num/den;
    float dnum = inDelta*inDelta*(inDp1*th*th + 2.0f*inDelta*t1 + inD*omt*omt);
    float lad = __logf(dnum) - 2.0f*__logf(den);
    bool inside = (x >= -1.0f) && (x <= 1.0f);
    yo   = inside ? y   : x;
    lado = inside ? lad : 0.0f;
}
template<int OUTW>
__device__ __forceinline__ void addrow(float v, const float* __restrict__ Wrow, float* acc){
#pragma unroll
    for (int j=0;j<OUTW;++j) acc[j] = fmaf(v, Wrow[j], acc[j]);
}
template<int KIN, int OUT>
__device__ __forceinline__ void dense(const float* x, const float* __restrict__ W,
        const float* __restrict__ B, float* acc){
#pragma unroll
    for (int j=0;j<OUT;++j) acc[j] = B[j];
#pragma unroll
    for (int k=0;k<KIN;++k){
#pragma unroll
        for (int j=0;j<OUT;++j) acc[j] = fmaf(x[k], W[k*OUT+j], acc[j]);
    }
}
__device__ __forceinline__ void mlp_layer0(float t, const float* c,
        const float* __restrict__ W0, const float* __restrict__ B0, float* h)
{
#pragma unroll
    for (int j=0;j<32;++j) h[j] = B0[j];
    addrow<32>(t, W0 + 0*32, h);
    float s, co;
    __sincosf(t*1.0f,       &s,&co); addrow<32>(s, W0+1*32, h); addrow<32>(co, W0+2*32, h);
    __sincosf(t*3.3333333f, &s,&co); addrow<32>(s, W0+3*32, h); addrow<32>(co, W0+4*32, h);
    __sincosf(t*5.6666665f, &s,&co); addrow<32>(s, W0+5*32, h); addrow<32>(co, W0+6*32, h);
    __sincosf(t*8.0f,       &s,&co); addrow<32>(s, W0+7*32, h); addrow<32>(co, W0+8*32, h);
    addrow<32>(c[8], W0 + 9*32, h);
    addrow<32>(c[9], W0 +10*32, h);
    float f = 1.0f;
#pragma unroll
    for (int fi=0; fi<5; ++fi){
        float s8,c8v,s9,c9v;
        __sincosf(c[8]*f, &s8, &c8v);
        __sincosf(c[9]*f, &s9, &c9v);
        addrow<32>(s8,  W0 + (11+4*fi)*32, h);
        addrow<32>(s9,  W0 + (12+4*fi)*32, h);
        addrow<32>(c8v, W0 + (13+4*fi)*32, h);
        addrow<32>(c9v, W0 + (14+4*fi)*32, h);
        f *= 2.0f;
    }
#pragma unroll
    for (int k=0;k<8;++k) addrow<32>(c[k], W0 + (31+k)*32, h);
#pragma unroll
    for (int j=0;j<32;++j) h[j] = lrelu(h[j]);
}
__global__ __launch_bounds__(256,3) void nsf_kernel_f32(
    const float* __restrict__ wi, const float* __restrict__ cond,
    const float* __restrict__ p0_w0, const float* __restrict__ p0_b0,
    const float* __restrict__ p0_w1, const float* __restrict__ p0_b1,
    const float* __restrict__ m1_w0, const float* __restrict__ m1_b0,
    const float* __restrict__ m1_w1, const float* __restrict__ m1_b1,
    const float* __restrict__ m1_w2, const float* __restrict__ m1_b2,
    const float* __restrict__ m0_w0, const float* __restrict__ m0_b0,
    const float* __restrict__ m0_w1, const float* __restrict__ m0_b1,
    const float* __restrict__ m0_w2, const float* __restrict__ m0_b2,
    float* __restrict__ out)
{
    const int i = blockIdx.x*256 + threadIdx.x;
    float2 wv2 = reinterpret_cast<const float2*>(wi)[i];
    float w0v = wv2.x, w1v = wv2.y;
    const float* cp = cond + (size_t)i*10;
    float c[10];
#pragma unroll
    for (int k=0;k<10;++k) c[k] = cp[k];

    float tp[59];
    {
        float h[32], gg[32];
        mlp_layer0(w1v, c, m1_w0, m1_b0, h);
        dense<32,32>(h, m1_w1, m1_b1, gg);
#pragma unroll
        for (int j=0;j<32;++j) gg[j] = lrelu(gg[j]);
        dense<32,59>(gg, m1_w2, m1_b2, tp);
    }
    float y0, ld0; rqs_f32(w0v, tp, y0, ld0);
    {
        float h[32], gg[32];
        mlp_layer0(y0, c, m0_w0, m0_b0, h);
        dense<32,32>(h, m0_w1, m0_b1, gg);
#pragma unroll
        for (int j=0;j<32;++j) gg[j] = lrelu(gg[j]);
        dense<32,59>(gg, m0_w2, m0_b2, tp);
    }
    float y1, ld1; rqs_f32(w1v, tp, y1, ld1);

    float r[4];
    {
        float ph[32];
#pragma unroll
        for (int j=0;j<32;++j) ph[j] = p0_b0[j];
        addrow<32>(c[8], p0_w0 + 0*32, ph);
        addrow<32>(c[9], p0_w0 + 1*32, ph);
        float f = 1.0f;
#pragma unroll
        for (int fi=0; fi<5; ++fi){
            float s8,c8v,s9,c9v;
            __sincosf(c[8]*f, &s8, &c8v);
            __sincosf(c[9]*f, &s9, &c9v);
            addrow<32>(s8,  p0_w0 + (2+4*fi)*32, ph);
            addrow<32>(s9,  p0_w0 + (3+4*fi)*32, ph);
            addrow<32>(c8v, p0_w0 + (4+4*fi)*32, ph);
            addrow<32>(c9v, p0_w0 + (5+4*fi)*32, ph);
            f *= 2.0f;
        }
#pragma unroll
        for (int k=0;k<8;++k) addrow<32>(c[k], p0_w0 + (22+k)*32, ph);
#pragma unroll
        for (int j=0;j<32;++j) ph[j] = lrelu(ph[j]);
        dense<32,4>(ph, p0_w1, p0_b1, r);
    }

    float mu0=r[0], mu1=r[1], ls0=r[2], ls1=r[3];
    float is0 = __expf(-ls0), is1 = __expf(-ls1);
    float e0 = (y0-mu0)*is0, e1 = (y1-mu1)*is1;
    float rr = e0*e0 + e1*e1;
    float lp = -(ls0+ls1) - 1.8378770664093453f - 0.5f*rr + ld0 + ld1;

    reinterpret_cast<float2*>(out)[i] = make_float2(y0, y1);
    out[2*(size_t)N_PTS + i] = lp;
}

extern "C" void kernel_launch(void* const* d_in, const int* in_sizes, int n_in,
                              void* d_out, int out_size, void* d_ws, size_t ws_size,
                              hipStream_t stream)
{
    const float* wi    = (const float*)d_in[0];
    const float* cond  = (const float*)d_in[1];
    const float* p0_w0 = (const float*)d_in[2];
    const float* p0_b0 = (const float*)d_in[3];
    const float* p0_w1 = (const float*)d_in[4];
    const float* p0_b1 = (const float*)d_in[5];
    const float* m1_w0 = (const float*)d_in[6];
    const float* m1_b0 = (const float*)d_in[7];
    const float* m1_w1 = (const float*)d_in[8];
    const float* m1_b1 = (const float*)d_in[9];
    const float* m1_w2 = (const float*)d_in[10];
    const float* m1_b2 = (const float*)d_in[11];
    const float* m0_w0 = (const float*)d_in[12];
    const float* m0_b0 = (const float*)d_in[13];
    const float* m0_w1 = (const float*)d_in[14];
    const float* m0_b1 = (const float*)d_in[15];
    const float* m0_w2 = (const float*)d_in[16];
    const float* m0_b2 = (const float*)d_in[17];
    float* out = (float*)d_out;

    dim3 block(256);
    if (ws_size >= (size_t)WS_BYTES) {
        _Float16* wsp = (_Float16*)d_ws;
        hipLaunchKernelGGL(pack_weights, dim3((PACK_ITEMS+255)/256), block, 0, stream,
            m1_w0, m1_w1, m1_w2, m0_w0, m0_w1, m0_w2, p0_w0, p0_w1,
            m1_b0, m1_b1, m1_b2, m0_b0, m0_b1, m0_b2, p0_b0, wsp);
        hipLaunchKernelGGL(nsf_mfma, dim3(N_PTS/256), block, 0, stream,
            wi, cond, wsp, p0_b1, out);
    } else {
        hipLaunchKernelGGL(nsf_kernel_f32, dim3(N_PTS/256), block, 0, stream,
            wi, cond, p0_w0, p0_b0, p0_w1, p0_b1,
            m1_w0, m1_b0, m1_w1, m1_b1, m1_w2, m1_b2,
            m0_w0, m0_b0, m0_w1, m0_b1, m0_w2, m0_b2, out);
    }
}

// Round 9
// 159.519 us; speedup vs baseline: 4.6007x; 1.0455x over previous
//
#include <hip/hip_runtime.h>
#include <math.h>

#define N_PTS 2097152
#define TAILC 0.53974324f   // log(exp(1-0.001)-1)
#define LOG2E 1.4426950408889634f

typedef unsigned int u32;
typedef _Float16 half8 __attribute__((ext_vector_type(8)));
typedef _Float16 half4 __attribute__((ext_vector_type(4)));
typedef _Float16 h2    __attribute__((ext_vector_type(2)));
typedef __fp16   fp16x2 __attribute__((ext_vector_type(2)));
typedef float float4v  __attribute__((ext_vector_type(4)));

#define MFMA16 __builtin_amdgcn_mfma_f32_16x16x32_f16

__device__ __forceinline__ float lrelu(float x){ return x > 0.0f ? x : 0.01f*x; }
__device__ __forceinline__ float softplus_(float x){
    return fmaxf(x, 0.0f) + log1pf(__expf(-fabsf(x)));
}
__device__ __forceinline__ float exp2fast(float x){
#if __has_builtin(__builtin_amdgcn_exp2f)
    return __builtin_amdgcn_exp2f(x);
#else
    return exp2f(x);
#endif
}
__device__ __forceinline__ half4 pack4(float a0, float a1, float a2, float a3){
#if __has_builtin(__builtin_amdgcn_cvt_pkrtz)
    union { fp16x2 f; h2 h; } lo, hi;
    lo.f = __builtin_amdgcn_cvt_pkrtz(a0, a1);
    hi.f = __builtin_amdgcn_cvt_pkrtz(a2, a3);
    half4 r; r[0]=lo.h[0]; r[1]=lo.h[1]; r[2]=hi.h[0]; r[3]=hi.h[1];
    return r;
#else
    half4 r; r[0]=(_Float16)a0; r[1]=(_Float16)a1; r[2]=(_Float16)a2; r[3]=(_Float16)a3;
    return r;
#endif
}
__device__ __forceinline__ half8 join8(half4 a, half4 b){
    half8 r; r[0]=a[0]; r[1]=a[1]; r[2]=a[2]; r[3]=a[3];
    r[4]=b[0]; r[5]=b[1]; r[6]=b[2]; r[7]=b[3];
    return r;
}
__device__ __forceinline__ float fdot2(h2 a, h2 b, float c){
#if __has_builtin(__builtin_amdgcn_fdot2)
    return __builtin_amdgcn_fdot2(a, b, c, false);
#else
    return fmaf((float)a[0],(float)b[0], fmaf((float)a[1],(float)b[1], c));
#endif
}
__device__ __forceinline__ h2 u2h2(u32 u){ union{u32 a; h2 b;} x; x.a=u; return x.b; }

// physical position of logical output o for 32-wide layers (p = 8g + 4n + j, o = 16n+4g+j)
__device__ __host__ constexpr int ppos(int o){
    return 8*((o>>2)&3) + 4*(o>>4) + (o&3);
}
// physical position of logical output m for the 64-wide L2 layer (q = 16g + 8(n>>1) + 4(n&1) + j)
__device__ __host__ constexpr int qpos(int m){
    return 16*((m>>2)&3) + 8*((m>>4)>>1) + 4*((m>>4)&1) + (m&3);
}
// inverse: logical o at physical p (32-wide)
__device__ __host__ constexpr int pinv(int p){
    return 16*((p>>2)&1) + 4*(p>>3) + (p&3);
}

// Single shared allocation reachable from kernel AND noinline callees.
__device__ __forceinline__ _Float16* waveS(){
    __shared__ _Float16 S[4][4096];    // per-wave [64 rows][64 f16], swizzled
    return &S[0][0];
}
__device__ __forceinline__ half8 rd16(const _Float16* Sw, int row, int u){
    return *(const half8*)(Sw + row*64 + ((u ^ (row&7))<<3));
}
__device__ __forceinline__ void wr16(_Float16* Sw, int row, int u, half8 v){
    *(half8*)(Sw + row*64 + ((u ^ (row&7))<<3)) = v;
}

// ---- packed weights/biases in d_ws ----
// f16 region: WT[out][k_phys], k_phys permuted per pinv() for W1/W2 (their input = L-1 output layout).
// L0 A-col mapping: cols 0..29 = cond_e, 30..31 = 0, 32..40 = PE(t), 41..63 = 0 (logical = physical).
#define OFF_M1_W0T 0        // [32][64]
#define OFF_M1_W1T 2048     // [32][32]
#define OFF_M1_W2T 3072     // [64][32]
#define OFF_M0_W0T 5120
#define OFF_M0_W1T 7168
#define OFF_M0_W2T 8192
#define OFF_P0_W0T 10240    // [32][32]
#define WS_F16     11264
// f32 region (byte 22528)
#define FB_M1_B0   0
#define FB_M1_B1   32
#define FB_M1_B2   64       // padded to 64, outputs 0..39 pre-scaled by LOG2E
#define FB_M0_B0   128
#define FB_M0_B1   160
#define FB_M0_B2   192
#define FB_P0_B0   256
#define FB_PW1     288      // 64 u32: p0_w1 packed h2 pairs (logical order)
#define WS_BYTES   (22528 + 288*4 + 64*4)
#define PACK_ITEMS (WS_F16 + 288 + 64)

__global__ void pack_weights(const float* __restrict__ m1_w0, const float* __restrict__ m1_w1,
                             const float* __restrict__ m1_w2, const float* __restrict__ m0_w0,
                             const float* __restrict__ m0_w1, const float* __restrict__ m0_w2,
                             const float* __restrict__ p0_w0, const float* __restrict__ p0_w1,
                             const float* __restrict__ m1_b0, const float* __restrict__ m1_b1,
                             const float* __restrict__ m1_b2, const float* __restrict__ m0_b0,
                             const float* __restrict__ m0_b1, const float* __restrict__ m0_b2,
                             const float* __restrict__ p0_b0, _Float16* __restrict__ ws)
{
    int idx = blockIdx.x*256 + threadIdx.x;
    if (idx >= PACK_ITEMS) return;
    if (idx < WS_F16) {
        float v = 0.0f;
        if (idx < 2048 || (idx >= 5120 && idx < 7168)) {          // W0T [32][64], k logical
            const float* W = (idx < 2048) ? m1_w0 : m0_w0;
            int r = (idx < 2048) ? idx : idx - 5120;
            int o = r >> 6, k = r & 63;
            if (k < 30)                 v = W[(9+k)*32 + o];
            else if (k >= 32 && k < 41) v = W[(k-32)*32 + o];
        } else if (idx < 3072 || (idx >= 7168 && idx < 8192)) {   // W1T [32][32], k permuted
            const float* W = (idx < 3072) ? m1_w1 : m0_w1;
            int r = (idx < 3072) ? idx - 2048 : idx - 7168;
            int o = r >> 5, p = r & 31;
            v = W[pinv(p)*32 + o];
        } else if (idx < 5120 || (idx >= 8192 && idx < 10240)) {  // W2T [64][32], k permuted, rows<40 scaled
            const float* W = (idx < 5120) ? m1_w2 : m0_w2;
            int r = (idx < 5120) ? idx - 3072 : idx - 8192;
            int o = r >> 5, p = r & 31;
            if (o < 59) {
                v = W[pinv(p)*59 + o];
                if (o < 40) v *= LOG2E;
            }
        } else {                                                  // p0 W0T [32][32], k logical (cond_e)
            int r = idx - 10240;
            int o = r >> 5, k = r & 31;
            if (k < 30) v = p0_w0[k*32 + o];
        }
        ws[idx] = (_Float16)v;
        return;
    }
    float* wsf = (float*)(ws + WS_F16);
    int bi = idx - WS_F16;
    if (bi < 288) {
        float v = 0.0f;
        if      (bi < 32)  v = m1_b0[bi];
        else if (bi < 64)  v = m1_b1[bi-32];
        else if (bi < 128) { int o = bi-64;  if (o < 59) { v = m1_b2[o]; if (o < 40) v *= LOG2E; } }
        else if (bi < 160) v = m0_b0[bi-128];
        else if (bi < 192) v = m0_b1[bi-160];
        else if (bi < 256) { int o = bi-192; if (o < 59) { v = m0_b2[o]; if (o < 40) v *= LOG2E; } }
        else               v = p0_b0[bi-256];
        wsf[bi] = v;
        return;
    }
    int pi = bi - 288;            // 0..63 : p0_w1 packed pairs (logical k order)
    int k2 = pi >> 2, j = pi & 3;
    union{ _Float16 h; unsigned short s; } a, b;
    a.h = (_Float16)p0_w1[(2*k2)*4 + j];
    b.h = (_Float16)p0_w1[(2*k2+1)*4 + j];
    ((u32*)(wsf + FB_PW1))[pi] = (u32)a.s | ((u32)b.s << 16);
}

// ---------- one transform MLP (noinline, emitted once), swapped-operand MFMA ----------
// D = W^T x H. C/D: col = point (lane&15), row = output 4g+j.
// Both n-groups' 4 outputs merged into one b128 LDS write at permuted positions.
__device__ __noinline__ void mlp_lds(int tid,
    const _Float16* __restrict__ W0, const _Float16* __restrict__ W1,
    const _Float16* __restrict__ W2,
    const float* __restrict__ B0p, const float* __restrict__ B1p,
    const float* __restrict__ B2p)
{
    _Float16* Sw = waveS() + (tid>>6)*4096;
    const int l = tid & 63, mrow = l & 15, g = (l >> 4) & 3;

    // ---- L0: K=64 (2 ksteps), OUT=32 ----
    {
        half8 aW[2][2], bX[4][2];
#pragma unroll
        for (int n=0;n<2;++n)
#pragma unroll
            for (int s=0;s<2;++s)
                aW[n][s] = *(const half8*)(W0 + (16*n+mrow)*64 + 32*s + 8*g);
#pragma unroll
        for (int t=0;t<4;++t){
            int pt = 16*t + mrow;
#pragma unroll
            for (int s=0;s<2;++s) bX[t][s] = rd16(Sw, pt, 4*s+g);
        }
        float4v b0 = *(const float4v*)(B0p + 4*g);
        float4v b1 = *(const float4v*)(B0p + 16 + 4*g);
#pragma unroll
        for (int t=0;t<4;++t){
            float4v a0 = b0, a1 = b1;
            a0 = MFMA16(aW[0][0], bX[t][0], a0, 0,0,0);
            a0 = MFMA16(aW[0][1], bX[t][1], a0, 0,0,0);
            a1 = MFMA16(aW[1][0], bX[t][0], a1, 0,0,0);
            a1 = MFMA16(aW[1][1], bX[t][1], a1, 0,0,0);
            wr16(Sw, 16*t+mrow, g, join8(
                pack4(lrelu(a0[0]), lrelu(a0[1]), lrelu(a0[2]), lrelu(a0[3])),
                pack4(lrelu(a1[0]), lrelu(a1[1]), lrelu(a1[2]), lrelu(a1[3]))));
        }
    }
    __threadfence_block();
    // ---- L1: K=32, OUT=32 ----
    {
        half8 aW[2], bH[4];
#pragma unroll
        for (int n=0;n<2;++n) aW[n] = *(const half8*)(W1 + (16*n+mrow)*32 + 8*g);
#pragma unroll
        for (int t=0;t<4;++t) bH[t] = rd16(Sw, 16*t+mrow, g);
        float4v b0 = *(const float4v*)(B1p + 4*g);
        float4v b1 = *(const float4v*)(B1p + 16 + 4*g);
#pragma unroll
        for (int t=0;t<4;++t){
            float4v a0 = b0, a1 = b1;
            a0 = MFMA16(aW[0], bH[t], a0, 0,0,0);
            a1 = MFMA16(aW[1], bH[t], a1, 0,0,0);
            wr16(Sw, 16*t+mrow, g, join8(
                pack4(lrelu(a0[0]), lrelu(a0[1]), lrelu(a0[2]), lrelu(a0[3])),
                pack4(lrelu(a1[0]), lrelu(a1[1]), lrelu(a1[2]), lrelu(a1[3]))));
        }
    }
    __threadfence_block();
    // ---- L2: K=32, OUT=64 (59 real; outputs 0..39 pre-scaled by LOG2E), no activation ----
    {
        half8 aW[4], bH[4];
#pragma unroll
        for (int n=0;n<4;++n) aW[n] = *(const half8*)(W2 + (16*n+mrow)*32 + 8*g);
#pragma unroll
        for (int t=0;t<4;++t) bH[t] = rd16(Sw, 16*t+mrow, g);
        float4v bb[4];
#pragma unroll
        for (int n=0;n<4;++n) bb[n] = *(const float4v*)(B2p + 16*n + 4*g);
#pragma unroll
        for (int t=0;t<4;++t){
            float4v a0=bb[0], a1=bb[1], a2=bb[2], a3=bb[3];
            a0 = MFMA16(aW[0], bH[t], a0, 0,0,0);
            a1 = MFMA16(aW[1], bH[t], a1, 0,0,0);
            a2 = MFMA16(aW[2], bH[t], a2, 0,0,0);
            a3 = MFMA16(aW[3], bH[t], a3, 0,0,0);
            int row = 16*t + mrow;
            wr16(Sw, row, 2*g,   join8(pack4(a0[0],a0[1],a0[2],a0[3]),
                                       pack4(a1[0],a1[1],a1[2],a1[3])));
            wr16(Sw, row, 2*g+1, join8(pack4(a2[0],a2[1],a2[2],a2[3]),
                                       pack4(a3[0],a3[1],a3[2],a3[3])));
        }
    }
    __threadfence_block();
}

// ---------- spline (noinline, emitted once), reads permuted params from LDS ----------
// Params 0..39 (uw, uh) arrive pre-scaled by LOG2E -> use exp2 directly.
__device__ __noinline__ float2 rqs_lds(float x, int tid)
{
    const int l = tid & 63;
    const _Float16* Sw = waveS() + (tid>>6)*4096;

    half8 R[8];
#pragma unroll
    for (int u=0;u<8;++u) R[u] = rd16(Sw, l, u);

    float xc = fminf(fmaxf(x,-1.0f),1.0f);
    int idx = 0;
    float inCw = -1.0f, inW = 1.0f;
    {   // widths: logical 0..19 (scaled by LOG2E)
        float w[20];
#pragma unroll
        for (int i=0;i<20;++i){ int q = qpos(i); w[i] = (float)R[q>>3][q&7]; }
        float mw = w[0];
#pragma unroll
        for (int i=1;i<20;++i) mw = fmaxf(mw, w[i]);
        float sw = 0.f;
#pragma unroll
        for (int i=0;i<20;++i){ w[i] = exp2fast(w[i]-mw); sw += w[i]; }
        float invw = 0.98f / sw;
        float cum = 0.f;
#pragma unroll
        for (int i=0;i<20;++i){
            float wv = fmaf(invw, w[i], 0.001f);
            float cwL = (i==0) ? -1.0f : fmaf(2.0f, cum, -1.0f);
            float cumN = cum + wv;
            float cwR = (i==19) ? 1.0f : fmaf(2.0f, cumN, -1.0f);
            if (xc >= cwL){ idx = i; inCw = cwL; inW = cwR - cwL; }
            cum = cumN;
        }
    }
    float inCh = -1.0f, inH = 1.0f;
    {   // heights: logical 20..39 (scaled by LOG2E)
        float h[20];
#pragma unroll
        for (int i=0;i<20;++i){ int q = qpos(20+i); h[i] = (float)R[q>>3][q&7]; }
        float mh = h[0];
#pragma unroll
        for (int i=1;i<20;++i) mh = fmaxf(mh, h[i]);
        float sh = 0.f;
#pragma unroll
        for (int i=0;i<20;++i){ h[i] = exp2fast(h[i]-mh); sh += h[i]; }
        float invh = 0.98f / sh;
        float hcum = 0.f;
#pragma unroll
        for (int i=0;i<20;++i){
            float hv = fmaf(invh, h[i], 0.001f);
            float chL = (i==0) ? -1.0f : fmaf(2.0f, hcum, -1.0f);
            float hcumN = hcum + hv;
            float chR = (i==19) ? 1.0f : fmaf(2.0f, hcumN, -1.0f);
            if (i == idx){ inCh = chL; inH = chR - chL; }
            hcum = hcumN;
        }
    }
    float udl = TAILC, udr = TAILC;
    {   // derivatives: logical 40..58 (unscaled)
#pragma unroll
        for (int t=0;t<19;++t){
            int q = qpos(40+t);
            float v = (float)R[q>>3][q&7];
            if (idx == t+1) udl = v;
            if (idx == t)   udr = v;
        }
    }
    float inD   = 0.001f + softplus_(udl);
    float inDp1 = 0.001f + softplus_(udr);
    float inDelta = inH / inW;
    float th  = (xc - inCw) / inW;
    float omt = 1.0f - th;
    float t1  = th * omt;
    float num = inH * (inDelta*th*th + inD*t1);
    float den = inDelta + (inD + inDp1 - 2.0f*inDelta)*t1;
    float y = inCh + num/den;
    float dnum = inDelta*inDelta*(inDp1*th*th + 2.0f*inDelta*t1 + inD*omt*omt);
    float lad = __logf(dnum) - 2.0f*__logf(den);
    bool inside = (x >= -1.0f) && (x <= 1.0f);
    return make_float2(inside ? y : x, inside ? lad : 0.0f);
}

__global__ __launch_bounds__(256,4) void nsf_mfma(
    const float* __restrict__ wi, const float* __restrict__ cond,
    const _Float16* __restrict__ wsp,
    const float* __restrict__ p0_b1,
    float* __restrict__ out)
{
    const int tid = threadIdx.x;
    const int l = tid & 63, wid = tid >> 6;
    const int i = blockIdx.x*256 + wid*64 + l;
    _Float16* Sw = waveS() + wid*4096;
    const int mrow = l & 15, g = (l >> 4) & 3;
    const float* wsf = (const float*)(wsp + WS_F16);

    float2 wv2 = reinterpret_cast<const float2*>(wi)[i];
    float w0v = wv2.x, w1v = wv2.y;
    float c[10];
    {
        const float2* cp2 = reinterpret_cast<const float2*>(cond + (size_t)i*10);
#pragma unroll
        for (int k=0;k<5;++k){ float2 t2 = cp2[k]; c[2*k]=t2.x; c[2*k+1]=t2.y; }
    }

    // cond_e -> f16 chunks A0..A3 (cols 0..31, incl. 2 zero pads)
    half8 A0, A1, A2, A3, Z;
#pragma unroll
    for (int j=0;j<8;++j) Z[j] = (_Float16)0.0f;
    {
        _Float16 ce[30];
        ce[0] = (_Float16)c[8];
        ce[1] = (_Float16)c[9];
        float f = 1.0f;
#pragma unroll
        for (int fi=0; fi<5; ++fi){
            float s8,c8v,s9,c9v;
            __sincosf(c[8]*f, &s8, &c8v);
            __sincosf(c[9]*f, &s9, &c9v);
            ce[2+4*fi+0]=(_Float16)s8;  ce[2+4*fi+1]=(_Float16)s9;
            ce[2+4*fi+2]=(_Float16)c8v; ce[2+4*fi+3]=(_Float16)c9v;
            f *= 2.0f;
        }
#pragma unroll
        for (int k=0;k<8;++k) ce[22+k] = (_Float16)c[k];
#pragma unroll
        for (int j=0;j<8;++j){ A0[j]=ce[j]; A1[j]=ce[8+j]; A2[j]=ce[16+j]; }
#pragma unroll
        for (int j=0;j<8;++j) A3[j] = (j<6) ? ce[24+j] : (_Float16)0.0f;
    }

    auto mkPE = [&](float t, half8& P0, half8& P1){
        float s1,c1v,s2,c2v,s3,c3v,s4,c4v;
        __sincosf(t*1.0f,       &s1,&c1v);
        __sincosf(t*3.3333333f, &s2,&c2v);
        __sincosf(t*5.6666665f, &s3,&c3v);
        __sincosf(t*8.0f,       &s4,&c4v);
        P0[0]=(_Float16)t;   P0[1]=(_Float16)s1; P0[2]=(_Float16)c1v; P0[3]=(_Float16)s2;
        P0[4]=(_Float16)c2v; P0[5]=(_Float16)s3; P0[6]=(_Float16)c3v; P0[7]=(_Float16)s4;
        P1 = Z; P1[0] = (_Float16)c4v;
    };

    // ---- m1: stage xin(w1v), MLP, spline on w0 ----
    half8 P0, P1;
    mkPE(w1v, P0, P1);
    wr16(Sw,l,0,A0); wr16(Sw,l,1,A1); wr16(Sw,l,2,A2); wr16(Sw,l,3,A3);
    wr16(Sw,l,4,P0); wr16(Sw,l,5,P1); wr16(Sw,l,6,Z);  wr16(Sw,l,7,Z);
    __threadfence_block();
    mlp_lds(tid, wsp+OFF_M1_W0T, wsp+OFF_M1_W1T, wsp+OFF_M1_W2T,
            wsf+FB_M1_B0, wsf+FB_M1_B1, wsf+FB_M1_B2);
    float2 r0 = rqs_lds(w0v, tid);
    float y0 = r0.x, ld0 = r0.y;

    // ---- m0: stage xin(y0), MLP, spline on w1 ----
    mkPE(y0, P0, P1);
    wr16(Sw,l,0,A0); wr16(Sw,l,1,A1); wr16(Sw,l,2,A2); wr16(Sw,l,3,A3);
    wr16(Sw,l,4,P0); wr16(Sw,l,5,P1); wr16(Sw,l,6,Z);  wr16(Sw,l,7,Z);
    __threadfence_block();
    mlp_lds(tid, wsp+OFF_M0_W0T, wsp+OFF_M0_W1T, wsp+OFF_M0_W2T,
            wsf+FB_M0_B0, wsf+FB_M0_B1, wsf+FB_M0_B2);
    float2 r1 = rqs_lds(w1v, tid);
    float y1 = r1.x, ld1 = r1.y;

    // ---- p0: cond_e(30,+2pad) -> 32 (lrelu) via swapped MFMA, merged b128 writes ----
    wr16(Sw,l,0,A0); wr16(Sw,l,1,A1); wr16(Sw,l,2,A2); wr16(Sw,l,3,A3);
    __threadfence_block();
    {
        half8 aW[2], bC[4];
#pragma unroll
        for (int n=0;n<2;++n) aW[n] = *(const half8*)(wsp + OFF_P0_W0T + (16*n+mrow)*32 + 8*g);
#pragma unroll
        for (int t=0;t<4;++t) bC[t] = rd16(Sw, 16*t+mrow, g);
        const float* PB = wsf + FB_P0_B0;
        float4v b0 = *(const float4v*)(PB + 4*g);
        float4v b1 = *(const float4v*)(PB + 16 + 4*g);
#pragma unroll
        for (int t=0;t<4;++t){
            float4v a0 = b0, a1 = b1;
            a0 = MFMA16(aW[0], bC[t], a0, 0,0,0);
            a1 = MFMA16(aW[1], bC[t], a1, 0,0,0);
            wr16(Sw, 16*t+mrow, g, join8(
                pack4(lrelu(a0[0]), lrelu(a0[1]), lrelu(a0[2]), lrelu(a0[3])),
                pack4(lrelu(a1[0]), lrelu(a1[1]), lrelu(a1[2]), lrelu(a1[3]))));
        }
    }
    __threadfence_block();

    // ---- tail: per-thread 32 -> 4 via fdot2 (permuted unpack, logical-pair weights) ----
    float r4[4] = {p0_b1[0], p0_b1[1], p0_b1[2], p0_b1[3]};
    {
        half8 Tq[4];
#pragma unroll
        for (int u=0;u<4;++u) Tq[u] = rd16(Sw, l, u);
        const u32* pw = (const u32*)(wsf + FB_PW1);
#pragma unroll
        for (int k2=0;k2<16;++k2){
            int p = ppos(2*k2);                 // pair (2k2, 2k2+1) is position-adjacent
            h2 x; x[0] = Tq[p>>3][p&7]; x[1] = Tq[(p+1)>>3][(p+1)&7];
#pragma unroll
            for (int j=0;j<4;++j) r4[j] = fdot2(x, u2h2(pw[k2*4+j]), r4[j]);
        }
    }

    float mu0=r4[0], mu1=r4[1], ls0=r4[2], ls1=r4[3];
    float is0 = __expf(-ls0), is1 = __expf(-ls1);
    float e0 = (y0-mu0)*is0, e1 = (y1-mu1)*is1;
    float rr = e0*e0 + e1*e1;
    float lp = -(ls0+ls1) - 1.8378770664093453f - 0.5f*rr + ld0 + ld1;

    reinterpret_cast<float2*>(out)[i] = make_float2(y0, y1);
    out[2*(size_t)N_PTS + i] = lp;
}

// ---------------- fallback all-f32 kernel (known-good R1) ----------------
__device__ __forceinline__ void rqs_f32(float x, float* tp, float& yo, float& lado)
{
    float mw = tp[0];
#pragma unroll
    for (int i=1;i<20;++i) mw = fmaxf(mw, tp[i]);
    float sw = 0.f;
#pragma unroll
    for (int i=0;i<20;++i){ tp[i] = __expf(tp[i]-mw); sw += tp[i]; }
    float invw = 0.98f / sw;
    float mh = tp[20];
#pragma unroll
    for (int i=1;i<20;++i) mh = fmaxf(mh, tp[20+i]);
    float sh = 0.f;
#pragma unroll
    for (int i=0;i<20;++i){ tp[20+i] = __expf(tp[20+i]-mh); sh += tp[20+i]; }
    float invh = 0.98f / sh;
    float xc = fminf(fmaxf(x,-1.0f),1.0f);
    float cum = 0.f; int idx = 0;
    float inCw = -1.0f, inW = 1.0f;
#pragma unroll
    for (int i=0;i<20;++i){
        float wv = fmaf(invw, tp[i], 0.001f);
        float cwL = (i==0) ? -1.0f : fmaf(2.0f, cum, -1.0f);
        float cumN = cum + wv;
        float cwR = (i==19) ? 1.0f : fmaf(2.0f, cumN, -1.0f);
        if (xc >= cwL){ idx = i; inCw = cwL; inW = cwR - cwL; }
        cum = cumN;
    }
    float hcum = 0.f; float inCh = -1.0f, inH = 1.0f;
#pragma unroll
    for (int i=0;i<20;++i){
        float hv = fmaf(invh, tp[20+i], 0.001f);
        float chL = (i==0) ? -1.0f : fmaf(2.0f, hcum, -1.0f);
        float hcumN = hcum + hv;
        float chR = (i==19) ? 1.0f : fmaf(2.0f, hcumN, -1.0f);
        if (i == idx){ inCh = chL; inH = chR - chL; }
        hcum = hcumN;
    }
    float udl = TAILC, udr = TAILC;
#pragma unroll
    for (int t=0;t<19;++t){
        if (idx == t+1) udl = tp[40+t];
        if (idx == t)   udr = tp[40+t];
    }
    float inD   = 0.001f + softplus_(udl);
    float inDp1 = 0.001f + softplus_(udr);
    float inDelta = inH / inW;
    float th  = (xc - inCw) / inW;
    float omt = 1.0f - th;
    float t1  = th * omt;
    float num = inH * (inDelta*th*th + inD*t1);
    float den = inDelta + (inD + inDp1 - 2.0f*inDelta)*t1;
    float y = inCh + num/den;
    float dnum = inDelta*inDelta*(inDp1*th*th + 2.0f*inDelta*t1 + inD*omt*omt);
    float lad = __logf(dnum) - 2.0f*__logf(den);
    bool inside = (x >= -1.0f) && (x <= 1.0f);
    yo   = inside ? y   : x;
    lado = inside ? lad : 0.0f;
}
template<int OUTW>
__device__ __forceinline__ void addrow(float v, const float* __restrict__ Wrow, float* acc){
#pragma unroll
    for (int j=0;j<OUTW;++j) acc[j] = fmaf(v, Wrow[j], acc[j]);
}
template<int KIN, int OUT>
__device__ __forceinline__ void dense(const float* x, const float* __restrict__ W,
        const float* __restrict__ B, float* acc){
#pragma unroll
    for (int j=0;j<OUT;++j) acc[j] = B[j];
#pragma unroll
    for (int k=0;k<KIN;++k){
#pragma unroll
        for (int j=0;j<OUT;++j) acc[j] = fmaf(x[k], W[k*OUT+j], acc[j]);
    }
}
__device__ __forceinline__ void mlp_layer0(float t, const float* c,
        const float* __restrict__ W0, const float* __restrict__ B0, float* h)
{
#pragma unroll
    for (int j=0;j<32;++j) h[j] = B0[j];
    addrow<32>(t, W0 + 0*32, h);
    float s, co;
    __sincosf(t*1.0f,       &s,&co); addrow<32>(s, W0+1*32, h); addrow<32>(co, W0+2*32, h);
    __sincosf(t*3.3333333f, &s,&co); addrow<32>(s, W0+3*32, h); addrow<32>(co, W0+4*32, h);
    __sincosf(t*5.6666665f, &s,&co); addrow<32>(s, W0+5*32, h); addrow<32>(co, W0+6*32, h);
    __sincosf(t*8.0f,       &s,&co); addrow<32>(s, W0+7*32, h); addrow<32>(co, W0+8*32, h);
    addrow<32>(c[8], W0 + 9*32, h);
    addrow<32>(c[9], W0 +10*32, h);
    float f = 1.0f;
#pragma unroll
    for (int fi=0; fi<5; ++fi){
        float s8,c8v,s9,c9v;
        __sincosf(c[8]*f, &s8, &c8v);
        __sincosf(c[9]*f, &s9, &c9v);
        addrow<32>(s8,  W0 + (11+4*fi)*32, h);
        addrow<32>(s9,  W0 + (12+4*fi)*32, h);
        addrow<32>(c8v, W0 + (13+4*fi)*32, h);
        addrow<32>(c9v, W0 + (14+4*fi)*32, h);
        f *= 2.0f;
    }
#pragma unroll
    for (int k=0;k<8;++k) addrow<32>(c[k], W0 + (31+k)*32, h);
#pragma unroll
    for (int j=0;j<32;++j) h[j] = lrelu(h[j]);
}
__global__ __launch_bounds__(256,3) void nsf_kernel_f32(
    const float* __restrict__ wi, const float* __restrict__ cond,
    const float* __restrict__ p0_w0, const float* __restrict__ p0_b0,
    const float* __restrict__ p0_w1, const float* __restrict__ p0_b1,
    const float* __restrict__ m1_w0, const float* __restrict__ m1_b0,
    const float* __restrict__ m1_w1, const float* __restrict__ m1_b1,
    const float* __restrict__ m1_w2, const float* __restrict__ m1_b2,
    const float* __restrict__ m0_w0, const float* __restrict__ m0_b0,
    const float* __restrict__ m0_w1, const float* __restrict__ m0_b1,
    const float* __restrict__ m0_w2, const float* __restrict__ m0_b2,
    float* __restrict__ out)
{
    const int i = blockIdx.x*256 + threadIdx.x;
    float2 wv2 = reinterpret_cast<const float2*>(wi)[i];
    float w0v = wv2.x, w1v = wv2.y;
    const float* cp = cond + (size_t)i*10;
    float c[10];
#pragma unroll
    for (int k=0;k<10;++k) c[k] = cp[k];

    float tp[59];
    {
        float h[32], gg[32];
        mlp_layer0(w1v, c, m1_w0, m1_b0, h);
        dense<32,32>(h, m1_w1, m1_b1, gg);
#pragma unroll
        for (int j=0;j<32;++j) gg[j] = lrelu(gg[j]);
        dense<32,59>(gg, m1_w2, m1_b2, tp);
    }
    float y0, ld0; rqs_f32(w0v, tp, y0, ld0);
    {
        float h[32], gg[32];
        mlp_layer0(y0, c, m0_w0, m0_b0, h);
        dense<32,32>(h, m0_w1, m0_b1, gg);
#pragma unroll
        for (int j=0;j<32;++j) gg[j] = lrelu(gg[j]);
        dense<32,59>(gg, m0_w2, m0_b2, tp);
    }
    float y1, ld1; rqs_f32(w1v, tp, y1, ld1);

    float r[4];
    {
        float ph[32];
#pragma unroll
        for (int j=0;j<32;++j) ph[j] = p0_b0[j];
        addrow<32>(c[8], p0_w0 + 0*32, ph);
        addrow<32>(c[9], p0_w0 + 1*32, ph);
        float f = 1.0f;
#pragma unroll
        for (int fi=0; fi<5; ++fi){
            float s8,c8v,s9,c9v;
            __sincosf(c[8]*f, &s8, &c8v);
            __sincosf(c[9]*f, &s9, &c9v);
            addrow<32>(s8,  p0_w0 + (2+4*fi)*32, ph);
            addrow<32>(s9,  p0_w0 + (3+4*fi)*32, ph);
            addrow<32>(c8v, p0_w0 + (4+4*fi)*32, ph);
            addrow<32>(c9v, p0_w0 + (5+4*fi)*32, ph);
            f *= 2.0f;
        }
#pragma unroll
        for (int k=0;k<8;++k) addrow<32>(c[k], p0_w0 + (22+k)*32, ph);
#pragma unroll
        for (int j=0;j<32;++j) ph[j] = lrelu(ph[j]);
        dense<32,4>(ph, p0_w1, p0_b1, r);
    }

    float mu0=r[0], mu1=r[1], ls0=r[2], ls1=r[3];
    float is0 = __expf(-ls0), is1 = __expf(-ls1);
    float e0 = (y0-mu0)*is0, e1 = (y1-mu1)*is1;
    float rr = e0*e0 + e1*e1;
    float lp = -(ls0+ls1) - 1.8378770664093453f - 0.5f*rr + ld0 + ld1;

    reinterpret_cast<float2*>(out)[i] = make_float2(y0, y1);
    out[2*(size_t)N_PTS + i] = lp;
}

extern "C" void kernel_launch(void* const* d_in, const int* in_sizes, int n_in,
                              void* d_out, int out_size, void* d_ws, size_t ws_size,
                              hipStream_t stream)
{
    const float* wi    = (const float*)d_in[0];
    const float* cond  = (const float*)d_in[1];
    const float* p0_w0 = (const float*)d_in[2];
    const float* p0_b0 = (const float*)d_in[3];
    const float* p0_w1 = (const float*)d_in[4];
    const float* p0_b1 = (const float*)d_in[5];
    const float* m1_w0 = (const float*)d_in[6];
    const float* m1_b0 = (const float*)d_in[7];
    const float* m1_w1 = (const float*)d_in[8];
    const float* m1_b1 = (const float*)d_in[9];
    const float* m1_w2 = (const float*)d_in[10];
    const float* m1_b2 = (const float*)d_in[11];
    const float* m0_w0 = (const float*)d_in[12];
    const float* m0_b0 = (const float*)d_in[13];
    const float* m0_w1 = (const float*)d_in[14];
    const float* m0_b1 = (const float*)d_in[15];
    const float* m0_w2 = (const float*)d_in[16];
    const float* m0_b2 = (const float*)d_in[17];
    float* out = (float*)d_out;

    dim3 block(256);
    if (ws_size >= (size_t)WS_BYTES) {
        _Float16* wsp = (_Float16*)d_ws;
        hipLaunchKernelGGL(pack_weights, dim3((PACK_ITEMS+255)/256), block, 0, stream,
            m1_w0, m1_w1, m1_w2, m0_w0, m0_w1, m0_w2, p0_w0, p0_w1,
            m1_b0, m1_b1, m1_b2, m0_b0, m0_b1, m0_b2, p0_b0, wsp);
        hipLaunchKernelGGL(nsf_mfma, dim3(N_PTS/256), block, 0, stream,
            wi, cond, wsp, p0_b1, out);
    } else {
        hipLaunchKernelGGL(nsf_kernel_f32, dim3(N_PTS/256), block, 0, stream,
            wi, cond, p0_w0, p0_b0, p0_w1, p0_b1,
            m1_w0, m1_b0, m1_w1, m1_b1, m1_w2, m1_b2,
            m0_w0, m0_b0, m0_w1, m0_b1, m0_w2, m0_b2, out);
    }
}

// Round 10
// 131.524 us; speedup vs baseline: 5.5800x; 1.2129x over previous
//
#include <hip/hip_runtime.h>
#include <math.h>

#define N_PTS 2097152
#define TAILC 0.53974324f   // log(exp(1-0.001)-1)
#define LOG2E 1.4426950408889634f
#define LN2   0.6931471805599453f

typedef unsigned int u32;
typedef _Float16 half8 __attribute__((ext_vector_type(8)));
typedef _Float16 half4 __attribute__((ext_vector_type(4)));
typedef _Float16 h2    __attribute__((ext_vector_type(2)));
typedef __fp16   fp16x2 __attribute__((ext_vector_type(2)));
typedef float float4v  __attribute__((ext_vector_type(4)));

#define MFMA16 __builtin_amdgcn_mfma_f32_16x16x32_f16

__device__ __forceinline__ float lrelu(float x){ return x > 0.0f ? x : 0.01f*x; }
__device__ __forceinline__ float exp2fast(float x){
#if __has_builtin(__builtin_amdgcn_exp2f)
    return __builtin_amdgcn_exp2f(x);
#else
    return exp2f(x);
#endif
}
__device__ __forceinline__ float log2fast(float x){
#if __has_builtin(__builtin_amdgcn_logf)
    return __builtin_amdgcn_logf(x);
#else
    return __log2f(x);
#endif
}
// softplus(x) = ln2 * log2(1 + exp2(x*log2e)); f32-safe for |x| < ~80
__device__ __forceinline__ float softplus_(float x){
    return LN2 * log2fast(1.0f + exp2fast(x * LOG2E));
}
__device__ __forceinline__ half4 pack4(float a0, float a1, float a2, float a3){
#if __has_builtin(__builtin_amdgcn_cvt_pkrtz)
    union { fp16x2 f; h2 h; } lo, hi;
    lo.f = __builtin_amdgcn_cvt_pkrtz(a0, a1);
    hi.f = __builtin_amdgcn_cvt_pkrtz(a2, a3);
    half4 r; r[0]=lo.h[0]; r[1]=lo.h[1]; r[2]=hi.h[0]; r[3]=hi.h[1];
    return r;
#else
    half4 r; r[0]=(_Float16)a0; r[1]=(_Float16)a1; r[2]=(_Float16)a2; r[3]=(_Float16)a3;
    return r;
#endif
}
__device__ __forceinline__ half8 join8(half4 a, half4 b){
    half8 r; r[0]=a[0]; r[1]=a[1]; r[2]=a[2]; r[3]=a[3];
    r[4]=b[0]; r[5]=b[1]; r[6]=b[2]; r[7]=b[3];
    return r;
}
__device__ __forceinline__ float fdot2(h2 a, h2 b, float c){
#if __has_builtin(__builtin_amdgcn_fdot2)
    return __builtin_amdgcn_fdot2(a, b, c, false);
#else
    return fmaf((float)a[0],(float)b[0], fmaf((float)a[1],(float)b[1], c));
#endif
}
__device__ __forceinline__ h2 u2h2(u32 u){ union{u32 a; h2 b;} x; x.a=u; return x.b; }

// physical position of logical output o for 32-wide layers (p = 8g + 4n + j, o = 16n+4g+j)
__device__ __host__ constexpr int ppos(int o){
    return 8*((o>>2)&3) + 4*(o>>4) + (o&3);
}
// physical position of logical output m for the 64-wide L2 layer
__device__ __host__ constexpr int qpos(int m){
    return 16*((m>>2)&3) + 8*((m>>4)>>1) + 4*((m>>4)&1) + (m&3);
}
// inverse: logical o at physical p (32-wide)
__device__ __host__ constexpr int pinv(int p){
    return 16*((p>>2)&1) + 4*(p>>3) + (p&3);
}

// Single shared allocation reachable from kernel AND noinline callees.
__device__ __forceinline__ _Float16* waveS(){
    __shared__ _Float16 S[4][4096];    // per-wave [64 rows][64 f16], swizzled
    return &S[0][0];
}
__device__ __forceinline__ half8 rd16(const _Float16* Sw, int row, int u){
    return *(const half8*)(Sw + row*64 + ((u ^ (row&7))<<3));
}
__device__ __forceinline__ void wr16(_Float16* Sw, int row, int u, half8 v){
    *(half8*)(Sw + row*64 + ((u ^ (row&7))<<3)) = v;
}

// ---- packed weights/biases in d_ws ----
#define OFF_M1_W0T 0        // [32][64]
#define OFF_M1_W1T 2048     // [32][32]
#define OFF_M1_W2T 3072     // [64][32]
#define OFF_M0_W0T 5120
#define OFF_M0_W1T 7168
#define OFF_M0_W2T 8192
#define OFF_P0_W0T 10240    // [32][32]
#define WS_F16     11264
// f32 region (byte 22528)
#define FB_M1_B0   0
#define FB_M1_B1   32
#define FB_M1_B2   64       // padded to 64, outputs 0..39 pre-scaled by LOG2E
#define FB_M0_B0   128
#define FB_M0_B1   160
#define FB_M0_B2   192
#define FB_P0_B0   256
#define FB_PW1     288      // 64 u32: p0_w1 packed h2 pairs
#define WS_BYTES   (22528 + 288*4 + 64*4)
#define PACK_ITEMS (WS_F16 + 288 + 64)

__global__ void pack_weights(const float* __restrict__ m1_w0, const float* __restrict__ m1_w1,
                             const float* __restrict__ m1_w2, const float* __restrict__ m0_w0,
                             const float* __restrict__ m0_w1, const float* __restrict__ m0_w2,
                             const float* __restrict__ p0_w0, const float* __restrict__ p0_w1,
                             const float* __restrict__ m1_b0, const float* __restrict__ m1_b1,
                             const float* __restrict__ m1_b2, const float* __restrict__ m0_b0,
                             const float* __restrict__ m0_b1, const float* __restrict__ m0_b2,
                             const float* __restrict__ p0_b0, _Float16* __restrict__ ws)
{
    int idx = blockIdx.x*256 + threadIdx.x;
    if (idx >= PACK_ITEMS) return;
    if (idx < WS_F16) {
        float v = 0.0f;
        if (idx < 2048 || (idx >= 5120 && idx < 7168)) {          // W0T [32][64], k logical
            const float* W = (idx < 2048) ? m1_w0 : m0_w0;
            int r = (idx < 2048) ? idx : idx - 5120;
            int o = r >> 6, k = r & 63;
            if (k < 30)                 v = W[(9+k)*32 + o];
            else if (k >= 32 && k < 41) v = W[(k-32)*32 + o];
        } else if (idx < 3072 || (idx >= 7168 && idx < 8192)) {   // W1T [32][32], k permuted
            const float* W = (idx < 3072) ? m1_w1 : m0_w1;
            int r = (idx < 3072) ? idx - 2048 : idx - 7168;
            int o = r >> 5, p = r & 31;
            v = W[pinv(p)*32 + o];
        } else if (idx < 5120 || (idx >= 8192 && idx < 10240)) {  // W2T [64][32], k permuted, rows<40 scaled
            const float* W = (idx < 5120) ? m1_w2 : m0_w2;
            int r = (idx < 5120) ? idx - 3072 : idx - 8192;
            int o = r >> 5, p = r & 31;
            if (o < 59) {
                v = W[pinv(p)*59 + o];
                if (o < 40) v *= LOG2E;
            }
        } else {                                                  // p0 W0T [32][32], k logical
            int r = idx - 10240;
            int o = r >> 5, k = r & 31;
            if (k < 30) v = p0_w0[k*32 + o];
        }
        ws[idx] = (_Float16)v;
        return;
    }
    float* wsf = (float*)(ws + WS_F16);
    int bi = idx - WS_F16;
    if (bi < 288) {
        float v = 0.0f;
        if      (bi < 32)  v = m1_b0[bi];
        else if (bi < 64)  v = m1_b1[bi-32];
        else if (bi < 128) { int o = bi-64;  if (o < 59) { v = m1_b2[o]; if (o < 40) v *= LOG2E; } }
        else if (bi < 160) v = m0_b0[bi-128];
        else if (bi < 192) v = m0_b1[bi-160];
        else if (bi < 256) { int o = bi-192; if (o < 59) { v = m0_b2[o]; if (o < 40) v *= LOG2E; } }
        else               v = p0_b0[bi-256];
        wsf[bi] = v;
        return;
    }
    int pi = bi - 288;            // 0..63 : p0_w1 packed pairs
    int k2 = pi >> 2, j = pi & 3;
    union{ _Float16 h; unsigned short s; } a, b;
    a.h = (_Float16)p0_w1[(2*k2)*4 + j];
    b.h = (_Float16)p0_w1[(2*k2+1)*4 + j];
    ((u32*)(wsf + FB_PW1))[pi] = (u32)a.s | ((u32)b.s << 16);
}

// ---------- one transform MLP (noinline, emitted once), swapped-operand MFMA ----------
__device__ __noinline__ void mlp_lds(int tid,
    const _Float16* __restrict__ W0, const _Float16* __restrict__ W1,
    const _Float16* __restrict__ W2,
    const float* __restrict__ B0p, const float* __restrict__ B1p,
    const float* __restrict__ B2p)
{
    _Float16* Sw = waveS() + (tid>>6)*4096;
    const int l = tid & 63, mrow = l & 15, g = (l >> 4) & 3;

    // ---- L0: K=64 (2 ksteps), OUT=32 ----
    {
        half8 aW[2][2], bX[4][2];
#pragma unroll
        for (int n=0;n<2;++n)
#pragma unroll
            for (int s=0;s<2;++s)
                aW[n][s] = *(const half8*)(W0 + (16*n+mrow)*64 + 32*s + 8*g);
#pragma unroll
        for (int t=0;t<4;++t){
            int pt = 16*t + mrow;
#pragma unroll
            for (int s=0;s<2;++s) bX[t][s] = rd16(Sw, pt, 4*s+g);
        }
        float4v b0 = *(const float4v*)(B0p + 4*g);
        float4v b1 = *(const float4v*)(B0p + 16 + 4*g);
#pragma unroll
        for (int t=0;t<4;++t){
            float4v a0 = b0, a1 = b1;
            a0 = MFMA16(aW[0][0], bX[t][0], a0, 0,0,0);
            a0 = MFMA16(aW[0][1], bX[t][1], a0, 0,0,0);
            a1 = MFMA16(aW[1][0], bX[t][0], a1, 0,0,0);
            a1 = MFMA16(aW[1][1], bX[t][1], a1, 0,0,0);
            wr16(Sw, 16*t+mrow, g, join8(
                pack4(lrelu(a0[0]), lrelu(a0[1]), lrelu(a0[2]), lrelu(a0[3])),
                pack4(lrelu(a1[0]), lrelu(a1[1]), lrelu(a1[2]), lrelu(a1[3]))));
        }
    }
    __threadfence_block();
    // ---- L1: K=32, OUT=32 ----
    {
        half8 aW[2], bH[4];
#pragma unroll
        for (int n=0;n<2;++n) aW[n] = *(const half8*)(W1 + (16*n+mrow)*32 + 8*g);
#pragma unroll
        for (int t=0;t<4;++t) bH[t] = rd16(Sw, 16*t+mrow, g);
        float4v b0 = *(const float4v*)(B1p + 4*g);
        float4v b1 = *(const float4v*)(B1p + 16 + 4*g);
#pragma unroll
        for (int t=0;t<4;++t){
            float4v a0 = b0, a1 = b1;
            a0 = MFMA16(aW[0], bH[t], a0, 0,0,0);
            a1 = MFMA16(aW[1], bH[t], a1, 0,0,0);
            wr16(Sw, 16*t+mrow, g, join8(
                pack4(lrelu(a0[0]), lrelu(a0[1]), lrelu(a0[2]), lrelu(a0[3])),
                pack4(lrelu(a1[0]), lrelu(a1[1]), lrelu(a1[2]), lrelu(a1[3]))));
        }
    }
    __threadfence_block();
    // ---- L2: K=32, OUT=64 (59 real; outputs 0..39 pre-scaled by LOG2E) ----
    {
        half8 aW[4], bH[4];
#pragma unroll
        for (int n=0;n<4;++n) aW[n] = *(const half8*)(W2 + (16*n+mrow)*32 + 8*g);
#pragma unroll
        for (int t=0;t<4;++t) bH[t] = rd16(Sw, 16*t+mrow, g);
        float4v bb[4];
#pragma unroll
        for (int n=0;n<4;++n) bb[n] = *(const float4v*)(B2p + 16*n + 4*g);
#pragma unroll
        for (int t=0;t<4;++t){
            float4v a0=bb[0], a1=bb[1], a2=bb[2], a3=bb[3];
            a0 = MFMA16(aW[0], bH[t], a0, 0,0,0);
            a1 = MFMA16(aW[1], bH[t], a1, 0,0,0);
            a2 = MFMA16(aW[2], bH[t], a2, 0,0,0);
            a3 = MFMA16(aW[3], bH[t], a3, 0,0,0);
            int row = 16*t + mrow;
            wr16(Sw, row, 2*g,   join8(pack4(a0[0],a0[1],a0[2],a0[3]),
                                       pack4(a1[0],a1[1],a1[2],a1[3])));
            wr16(Sw, row, 2*g+1, join8(pack4(a2[0],a2[1],a2[2],a2[3]),
                                       pack4(a3[0],a3[1],a3[2],a3[3])));
        }
    }
    __threadfence_block();
}

// ---------- spline (noinline, emitted once) ----------
// uw/uh arrive pre-scaled by LOG2E -> exp2 direct, NO max subtraction
// (softmax shift-invariant; |tp| small so exp2 is f32-safe).
__device__ __noinline__ float2 rqs_lds(float x, int tid)
{
    const int l = tid & 63;
    const int swz = l & 7;
    const _Float16* Sw = waveS() + (tid>>6)*4096;

    // widths+heights live in units {0,1,2,3,4,6}; derivs read dynamically below.
    half8 R[8];
    R[0]=rd16(Sw,l,0); R[1]=rd16(Sw,l,1); R[2]=rd16(Sw,l,2);
    R[3]=rd16(Sw,l,3); R[4]=rd16(Sw,l,4); R[6]=rd16(Sw,l,6);
    R[5]=R[4]; R[7]=R[6];   // dead; avoids UB (compile-time q never hits 5/7 for m<40)

    float xc = fminf(fmaxf(x,-1.0f),1.0f);
    float u01 = fmaf(xc, 0.5f, 0.5f);       // walk in normalized cum-space

    int idx = 0; float cumL = 0.0f, wvL = 1.0f;
    {
        float w[20];
#pragma unroll
        for (int i=0;i<20;++i){ int q = qpos(i); w[i] = exp2fast((float)R[q>>3][q&7]); }
        float sw = 0.f;
#pragma unroll
        for (int i=0;i<20;++i) sw += w[i];
        float invw = 0.98f / sw;
        float cum = 0.f;
#pragma unroll
        for (int i=0;i<20;++i){
            float wv = fmaf(invw, w[i], 0.001f);
            if (u01 >= cum){ idx = i; cumL = cum; wvL = wv; }
            cum += wv;
        }
    }
    float inCw = fmaf(2.0f, cumL, -1.0f);
    float inW  = 2.0f * wvL;

    float hcumL = 0.0f, hvL = 1.0f;
    {
        float h[20];
#pragma unroll
        for (int i=0;i<20;++i){ int q = qpos(20+i); h[i] = exp2fast((float)R[q>>3][q&7]); }
        float sh = 0.f;
#pragma unroll
        for (int i=0;i<20;++i) sh += h[i];
        float invh = 0.98f / sh;
        float hcum = 0.f;
#pragma unroll
        for (int i=0;i<20;++i){
            float hv = fmaf(invh, h[i], 0.001f);
            if (i == idx){ hcumL = hcum; hvL = hv; }
            hcum += hv;
        }
    }
    float inCh = fmaf(2.0f, hcumL, -1.0f);
    float inH  = 2.0f * hvL;

    // derivs: udl = idx>0 ? tp[39+idx] : TAILC ; udr = idx<19 ? tp[40+idx] : TAILC
    auto rdq = [&](int m)->float{
        int q = 16*((m>>2)&3) + 8*((m>>4)>>1) + 4*((m>>4)&1) + (m&3);
        return (float)Sw[l*64 + (((q>>3) ^ swz)<<3) + (q&7)];
    };
    float dl = rdq(39+idx);
    float dr = rdq(40+idx);
    float udl = (idx>0)  ? dl : TAILC;
    float udr = (idx<19) ? dr : TAILC;

    float inD   = 0.001f + softplus_(udl);
    float inDp1 = 0.001f + softplus_(udr);
    float inDelta = inH / inW;
    float th  = (xc - inCw) / inW;
    float omt = 1.0f - th;
    float t1  = th * omt;
    float num = inH * (inDelta*th*th + inD*t1);
    float den = inDelta + (inD + inDp1 - 2.0f*inDelta)*t1;
    float y = inCh + num/den;
    float dnum = inDelta*inDelta*(inDp1*th*th + 2.0f*inDelta*t1 + inD*omt*omt);
    float lad = LN2 * (log2fast(dnum) - 2.0f*log2fast(den));
    bool inside = (x >= -1.0f) && (x <= 1.0f);
    return make_float2(inside ? y : x, inside ? lad : 0.0f);
}

__global__ __launch_bounds__(256,4) void nsf_mfma(
    const float* __restrict__ wi, const float* __restrict__ cond,
    const _Float16* __restrict__ wsp,
    const float* __restrict__ p0_b1,
    float* __restrict__ out)
{
    const int tid = threadIdx.x;
    const int l = tid & 63, wid = tid >> 6;
    const int i = blockIdx.x*256 + wid*64 + l;
    _Float16* Sw = waveS() + wid*4096;
    const int mrow = l & 15, g = (l >> 4) & 3;
    const float* wsf = (const float*)(wsp + WS_F16);

    float2 wv2 = reinterpret_cast<const float2*>(wi)[i];
    float w0v = wv2.x, w1v = wv2.y;
    float c[10];
    {
        const float2* cp2 = reinterpret_cast<const float2*>(cond + (size_t)i*10);
#pragma unroll
        for (int k=0;k<5;++k){ float2 t2 = cp2[k]; c[2*k]=t2.x; c[2*k+1]=t2.y; }
    }

    // cond_e -> f16 chunks A0..A3 (cols 0..31, incl. 2 zero pads)
    half8 A0, A1, A2, A3, Z;
#pragma unroll
    for (int j=0;j<8;++j) Z[j] = (_Float16)0.0f;
    {
        _Float16 ce[30];
        ce[0] = (_Float16)c[8];
        ce[1] = (_Float16)c[9];
        float f = 1.0f;
#pragma unroll
        for (int fi=0; fi<5; ++fi){
            float s8,c8v,s9,c9v;
            __sincosf(c[8]*f, &s8, &c8v);
            __sincosf(c[9]*f, &s9, &c9v);
            ce[2+4*fi+0]=(_Float16)s8;  ce[2+4*fi+1]=(_Float16)s9;
            ce[2+4*fi+2]=(_Float16)c8v; ce[2+4*fi+3]=(_Float16)c9v;
            f *= 2.0f;
        }
#pragma unroll
        for (int k=0;k<8;++k) ce[22+k] = (_Float16)c[k];
#pragma unroll
        for (int j=0;j<8;++j){ A0[j]=ce[j]; A1[j]=ce[8+j]; A2[j]=ce[16+j]; }
#pragma unroll
        for (int j=0;j<8;++j) A3[j] = (j<6) ? ce[24+j] : (_Float16)0.0f;
    }

    auto mkPE = [&](float t, half8& P0, half8& P1){
        float s1,c1v,s2,c2v,s3,c3v,s4,c4v;
        __sincosf(t*1.0f,       &s1,&c1v);
        __sincosf(t*3.3333333f, &s2,&c2v);
        __sincosf(t*5.6666665f, &s3,&c3v);
        __sincosf(t*8.0f,       &s4,&c4v);
        P0[0]=(_Float16)t;   P0[1]=(_Float16)s1; P0[2]=(_Float16)c1v; P0[3]=(_Float16)s2;
        P0[4]=(_Float16)c2v; P0[5]=(_Float16)s3; P0[6]=(_Float16)c3v; P0[7]=(_Float16)s4;
        P1 = Z; P1[0] = (_Float16)c4v;
    };

    // ---- m1: stage xin(w1v), MLP, spline on w0 ----
    half8 P0, P1;
    mkPE(w1v, P0, P1);
    wr16(Sw,l,0,A0); wr16(Sw,l,1,A1); wr16(Sw,l,2,A2); wr16(Sw,l,3,A3);
    wr16(Sw,l,4,P0); wr16(Sw,l,5,P1); wr16(Sw,l,6,Z);  wr16(Sw,l,7,Z);
    __threadfence_block();
    mlp_lds(tid, wsp+OFF_M1_W0T, wsp+OFF_M1_W1T, wsp+OFF_M1_W2T,
            wsf+FB_M1_B0, wsf+FB_M1_B1, wsf+FB_M1_B2);
    float2 r0 = rqs_lds(w0v, tid);
    float y0 = r0.x, ld0 = r0.y;

    // ---- m0: stage xin(y0), MLP, spline on w1 ----
    mkPE(y0, P0, P1);
    wr16(Sw,l,0,A0); wr16(Sw,l,1,A1); wr16(Sw,l,2,A2); wr16(Sw,l,3,A3);
    wr16(Sw,l,4,P0); wr16(Sw,l,5,P1); wr16(Sw,l,6,Z);  wr16(Sw,l,7,Z);
    __threadfence_block();
    mlp_lds(tid, wsp+OFF_M0_W0T, wsp+OFF_M0_W1T, wsp+OFF_M0_W2T,
            wsf+FB_M0_B0, wsf+FB_M0_B1, wsf+FB_M0_B2);
    float2 r1 = rqs_lds(w1v, tid);
    float y1 = r1.x, ld1 = r1.y;

    // ---- p0: cond_e(30,+2pad) -> 32 (lrelu) via swapped MFMA ----
    wr16(Sw,l,0,A0); wr16(Sw,l,1,A1); wr16(Sw,l,2,A2); wr16(Sw,l,3,A3);
    __threadfence_block();
    {
        half8 aW[2], bC[4];
#pragma unroll
        for (int n=0;n<2;++n) aW[n] = *(const half8*)(wsp + OFF_P0_W0T + (16*n+mrow)*32 + 8*g);
#pragma unroll
        for (int t=0;t<4;++t) bC[t] = rd16(Sw, 16*t+mrow, g);
        const float* PB = wsf + FB_P0_B0;
        float4v b0 = *(const float4v*)(PB + 4*g);
        float4v b1 = *(const float4v*)(PB + 16 + 4*g);
#pragma unroll
        for (int t=0;t<4;++t){
            float4v a0 = b0, a1 = b1;
            a0 = MFMA16(aW[0], bC[t], a0, 0,0,0);
            a1 = MFMA16(aW[1], bC[t], a1, 0,0,0);
            wr16(Sw, 16*t+mrow, g, join8(
                pack4(lrelu(a0[0]), lrelu(a0[1]), lrelu(a0[2]), lrelu(a0[3])),
                pack4(lrelu(a1[0]), lrelu(a1[1]), lrelu(a1[2]), lrelu(a1[3]))));
        }
    }
    __threadfence_block();

    // ---- tail: per-thread 32 -> 4 via fdot2 (permuted unpack) ----
    float r4[4] = {p0_b1[0], p0_b1[1], p0_b1[2], p0_b1[3]};
    {
        half8 Tq[4];
#pragma unroll
        for (int u=0;u<4;++u) Tq[u] = rd16(Sw, l, u);
        const u32* pw = (const u32*)(wsf + FB_PW1);
#pragma unroll
        for (int k2=0;k2<16;++k2){
            int p = ppos(2*k2);                 // pair (2k2, 2k2+1) is position-adjacent
            h2 x; x[0] = Tq[p>>3][p&7]; x[1] = Tq[(p+1)>>3][(p+1)&7];
#pragma unroll
            for (int j=0;j<4;++j) r4[j] = fdot2(x, u2h2(pw[k2*4+j]), r4[j]);
        }
    }

    float mu0=r4[0], mu1=r4[1], ls0=r4[2], ls1=r4[3];
    float is0 = __expf(-ls0), is1 = __expf(-ls1);
    float e0 = (y0-mu0)*is0, e1 = (y1-mu1)*is1;
    float rr = e0*e0 + e1*e1;
    float lp = -(ls0+ls1) - 1.8378770664093453f - 0.5f*rr + ld0 + ld1;

    reinterpret_cast<float2*>(out)[i] = make_float2(y0, y1);
    out[2*(size_t)N_PTS + i] = lp;
}

// ---------------- fallback all-f32 kernel (known-good R1) ----------------
__device__ __forceinline__ float softplus_ref(float x){
    return fmaxf(x, 0.0f) + log1pf(__expf(-fabsf(x)));
}
__device__ __forceinline__ void rqs_f32(float x, float* tp, float& yo, float& lado)
{
    float mw = tp[0];
#pragma unroll
    for (int i=1;i<20;++i) mw = fmaxf(mw, tp[i]);
    float sw = 0.f;
#pragma unroll
    for (int i=0;i<20;++i){ tp[i] = __expf(tp[i]-mw); sw += tp[i]; }
    float invw = 0.98f / sw;
    float mh = tp[20];
#pragma unroll
    for (int i=1;i<20;++i) mh = fmaxf(mh, tp[20+i]);
    float sh = 0.f;
#pragma unroll
    for (int i=0;i<20;++i){ tp[20+i] = __expf(tp[20+i]-mh); sh += tp[20+i]; }
    float invh = 0.98f / sh;
    float xc = fminf(fmaxf(x,-1.0f),1.0f);
    float cum = 0.f; int idx = 0;
    float inCw = -1.0f, inW = 1.0f;
#pragma unroll
    for (int i=0;i<20;++i){
        float wv = fmaf(invw, tp[i], 0.001f);
        float cwL = (i==0) ? -1.0f : fmaf(2.0f, cum, -1.0f);
        float cumN = cum + wv;
        float cwR = (i==19) ? 1.0f : fmaf(2.0f, cumN, -1.0f);
        if (xc >= cwL){ idx = i; inCw = cwL; inW = cwR - cwL; }
        cum = cumN;
    }
    float hcum = 0.f; float inCh = -1.0f, inH = 1.0f;
#pragma unroll
    for (int i=0;i<20;++i){
        float hv = fmaf(invh, tp[20+i], 0.001f);
        float chL = (i==0) ? -1.0f : fmaf(2.0f, hcum, -1.0f);
        float hcumN = hcum + hv;
        float chR = (i==19) ? 1.0f : fmaf(2.0f, hcumN, -1.0f);
        if (i == idx){ inCh = chL; inH = chR - chL; }
        hcum = hcumN;
    }
    float udl = TAILC, udr = TAILC;
#pragma unroll
    for (int t=0;t<19;++t){
        if (idx == t+1) udl = tp[40+t];
        if (idx == t)   udr = tp[40+t];
    }
    float inD   = 0.001f + softplus_ref(udl);
    float inDp1 = 0.001f + softplus_ref(udr);
    float inDelta = inH / inW;
    float th  = (xc - inCw) / inW;
    float omt = 1.0f - th;
    float t1  = th * omt;
    float num = inH * (inDelta*th*th + inD*t1);
    float den = inDelta + (inD + inDp1 - 2.0f*inDelta)*t1;
    float y = inCh + num/den;
    float dnum = inDelta*inDelta*(inDp1*th*th + 2.0f*inDelta*t1 + inD*omt*omt);
    float lad = __logf(dnum) - 2.0f*__logf(den);
    bool inside = (x >= -1.0f) && (x <= 1.0f);
    yo   = inside ? y   : x;
    lado = inside ? lad : 0.0f;
}
template<int OUTW>
__device__ __forceinline__ void addrow(float v, const float* __restrict__ Wrow, float* acc){
#pragma unroll
    for (int j=0;j<OUTW;++j) acc[j] = fmaf(v, Wrow[j], acc[j]);
}
template<int KIN, int OUT>
__device__ __forceinline__ void dense(const float* x, const float* __restrict__ W,
        const float* __restrict__ B, float* acc){
#pragma unroll
    for (int j=0;j<OUT;++j) acc[j] = B[j];
#pragma unroll
    for (int k=0;k<KIN;++k){
#pragma unroll
        for (int j=0;j<OUT;++j) acc[j] = fmaf(x[k], W[k*OUT+j], acc[j]);
    }
}
__device__ __forceinline__ void mlp_layer0(float t, const float* c,
        const float* __restrict__ W0, const float* __restrict__ B0, float* h)
{
#pragma unroll
    for (int j=0;j<32;++j) h[j] = B0[j];
    addrow<32>(t, W0 + 0*32, h);
    float s, co;
    __sincosf(t*1.0f,       &s,&co); addrow<32>(s, W0+1*32, h); addrow<32>(co, W0+2*32, h);
    __sincosf(t*3.3333333f, &s,&co); addrow<32>(s, W0+3*32, h); addrow<32>(co, W0+4*32, h);
    __sincosf(t*5.6666665f, &s,&co); addrow<32>(s, W0+5*32, h); addrow<32>(co, W0+6*32, h);
    __sincosf(t*8.0f,       &s,&co); addrow<32>(s, W0+7*32, h); addrow<32>(co, W0+8*32, h);
    addrow<32>(c[8], W0 + 9*32, h);
    addrow<32>(c[9], W0 +10*32, h);
    float f = 1.0f;
#pragma unroll
    for (int fi=0; fi<5; ++fi){
        float s8,c8v,s9,c9v;
        __sincosf(c[8]*f, &s8, &c8v);
        __sincosf(c[9]*f, &s9, &c9v);
        addrow<32>(s8,  W0 + (11+4*fi)*32, h);
        addrow<32>(s9,  W0 + (12+4*fi)*32, h);
        addrow<32>(c8v, W0 + (13+4*fi)*32, h);
        addrow<32>(c9v, W0 + (14+4*fi)*32, h);
        f *= 2.0f;
    }
#pragma unroll
    for (int k=0;k<8;++k) addrow<32>(c[k], W0 + (31+k)*32, h);
#pragma unroll
    for (int j=0;j<32;++j) h[j] = lrelu(h[j]);
}
__global__ __launch_bounds__(256,3) void nsf_kernel_f32(
    const float* __restrict__ wi, const float* __restrict__ cond,
    const float* __restrict__ p0_w0, const float* __restrict__ p0_b0,
    const float* __restrict__ p0_w1, const float* __restrict__ p0_b1,
    const float* __restrict__ m1_w0, const float* __restrict__ m1_b0,
    const float* __restrict__ m1_w1, const float* __restrict__ m1_b1,
    const float* __restrict__ m1_w2, const float* __restrict__ m1_b2,
    const float* __restrict__ m0_w0, const float* __restrict__ m0_b0,
    const float* __restrict__ m0_w1, const float* __restrict__ m0_b1,
    const float* __restrict__ m0_w2, const float* __restrict__ m0_b2,
    float* __restrict__ out)
{
    const int i = blockIdx.x*256 + threadIdx.x;
    float2 wv2 = reinterpret_cast<const float2*>(wi)[i];
    float w0v = wv2.x, w1v = wv2.y;
    const float* cp = cond + (size_t)i*10;
    float c[10];
#pragma unroll
    for (int k=0;k<10;++k) c[k] = cp[k];

    float tp[59];
    {
        float h[32], gg[32];
        mlp_layer0(w1v, c, m1_w0, m1_b0, h);
        dense<32,32>(h, m1_w1, m1_b1, gg);
#pragma unroll
        for (int j=0;j<32;++j) gg[j] = lrelu(gg[j]);
        dense<32,59>(gg, m1_w2, m1_b2, tp);
    }
    float y0, ld0; rqs_f32(w0v, tp, y0, ld0);
    {
        float h[32], gg[32];
        mlp_layer0(y0, c, m0_w0, m0_b0, h);
        dense<32,32>(h, m0_w1, m0_b1, gg);
#pragma unroll
        for (int j=0;j<32;++j) gg[j] = lrelu(gg[j]);
        dense<32,59>(gg, m0_w2, m0_b2, tp);
    }
    float y1, ld1; rqs_f32(w1v, tp, y1, ld1);

    float r[4];
    {
        float ph[32];
#pragma unroll
        for (int j=0;j<32;++j) ph[j] = p0_b0[j];
        addrow<32>(c[8], p0_w0 + 0*32, ph);
        addrow<32>(c[9], p0_w0 + 1*32, ph);
        float f = 1.0f;
#pragma unroll
        for (int fi=0; fi<5; ++fi){
            float s8,c8v,s9,c9v;
            __sincosf(c[8]*f, &s8, &c8v);
            __sincosf(c[9]*f, &s9, &c9v);
            addrow<32>(s8,  p0_w0 + (2+4*fi)*32, ph);
            addrow<32>(s9,  p0_w0 + (3+4*fi)*32, ph);
            addrow<32>(c8v, p0_w0 + (4+4*fi)*32, ph);
            addrow<32>(c9v, p0_w0 + (5+4*fi)*32, ph);
            f *= 2.0f;
        }
#pragma unroll
        for (int k=0;k<8;++k) addrow<32>(c[k], p0_w0 + (22+k)*32, ph);
#pragma unroll
        for (int j=0;j<32;++j) ph[j] = lrelu(ph[j]);
        dense<32,4>(ph, p0_w1, p0_b1, r);
    }

    float mu0=r[0], mu1=r[1], ls0=r[2], ls1=r[3];
    float is0 = __expf(-ls0), is1 = __expf(-ls1);
    float e0 = (y0-mu0)*is0, e1 = (y1-mu1)*is1;
    float rr = e0*e0 + e1*e1;
    float lp = -(ls0+ls1) - 1.8378770664093453f - 0.5f*rr + ld0 + ld1;

    reinterpret_cast<float2*>(out)[i] = make_float2(y0, y1);
    out[2*(size_t)N_PTS + i] = lp;
}

extern "C" void kernel_launch(void* const* d_in, const int* in_sizes, int n_in,
                              void* d_out, int out_size, void* d_ws, size_t ws_size,
                              hipStream_t stream)
{
    const float* wi    = (const float*)d_in[0];
    const float* cond  = (const float*)d_in[1];
    const float* p0_w0 = (const float*)d_in[2];
    const float* p0_b0 = (const float*)d_in[3];
    const float* p0_w1 = (const float*)d_in[4];
    const float* p0_b1 = (const float*)d_in[5];
    const float* m1_w0 = (const float*)d_in[6];
    const float* m1_b0 = (const float*)d_in[7];
    const float* m1_w1 = (const float*)d_in[8];
    const float* m1_b1 = (const float*)d_in[9];
    const float* m1_w2 = (const float*)d_in[10];
    const float* m1_b2 = (const float*)d_in[11];
    const float* m0_w0 = (const float*)d_in[12];
    const float* m0_b0 = (const float*)d_in[13];
    const float* m0_w1 = (const float*)d_in[14];
    const float* m0_b1 = (const float*)d_in[15];
    const float* m0_w2 = (const float*)d_in[16];
    const float* m0_b2 = (const float*)d_in[17];
    float* out = (float*)d_out;

    dim3 block(256);
    if (ws_size >= (size_t)WS_BYTES) {
        _Float16* wsp = (_Float16*)d_ws;
        hipLaunchKernelGGL(pack_weights, dim3((PACK_ITEMS+255)/256), block, 0, stream,
            m1_w0, m1_w1, m1_w2, m0_w0, m0_w1, m0_w2, p0_w0, p0_w1,
            m1_b0, m1_b1, m1_b2, m0_b0, m0_b1, m0_b2, p0_b0, wsp);
        hipLaunchKernelGGL(nsf_mfma, dim3(N_PTS/256), block, 0, stream,
            wi, cond, wsp, p0_b1, out);
    } else {
        hipLaunchKernelGGL(nsf_kernel_f32, dim3(N_PTS/256), block, 0, stream,
            wi, cond, p0_w0, p0_b0, p0_w1, p0_b1,
            m1_w0, m1_b0, m1_w1, m1_b1, m1_w2, m1_b2,
            m0_w0, m0_b0, m0_w1, m0_b1, m0_w2, m0_b2, out);
    }
}

// Round 12
// 127.729 us; speedup vs baseline: 5.7458x; 1.0297x over previous
//
#include <hip/hip_runtime.h>
#include <math.h>

#define N_PTS 2097152
#define TAILC 0.53974324f   // log(exp(1-0.001)-1)
#define LOG2E 1.4426950408889634f
#define LN2   0.6931471805599453f

typedef unsigned int u32;
typedef _Float16 half8 __attribute__((ext_vector_type(8)));
typedef _Float16 half4 __attribute__((ext_vector_type(4)));
typedef _Float16 h2    __attribute__((ext_vector_type(2)));
typedef __fp16   fp16x2 __attribute__((ext_vector_type(2)));
typedef float float4v  __attribute__((ext_vector_type(4)));

#define MFMA16 __builtin_amdgcn_mfma_f32_16x16x32_f16

__device__ __forceinline__ float lrelu(float x){ return x > 0.0f ? x : 0.01f*x; }
__device__ __forceinline__ float exp2fast(float x){
#if __has_builtin(__builtin_amdgcn_exp2f)
    return __builtin_amdgcn_exp2f(x);
#else
    return exp2f(x);
#endif
}
__device__ __forceinline__ float log2fast(float x){
#if __has_builtin(__builtin_amdgcn_logf)
    return __builtin_amdgcn_logf(x);
#else
    return __log2f(x);
#endif
}
// softplus(x) = ln2 * log2(1 + exp2(x*log2e)); f32-safe for |x| < ~80
__device__ __forceinline__ float softplus_(float x){
    return LN2 * log2fast(1.0f + exp2fast(x * LOG2E));
}
__device__ __forceinline__ half4 pack4(float a0, float a1, float a2, float a3){
#if __has_builtin(__builtin_amdgcn_cvt_pkrtz)
    union { fp16x2 f; h2 h; } lo, hi;
    lo.f = __builtin_amdgcn_cvt_pkrtz(a0, a1);
    hi.f = __builtin_amdgcn_cvt_pkrtz(a2, a3);
    half4 r; r[0]=lo.h[0]; r[1]=lo.h[1]; r[2]=hi.h[0]; r[3]=hi.h[1];
    return r;
#else
    half4 r; r[0]=(_Float16)a0; r[1]=(_Float16)a1; r[2]=(_Float16)a2; r[3]=(_Float16)a3;
    return r;
#endif
}
// packed f16 leaky-relu: v_pk_mul_f16 + v_pk_max_f16 via elementwise builtins
__device__ __forceinline__ h2 lrelu2(h2 x){
#if __has_builtin(__builtin_elementwise_max)
    h2 m = x * (_Float16)0.01f;
    return __builtin_elementwise_max(x, m);
#else
    h2 r; r[0] = (x[0] > (_Float16)0 ? x[0] : x[0]*(_Float16)0.01f);
    r[1] = (x[1] > (_Float16)0 ? x[1] : x[1]*(_Float16)0.01f);
    return r;
#endif
}
// pack 4 f32 -> 4 f16 then leaky-relu in PACKED f16
__device__ __forceinline__ half4 pack4_lrelu(float a0, float a1, float a2, float a3){
#if __has_builtin(__builtin_amdgcn_cvt_pkrtz)
    union { fp16x2 f; h2 h; } lo, hi;
    lo.f = __builtin_amdgcn_cvt_pkrtz(a0, a1);
    hi.f = __builtin_amdgcn_cvt_pkrtz(a2, a3);
    h2 lm = lrelu2(lo.h), hm = lrelu2(hi.h);
    half4 r; r[0]=lm[0]; r[1]=lm[1]; r[2]=hm[0]; r[3]=hm[1];
    return r;
#else
    return pack4(lrelu(a0), lrelu(a1), lrelu(a2), lrelu(a3));
#endif
}
__device__ __forceinline__ half8 join8(half4 a, half4 b){
    half8 r; r[0]=a[0]; r[1]=a[1]; r[2]=a[2]; r[3]=a[3];
    r[4]=b[0]; r[5]=b[1]; r[6]=b[2]; r[7]=b[3];
    return r;
}
__device__ __forceinline__ float fdot2(h2 a, h2 b, float c){
#if __has_builtin(__builtin_amdgcn_fdot2)
    return __builtin_amdgcn_fdot2(a, b, c, false);
#else
    return fmaf((float)a[0],(float)b[0], fmaf((float)a[1],(float)b[1], c));
#endif
}
__device__ __forceinline__ h2 u2h2(u32 u){ union{u32 a; h2 b;} x; x.a=u; return x.b; }

// physical position of logical output o for 32-wide layers (p = 8g + 4n + j, o = 16n+4g+j)
__device__ __host__ constexpr int ppos(int o){
    return 8*((o>>2)&3) + 4*(o>>4) + (o&3);
}
// physical position of logical output m for the 64-wide L2 layer
__device__ __host__ constexpr int qpos(int m){
    return 16*((m>>2)&3) + 8*((m>>4)>>1) + 4*((m>>4)&1) + (m&3);
}
// inverse: logical o at physical p (32-wide)
__device__ __host__ constexpr int pinv(int p){
    return 16*((p>>2)&1) + 4*(p>>3) + (p&3);
}

// Single shared allocation reachable from kernel AND noinline callees.
__device__ __forceinline__ _Float16* waveS(){
    __shared__ _Float16 S[4][4096];    // per-wave [64 rows][64 f16], swizzled
    return &S[0][0];
}
__device__ __forceinline__ half8 rd16(const _Float16* Sw, int row, int u){
    return *(const half8*)(Sw + row*64 + ((u ^ (row&7))<<3));
}
__device__ __forceinline__ void wr16(_Float16* Sw, int row, int u, half8 v){
    *(half8*)(Sw + row*64 + ((u ^ (row&7))<<3)) = v;
}

// ---- packed weights/biases in d_ws ----
#define OFF_M1_W0T 0        // [32][64]
#define OFF_M1_W1T 2048     // [32][32]
#define OFF_M1_W2T 3072     // [64][32]
#define OFF_M0_W0T 5120
#define OFF_M0_W1T 7168
#define OFF_M0_W2T 8192
#define OFF_P0_W0T 10240    // [32][32]
#define WS_F16     11264
// f32 region (byte 22528)
#define FB_M1_B0   0
#define FB_M1_B1   32
#define FB_M1_B2   64       // padded to 64, outputs 0..39 pre-scaled by LOG2E
#define FB_M0_B0   128
#define FB_M0_B1   160
#define FB_M0_B2   192
#define FB_P0_B0   256
#define FB_PW1     288      // 64 u32: p0_w1 packed h2 pairs
#define WS_BYTES   (22528 + 288*4 + 64*4)
#define PACK_ITEMS (WS_F16 + 288 + 64)

__global__ void pack_weights(const float* __restrict__ m1_w0, const float* __restrict__ m1_w1,
                             const float* __restrict__ m1_w2, const float* __restrict__ m0_w0,
                             const float* __restrict__ m0_w1, const float* __restrict__ m0_w2,
                             const float* __restrict__ p0_w0, const float* __restrict__ p0_w1,
                             const float* __restrict__ m1_b0, const float* __restrict__ m1_b1,
                             const float* __restrict__ m1_b2, const float* __restrict__ m0_b0,
                             const float* __restrict__ m0_b1, const float* __restrict__ m0_b2,
                             const float* __restrict__ p0_b0, _Float16* __restrict__ ws)
{
    int idx = blockIdx.x*256 + threadIdx.x;
    if (idx >= PACK_ITEMS) return;
    if (idx < WS_F16) {
        float v = 0.0f;
        if (idx < 2048 || (idx >= 5120 && idx < 7168)) {          // W0T [32][64], k logical
            const float* W = (idx < 2048) ? m1_w0 : m0_w0;
            int r = (idx < 2048) ? idx : idx - 5120;
            int o = r >> 6, k = r & 63;
            if (k < 30)                 v = W[(9+k)*32 + o];
            else if (k >= 32 && k < 41) v = W[(k-32)*32 + o];
        } else if (idx < 3072 || (idx >= 7168 && idx < 8192)) {   // W1T [32][32], k permuted
            const float* W = (idx < 3072) ? m1_w1 : m0_w1;
            int r = (idx < 3072) ? idx - 2048 : idx - 7168;
            int o = r >> 5, p = r & 31;
            v = W[pinv(p)*32 + o];
        } else if (idx < 5120 || (idx >= 8192 && idx < 10240)) {  // W2T [64][32], k permuted, rows<40 scaled
            const float* W = (idx < 5120) ? m1_w2 : m0_w2;
            int r = (idx < 5120) ? idx - 3072 : idx - 8192;
            int o = r >> 5, p = r & 31;
            if (o < 59) {
                v = W[pinv(p)*59 + o];
                if (o < 40) v *= LOG2E;
            }
        } else {                                                  // p0 W0T [32][32], k logical
            int r = idx - 10240;
            int o = r >> 5, k = r & 31;
            if (k < 30) v = p0_w0[k*32 + o];
        }
        ws[idx] = (_Float16)v;
        return;
    }
    float* wsf = (float*)(ws + WS_F16);
    int bi = idx - WS_F16;
    if (bi < 288) {
        float v = 0.0f;
        if      (bi < 32)  v = m1_b0[bi];
        else if (bi < 64)  v = m1_b1[bi-32];
        else if (bi < 128) { int o = bi-64;  if (o < 59) { v = m1_b2[o]; if (o < 40) v *= LOG2E; } }
        else if (bi < 160) v = m0_b0[bi-128];
        else if (bi < 192) v = m0_b1[bi-160];
        else if (bi < 256) { int o = bi-192; if (o < 59) { v = m0_b2[o]; if (o < 40) v *= LOG2E; } }
        else               v = p0_b0[bi-256];
        wsf[bi] = v;
        return;
    }
    int pi = bi - 288;            // 0..63 : p0_w1 packed pairs
    int k2 = pi >> 2, j = pi & 3;
    union{ _Float16 h; unsigned short s; } a, b;
    a.h = (_Float16)p0_w1[(2*k2)*4 + j];
    b.h = (_Float16)p0_w1[(2*k2+1)*4 + j];
    ((u32*)(wsf + FB_PW1))[pi] = (u32)a.s | ((u32)b.s << 16);
}

// ---------- one transform MLP (noinline, emitted once), swapped-operand MFMA ----------
__device__ __noinline__ void mlp_lds(int tid,
    const _Float16* __restrict__ W0, const _Float16* __restrict__ W1,
    const _Float16* __restrict__ W2,
    const float* __restrict__ B0p, const float* __restrict__ B1p,
    const float* __restrict__ B2p)
{
    _Float16* Sw = waveS() + (tid>>6)*4096;
    const int l = tid & 63, mrow = l & 15, g = (l >> 4) & 3;

    // ---- L0: K=64 (2 ksteps), OUT=32 ----
    {
        half8 aW[2][2], bX[4][2];
#pragma unroll
        for (int n=0;n<2;++n)
#pragma unroll
            for (int s=0;s<2;++s)
                aW[n][s] = *(const half8*)(W0 + (16*n+mrow)*64 + 32*s + 8*g);
#pragma unroll
        for (int t=0;t<4;++t){
            int pt = 16*t + mrow;
#pragma unroll
            for (int s=0;s<2;++s) bX[t][s] = rd16(Sw, pt, 4*s+g);
        }
        float4v b0 = *(const float4v*)(B0p + 4*g);
        float4v b1 = *(const float4v*)(B0p + 16 + 4*g);
#pragma unroll
        for (int t=0;t<4;++t){
            float4v a0 = b0, a1 = b1;
            a0 = MFMA16(aW[0][0], bX[t][0], a0, 0,0,0);
            a0 = MFMA16(aW[0][1], bX[t][1], a0, 0,0,0);
            a1 = MFMA16(aW[1][0], bX[t][0], a1, 0,0,0);
            a1 = MFMA16(aW[1][1], bX[t][1], a1, 0,0,0);
            wr16(Sw, 16*t+mrow, g, join8(
                pack4_lrelu(a0[0], a0[1], a0[2], a0[3]),
                pack4_lrelu(a1[0], a1[1], a1[2], a1[3])));
        }
    }
    __threadfence_block();
    // ---- L1: K=32, OUT=32 ----
    {
        half8 aW[2], bH[4];
#pragma unroll
        for (int n=0;n<2;++n) aW[n] = *(const half8*)(W1 + (16*n+mrow)*32 + 8*g);
#pragma unroll
        for (int t=0;t<4;++t) bH[t] = rd16(Sw, 16*t+mrow, g);
        float4v b0 = *(const float4v*)(B1p + 4*g);
        float4v b1 = *(const float4v*)(B1p + 16 + 4*g);
#pragma unroll
        for (int t=0;t<4;++t){
            float4v a0 = b0, a1 = b1;
            a0 = MFMA16(aW[0], bH[t], a0, 0,0,0);
            a1 = MFMA16(aW[1], bH[t], a1, 0,0,0);
            wr16(Sw, 16*t+mrow, g, join8(
                pack4_lrelu(a0[0], a0[1], a0[2], a0[3]),
                pack4_lrelu(a1[0], a1[1], a1[2], a1[3])));
        }
    }
    __threadfence_block();
    // ---- L2: K=32, OUT=64 (59 real; outputs 0..39 pre-scaled by LOG2E) ----
    {
        half8 aW[4], bH[4];
#pragma unroll
        for (int n=0;n<4;++n) aW[n] = *(const half8*)(W2 + (16*n+mrow)*32 + 8*g);
#pragma unroll
        for (int t=0;t<4;++t) bH[t] = rd16(Sw, 16*t+mrow, g);
        float4v bb[4];
#pragma unroll
        for (int n=0;n<4;++n) bb[n] = *(const float4v*)(B2p + 16*n + 4*g);
#pragma unroll
        for (int t=0;t<4;++t){
            float4v a0=bb[0], a1=bb[1], a2=bb[2], a3=bb[3];
            a0 = MFMA16(aW[0], bH[t], a0, 0,0,0);
            a1 = MFMA16(aW[1], bH[t], a1, 0,0,0);
            a2 = MFMA16(aW[2], bH[t], a2, 0,0,0);
            a3 = MFMA16(aW[3], bH[t], a3, 0,0,0);
            int row = 16*t + mrow;
            wr16(Sw, row, 2*g,   join8(pack4(a0[0],a0[1],a0[2],a0[3]),
                                       pack4(a1[0],a1[1],a1[2],a1[3])));
            wr16(Sw, row, 2*g+1, join8(pack4(a2[0],a2[1],a2[2],a2[3]),
                                       pack4(a3[0],a3[1],a3[2],a3[3])));
        }
    }
    __threadfence_block();
}

// ---------- spline (noinline, emitted once) ----------
// uw/uh arrive pre-scaled by LOG2E -> exp2 direct, NO max subtraction.
// Single merged walk: both (cum,wv) and (hcum,hv) selected under u01>=cum.
__device__ __noinline__ float2 rqs_lds(float x, int tid)
{
    const int l = tid & 63;
    const int swz = l & 7;
    const _Float16* Sw = waveS() + (tid>>6)*4096;

    // widths+heights live in units {0,1,2,3,4,6}; derivs read dynamically below.
    half8 R[8];
    R[0]=rd16(Sw,l,0); R[1]=rd16(Sw,l,1); R[2]=rd16(Sw,l,2);
    R[3]=rd16(Sw,l,3); R[4]=rd16(Sw,l,4); R[6]=rd16(Sw,l,6);
    R[5]=R[4]; R[7]=R[6];   // dead (q never hits 5/7 for m<40); avoids UB

    float xc = fminf(fmaxf(x,-1.0f),1.0f);
    float u01 = fmaf(xc, 0.5f, 0.5f);       // walk in normalized cum-space

    float w[20], h[20];
#pragma unroll
    for (int i=0;i<20;++i){ int q = qpos(i);    w[i] = exp2fast((float)R[q>>3][q&7]); }
#pragma unroll
    for (int i=0;i<20;++i){ int q = qpos(20+i); h[i] = exp2fast((float)R[q>>3][q&7]); }
    float sw = 0.f, sh = 0.f;
#pragma unroll
    for (int i=0;i<20;++i){ sw += w[i]; sh += h[i]; }
    float invw = 0.98f / sw;
    float invh = 0.98f / sh;

    int idx = 0;
    float cumL = 0.0f, wvL = 1.0f, hcumL = 0.0f, hvL = 1.0f;
    float cum = 0.f, hcum = 0.f;
#pragma unroll
    for (int i=0;i<20;++i){
        float wv = fmaf(invw, w[i], 0.001f);
        float hv = fmaf(invh, h[i], 0.001f);
        if (u01 >= cum){ idx = i; cumL = cum; wvL = wv; hcumL = hcum; hvL = hv; }
        cum += wv; hcum += hv;
    }

    // derivs: udl = idx>0 ? tp[39+idx] : TAILC ; udr = idx<19 ? tp[40+idx] : TAILC
    auto rdq = [&](int m)->float{
        int q = 16*((m>>2)&3) + 8*((m>>4)>>1) + 4*((m>>4)&1) + (m&3);
        return (float)Sw[l*64 + (((q>>3) ^ swz)<<3) + (q&7)];
    };
    float dl = rdq(39+idx);
    float dr = rdq(40+idx);
    float udl = (idx>0)  ? dl : TAILC;
    float udr = (idx<19) ? dr : TAILC;

    float inD   = 0.001f + softplus_(udl);
    float inDp1 = 0.001f + softplus_(udr);
    float inDelta = hvL / wvL;              // (2hvL)/(2wvL)
    float inH  = 2.0f * hvL;
    float inCh = fmaf(2.0f, hcumL, -1.0f);
    float th  = (u01 - cumL) / wvL;         // == (xc - inCw)/inW
    float omt = 1.0f - th;
    float t1  = th * omt;
    float num = inH * (inDelta*th*th + inD*t1);
    float den = inDelta + (inD + inDp1 - 2.0f*inDelta)*t1;
    float y = inCh + num/den;
    float dnum = inDelta*inDelta*(inDp1*th*th + 2.0f*inDelta*t1 + inD*omt*omt);
    float lad = LN2 * (log2fast(dnum) - 2.0f*log2fast(den));
    bool inside = (x >= -1.0f) && (x <= 1.0f);
    return make_float2(inside ? y : x, inside ? lad : 0.0f);
}

__global__ __launch_bounds__(256,4) void nsf_mfma(
    const float* __restrict__ wi, const float* __restrict__ cond,
    const _Float16* __restrict__ wsp,
    const float* __restrict__ p0_b1,
    float* __restrict__ out)
{
    const int tid = threadIdx.x;
    const int l = tid & 63, wid = tid >> 6;
    const int i = blockIdx.x*256 + wid*64 + l;
    _Float16* Sw = waveS() + wid*4096;
    const int mrow = l & 15, g = (l >> 4) & 3;
    const float* wsf = (const float*)(wsp + WS_F16);

    float2 wv2 = reinterpret_cast<const float2*>(wi)[i];
    float w0v = wv2.x, w1v = wv2.y;
    float c[10];
    {
        const float2* cp2 = reinterpret_cast<const float2*>(cond + (size_t)i*10);
#pragma unroll
        for (int k=0;k<5;++k){ float2 t2 = cp2[k]; c[2*k]=t2.x; c[2*k+1]=t2.y; }
    }

    // cond_e -> f16 chunks A0..A3 (cols 0..31, incl. 2 zero pads)
    half8 A0, A1, A2, A3, Z;
#pragma unroll
    for (int j=0;j<8;++j) Z[j] = (_Float16)0.0f;
    {
        _Float16 ce[30];
        ce[0] = (_Float16)c[8];
        ce[1] = (_Float16)c[9];
        float f = 1.0f;
#pragma unroll
        for (int fi=0; fi<5; ++fi){
            float s8,c8v,s9,c9v;
            __sincosf(c[8]*f, &s8, &c8v);
            __sincosf(c[9]*f, &s9, &c9v);
            ce[2+4*fi+0]=(_Float16)s8;  ce[2+4*fi+1]=(_Float16)s9;
            ce[2+4*fi+2]=(_Float16)c8v; ce[2+4*fi+3]=(_Float16)c9v;
            f *= 2.0f;
        }
#pragma unroll
        for (int k=0;k<8;++k) ce[22+k] = (_Float16)c[k];
#pragma unroll
        for (int j=0;j<8;++j){ A0[j]=ce[j]; A1[j]=ce[8+j]; A2[j]=ce[16+j]; }
#pragma unroll
        for (int j=0;j<8;++j) A3[j] = (j<6) ? ce[24+j] : (_Float16)0.0f;
    }

    auto mkPE = [&](float t, half8& P0, half8& P1){
        float s1,c1v,s2,c2v,s3,c3v,s4,c4v;
        __sincosf(t*1.0f,       &s1,&c1v);
        __sincosf(t*3.3333333f, &s2,&c2v);
        __sincosf(t*5.6666665f, &s3,&c3v);
        __sincosf(t*8.0f,       &s4,&c4v);
        P0[0]=(_Float16)t;   P0[1]=(_Float16)s1; P0[2]=(_Float16)c1v; P0[3]=(_Float16)s2;
        P0[4]=(_Float16)c2v; P0[5]=(_Float16)s3; P0[6]=(_Float16)c3v; P0[7]=(_Float16)s4;
        P1 = Z; P1[0] = (_Float16)c4v;
    };

    // ---- m1: stage xin(w1v), MLP, spline on w0 ----
    half8 P0, P1;
    mkPE(w1v, P0, P1);
    wr16(Sw,l,0,A0); wr16(Sw,l,1,A1); wr16(Sw,l,2,A2); wr16(Sw,l,3,A3);
    wr16(Sw,l,4,P0); wr16(Sw,l,5,P1); wr16(Sw,l,6,Z);  wr16(Sw,l,7,Z);
    __threadfence_block();
    mlp_lds(tid, wsp+OFF_M1_W0T, wsp+OFF_M1_W1T, wsp+OFF_M1_W2T,
            wsf+FB_M1_B0, wsf+FB_M1_B1, wsf+FB_M1_B2);
    float2 r0 = rqs_lds(w0v, tid);
    float y0 = r0.x, ld0 = r0.y;

    // ---- m0: stage xin(y0), MLP, spline on w1 ----
    mkPE(y0, P0, P1);
    wr16(Sw,l,0,A0); wr16(Sw,l,1,A1); wr16(Sw,l,2,A2); wr16(Sw,l,3,A3);
    wr16(Sw,l,4,P0); wr16(Sw,l,5,P1); wr16(Sw,l,6,Z);  wr16(Sw,l,7,Z);
    __threadfence_block();
    mlp_lds(tid, wsp+OFF_M0_W0T, wsp+OFF_M0_W1T, wsp+OFF_M0_W2T,
            wsf+FB_M0_B0, wsf+FB_M0_B1, wsf+FB_M0_B2);
    float2 r1 = rqs_lds(w1v, tid);
    float y1 = r1.x, ld1 = r1.y;

    // ---- p0: cond_e(30,+2pad) -> 32 (lrelu) via swapped MFMA ----
    wr16(Sw,l,0,A0); wr16(Sw,l,1,A1); wr16(Sw,l,2,A2); wr16(Sw,l,3,A3);
    __threadfence_block();
    {
        half8 aW[2], bC[4];
#pragma unroll
        for (int n=0;n<2;++n) aW[n] = *(const half8*)(wsp + OFF_P0_W0T + (16*n+mrow)*32 + 8*g);
#pragma unroll
        for (int t=0;t<4;++t) bC[t] = rd16(Sw, 16*t+mrow, g);
        const float* PB = wsf + FB_P0_B0;
        float4v b0 = *(const float4v*)(PB + 4*g);
        float4v b1 = *(const float4v*)(PB + 16 + 4*g);
#pragma unroll
        for (int t=0;t<4;++t){
            float4v a0 = b0, a1 = b1;
            a0 = MFMA16(aW[0], bC[t], a0, 0,0,0);
            a1 = MFMA16(aW[1], bC[t], a1, 0,0,0);
            wr16(Sw, 16*t+mrow, g, join8(
                pack4_lrelu(a0[0], a0[1], a0[2], a0[3]),
                pack4_lrelu(a1[0], a1[1], a1[2], a1[3])));
        }
    }
    __threadfence_block();

    // ---- tail: per-thread 32 -> 4 via fdot2 (permuted unpack) ----
    float r4[4] = {p0_b1[0], p0_b1[1], p0_b1[2], p0_b1[3]};
    {
        half8 Tq[4];
#pragma unroll
        for (int u=0;u<4;++u) Tq[u] = rd16(Sw, l, u);
        const u32* pw = (const u32*)(wsf + FB_PW1);
#pragma unroll
        for (int k2=0;k2<16;++k2){
            int p = ppos(2*k2);                 // pair (2k2, 2k2+1) is position-adjacent
            h2 x; x[0] = Tq[p>>3][p&7]; x[1] = Tq[(p+1)>>3][(p+1)&7];
#pragma unroll
            for (int j=0;j<4;++j) r4[j] = fdot2(x, u2h2(pw[k2*4+j]), r4[j]);
        }
    }

    float mu0=r4[0], mu1=r4[1], ls0=r4[2], ls1=r4[3];
    float is0 = __expf(-ls0), is1 = __expf(-ls1);
    float e0 = (y0-mu0)*is0, e1 = (y1-mu1)*is1;
    float rr = e0*e0 + e1*e1;
    float lp = -(ls0+ls1) - 1.8378770664093453f - 0.5f*rr + ld0 + ld1;

    reinterpret_cast<float2*>(out)[i] = make_float2(y0, y1);
    out[2*(size_t)N_PTS + i] = lp;
}

// ---------------- fallback all-f32 kernel (known-good R1) ----------------
__device__ __forceinline__ float softplus_ref(float x){
    return fmaxf(x, 0.0f) + log1pf(__expf(-fabsf(x)));
}
__device__ __forceinline__ void rqs_f32(float x, float* tp, float& yo, float& lado)
{
    float mw = tp[0];
#pragma unroll
    for (int i=1;i<20;++i) mw = fmaxf(mw, tp[i]);
    float sw = 0.f;
#pragma unroll
    for (int i=0;i<20;++i){ tp[i] = __expf(tp[i]-mw); sw += tp[i]; }
    float invw = 0.98f / sw;
    float mh = tp[20];
#pragma unroll
    for (int i=1;i<20;++i) mh = fmaxf(mh, tp[20+i]);
    float sh = 0.f;
#pragma unroll
    for (int i=0;i<20;++i){ tp[20+i] = __expf(tp[20+i]-mh); sh += tp[20+i]; }
    float invh = 0.98f / sh;
    float xc = fminf(fmaxf(x,-1.0f),1.0f);
    float cum = 0.f; int idx = 0;
    float inCw = -1.0f, inW = 1.0f;
#pragma unroll
    for (int i=0;i<20;++i){
        float wv = fmaf(invw, tp[i], 0.001f);
        float cwL = (i==0) ? -1.0f : fmaf(2.0f, cum, -1.0f);
        float cumN = cum + wv;
        float cwR = (i==19) ? 1.0f : fmaf(2.0f, cumN, -1.0f);
        if (xc >= cwL){ idx = i; inCw = cwL; inW = cwR - cwL; }
        cum = cumN;
    }
    float hcum = 0.f; float inCh = -1.0f, inH = 1.0f;
#pragma unroll
    for (int i=0;i<20;++i){
        float hv = fmaf(invh, tp[20+i], 0.001f);
        float chL = (i==0) ? -1.0f : fmaf(2.0f, hcum, -1.0f);
        float hcumN = hcum + hv;
        float chR = (i==19) ? 1.0f : fmaf(2.0f, hcumN, -1.0f);
        if (i == idx){ inCh = chL; inH = chR - chL; }
        hcum = hcumN;
    }
    float udl = TAILC, udr = TAILC;
#pragma unroll
    for (int t=0;t<19;++t){
        if (idx == t+1) udl = tp[40+t];
        if (idx == t)   udr = tp[40+t];
    }
    float inD   = 0.001f + softplus_ref(udl);
    float inDp1 = 0.001f + softplus_ref(udr);
    float inDelta = inH / inW;
    float th  = (xc - inCw) / inW;
    float omt = 1.0f - th;
    float t1  = th * omt;
    float num = inH * (inDelta*th*th + inD*t1);
    float den = inDelta + (inD + inDp1 - 2.0f*inDelta)*t1;
    float y = inCh + num/den;
    float dnum = inDelta*inDelta*(inDp1*th*th + 2.0f*inDelta*t1 + inD*omt*omt);
    float lad = __logf(dnum) - 2.0f*__logf(den);
    bool inside = (x >= -1.0f) && (x <= 1.0f);
    yo   = inside ? y   : x;
    lado = inside ? lad : 0.0f;
}
template<int OUTW>
__device__ __forceinline__ void addrow(float v, const float* __restrict__ Wrow, float* acc){
#pragma unroll
    for (int j=0;j<OUTW;++j) acc[j] = fmaf(v, Wrow[j], acc[j]);
}
template<int KIN, int OUT>
__device__ __forceinline__ void dense(const float* x, const float* __restrict__ W,
        const float* __restrict__ B, float* acc){
#pragma unroll
    for (int j=0;j<OUT;++j) acc[j] = B[j];
#pragma unroll
    for (int k=0;k<KIN;++k){
#pragma unroll
        for (int j=0;j<OUT;++j) acc[j] = fmaf(x[k], W[k*OUT+j], acc[j]);
    }
}
__device__ __forceinline__ void mlp_layer0(float t, const float* c,
        const float* __restrict__ W0, const float* __restrict__ B0, float* h)
{
#pragma unroll
    for (int j=0;j<32;++j) h[j] = B0[j];
    addrow<32>(t, W0 + 0*32, h);
    float s, co;
    __sincosf(t*1.0f,       &s,&co); addrow<32>(s, W0+1*32, h); addrow<32>(co, W0+2*32, h);
    __sincosf(t*3.3333333f, &s,&co); addrow<32>(s, W0+3*32, h); addrow<32>(co, W0+4*32, h);
    __sincosf(t*5.6666665f, &s,&co); addrow<32>(s, W0+5*32, h); addrow<32>(co, W0+6*32, h);
    __sincosf(t*8.0f,       &s,&co); addrow<32>(s, W0+7*32, h); addrow<32>(co, W0+8*32, h);
    addrow<32>(c[8], W0 + 9*32, h);
    addrow<32>(c[9], W0 +10*32, h);
    float f = 1.0f;
#pragma unroll
    for (int fi=0; fi<5; ++fi){
        float s8,c8v,s9,c9v;
        __sincosf(c[8]*f, &s8, &c8v);
        __sincosf(c[9]*f, &s9, &c9v);
        addrow<32>(s8,  W0 + (11+4*fi)*32, h);
        addrow<32>(s9,  W0 + (12+4*fi)*32, h);
        addrow<32>(c8v, W0 + (13+4*fi)*32, h);
        addrow<32>(c9v, W0 + (14+4*fi)*32, h);
        f *= 2.0f;
    }
#pragma unroll
    for (int k=0;k<8;++k) addrow<32>(c[k], W0 + (31+k)*32, h);
#pragma unroll
    for (int j=0;j<32;++j) h[j] = lrelu(h[j]);
}
__global__ __launch_bounds__(256,3) void nsf_kernel_f32(
    const float* __restrict__ wi, const float* __restrict__ cond,
    const float* __restrict__ p0_w0, const float* __restrict__ p0_b0,
    const float* __restrict__ p0_w1, const float* __restrict__ p0_b1,
    const float* __restrict__ m1_w0, const float* __restrict__ m1_b0,
    const float* __restrict__ m1_w1, const float* __restrict__ m1_b1,
    const float* __restrict__ m1_w2, const float* __restrict__ m1_b2,
    const float* __restrict__ m0_w0, const float* __restrict__ m0_b0,
    const float* __restrict__ m0_w1, const float* __restrict__ m0_b1,
    const float* __restrict__ m0_w2, const float* __restrict__ m0_b2,
    float* __restrict__ out)
{
    const int i = blockIdx.x*256 + threadIdx.x;
    float2 wv2 = reinterpret_cast<const float2*>(wi)[i];
    float w0v = wv2.x, w1v = wv2.y;
    const float* cp = cond + (size_t)i*10;
    float c[10];
#pragma unroll
    for (int k=0;k<10;++k) c[k] = cp[k];

    float tp[59];
    {
        float h[32], gg[32];
        mlp_layer0(w1v, c, m1_w0, m1_b0, h);
        dense<32,32>(h, m1_w1, m1_b1, gg);
#pragma unroll
        for (int j=0;j<32;++j) gg[j] = lrelu(gg[j]);
        dense<32,59>(gg, m1_w2, m1_b2, tp);
    }
    float y0, ld0; rqs_f32(w0v, tp, y0, ld0);
    {
        float h[32], gg[32];
        mlp_layer0(y0, c, m0_w0, m0_b0, h);
        dense<32,32>(h, m0_w1, m0_b1, gg);
#pragma unroll
        for (int j=0;j<32;++j) gg[j] = lrelu(gg[j]);
        dense<32,59>(gg, m0_w2, m0_b2, tp);
    }
    float y1, ld1; rqs_f32(w1v, tp, y1, ld1);

    float r[4];
    {
        float ph[32];
#pragma unroll
        for (int j=0;j<32;++j) ph[j] = p0_b0[j];
        addrow<32>(c[8], p0_w0 + 0*32, ph);
        addrow<32>(c[9], p0_w0 + 1*32, ph);
        float f = 1.0f;
#pragma unroll
        for (int fi=0; fi<5; ++fi){
            float s8,c8v,s9,c9v;
            __sincosf(c[8]*f, &s8, &c8v);
            __sincosf(c[9]*f, &s9, &c9v);
            addrow<32>(s8,  p0_w0 + (2+4*fi)*32, ph);
            addrow<32>(s9,  p0_w0 + (3+4*fi)*32, ph);
            addrow<32>(c8v, p0_w0 + (4+4*fi)*32, ph);
            addrow<32>(c9v, p0_w0 + (5+4*fi)*32, ph);
            f *= 2.0f;
        }
#pragma unroll
        for (int k=0;k<8;++k) addrow<32>(c[k], p0_w0 + (22+k)*32, ph);
#pragma unroll
        for (int j=0;j<32;++j) ph[j] = lrelu(ph[j]);
        dense<32,4>(ph, p0_w1, p0_b1, r);
    }

    float mu0=r[0], mu1=r[1], ls0=r[2], ls1=r[3];
    float is0 = __expf(-ls0), is1 = __expf(-ls1);
    float e0 = (y0-mu0)*is0, e1 = (y1-mu1)*is1;
    float rr = e0*e0 + e1*e1;
    float lp = -(ls0+ls1) - 1.8378770664093453f - 0.5f*rr + ld0 + ld1;

    reinterpret_cast<float2*>(out)[i] = make_float2(y0, y1);
    out[2*(size_t)N_PTS + i] = lp;
}

extern "C" void kernel_launch(void* const* d_in, const int* in_sizes, int n_in,
                              void* d_out, int out_size, void* d_ws, size_t ws_size,
                              hipStream_t stream)
{
    const float* wi    = (const float*)d_in[0];
    const float* cond  = (const float*)d_in[1];
    const float* p0_w0 = (const float*)d_in[2];
    const float* p0_b0 = (const float*)d_in[3];
    const float* p0_w1 = (const float*)d_in[4];
    const float* p0_b1 = (const float*)d_in[5];
    const float* m1_w0 = (const float*)d_in[6];
    const float* m1_b0 = (const float*)d_in[7];
    const float* m1_w1 = (const float*)d_in[8];
    const float* m1_b1 = (const float*)d_in[9];
    const float* m1_w2 = (const float*)d_in[10];
    const float* m1_b2 = (const float*)d_in[11];
    const float* m0_w0 = (const float*)d_in[12];
    const float* m0_b0 = (const float*)d_in[13];
    const float* m0_w1 = (const float*)d_in[14];
    const float* m0_b1 = (const float*)d_in[15];
    const float* m0_w2 = (const float*)d_in[16];
    const float* m0_b2 = (const float*)d_in[17];
    float* out = (float*)d_out;

    dim3 block(256);
    if (ws_size >= (size_t)WS_BYTES) {
        _Float16* wsp = (_Float16*)d_ws;
        hipLaunchKernelGGL(pack_weights, dim3((PACK_ITEMS+255)/256), block, 0, stream,
            m1_w0, m1_w1, m1_w2, m0_w0, m0_w1, m0_w2, p0_w0, p0_w1,
            m1_b0, m1_b1, m1_b2, m0_b0, m0_b1, m0_b2, p0_b0, wsp);
        hipLaunchKernelGGL(nsf_mfma, dim3(N_PTS/256), block, 0, stream,
            wi, cond, wsp, p0_b1, out);
    } else {
        hipLaunchKernelGGL(nsf_kernel_f32, dim3(N_PTS/256), block, 0, stream,
            wi, cond, p0_w0, p0_b0, p0_w1, p0_b1,
            m1_w0, m1_b0, m1_w1, m1_b1, m1_w2, m1_b2,
            m0_w0, m0_b0, m0_w1, m0_b1, m0_w2, m0_b2, out);
    }
}

// Round 13
// 126.877 us; speedup vs baseline: 5.7843x; 1.0067x over previous
//
#include <hip/hip_runtime.h>
#include <math.h>

#define N_PTS 2097152
#define TAILC 0.53974324f   // log(exp(1-0.001)-1)
#define LOG2E 1.4426950408889634f
#define LN2   0.6931471805599453f

typedef unsigned int u32;
typedef _Float16 half8 __attribute__((ext_vector_type(8)));
typedef _Float16 half4 __attribute__((ext_vector_type(4)));
typedef _Float16 h2    __attribute__((ext_vector_type(2)));
typedef __fp16   fp16x2 __attribute__((ext_vector_type(2)));
typedef float float4v  __attribute__((ext_vector_type(4)));

#define MFMA16 __builtin_amdgcn_mfma_f32_16x16x32_f16

__device__ __forceinline__ float lrelu(float x){ return x > 0.0f ? x : 0.01f*x; }
__device__ __forceinline__ float exp2fast(float x){
#if __has_builtin(__builtin_amdgcn_exp2f)
    return __builtin_amdgcn_exp2f(x);
#else
    return exp2f(x);
#endif
}
__device__ __forceinline__ float log2fast(float x){
#if __has_builtin(__builtin_amdgcn_logf)
    return __builtin_amdgcn_logf(x);
#else
    return __log2f(x);
#endif
}
// softplus(x) = ln2 * log2(1 + exp2(x*log2e)); f32-safe for |x| < ~80
__device__ __forceinline__ float softplus_(float x){
    return LN2 * log2fast(1.0f + exp2fast(x * LOG2E));
}
__device__ __forceinline__ half4 pack4(float a0, float a1, float a2, float a3){
#if __has_builtin(__builtin_amdgcn_cvt_pkrtz)
    union { fp16x2 f; h2 h; } lo, hi;
    lo.f = __builtin_amdgcn_cvt_pkrtz(a0, a1);
    hi.f = __builtin_amdgcn_cvt_pkrtz(a2, a3);
    half4 r; r[0]=lo.h[0]; r[1]=lo.h[1]; r[2]=hi.h[0]; r[3]=hi.h[1];
    return r;
#else
    half4 r; r[0]=(_Float16)a0; r[1]=(_Float16)a1; r[2]=(_Float16)a2; r[3]=(_Float16)a3;
    return r;
#endif
}
// packed f16 leaky-relu: v_pk_mul_f16 + v_pk_max_f16 via elementwise builtins
__device__ __forceinline__ h2 lrelu2(h2 x){
#if __has_builtin(__builtin_elementwise_max)
    h2 m = x * (_Float16)0.01f;
    return __builtin_elementwise_max(x, m);
#else
    h2 r; r[0] = (x[0] > (_Float16)0 ? x[0] : x[0]*(_Float16)0.01f);
    r[1] = (x[1] > (_Float16)0 ? x[1] : x[1]*(_Float16)0.01f);
    return r;
#endif
}
// pack 4 f32 -> 4 f16 then leaky-relu in PACKED f16
__device__ __forceinline__ half4 pack4_lrelu(float a0, float a1, float a2, float a3){
#if __has_builtin(__builtin_amdgcn_cvt_pkrtz)
    union { fp16x2 f; h2 h; } lo, hi;
    lo.f = __builtin_amdgcn_cvt_pkrtz(a0, a1);
    hi.f = __builtin_amdgcn_cvt_pkrtz(a2, a3);
    h2 lm = lrelu2(lo.h), hm = lrelu2(hi.h);
    half4 r; r[0]=lm[0]; r[1]=lm[1]; r[2]=hm[0]; r[3]=hm[1];
    return r;
#else
    return pack4(lrelu(a0), lrelu(a1), lrelu(a2), lrelu(a3));
#endif
}
__device__ __forceinline__ half8 join8(half4 a, half4 b){
    half8 r; r[0]=a[0]; r[1]=a[1]; r[2]=a[2]; r[3]=a[3];
    r[4]=b[0]; r[5]=b[1]; r[6]=b[2]; r[7]=b[3];
    return r;
}
__device__ __forceinline__ float fdot2(h2 a, h2 b, float c){
#if __has_builtin(__builtin_amdgcn_fdot2)
    return __builtin_amdgcn_fdot2(a, b, c, false);
#else
    return fmaf((float)a[0],(float)b[0], fmaf((float)a[1],(float)b[1], c));
#endif
}
__device__ __forceinline__ h2 u2h2(u32 u){ union{u32 a; h2 b;} x; x.a=u; return x.b; }

// physical position of logical output o for 32-wide layers (p = 8g + 4n + j, o = 16n+4g+j)
__device__ __host__ constexpr int ppos(int o){
    return 8*((o>>2)&3) + 4*(o>>4) + (o&3);
}
// physical position of logical output m for the 64-wide L2 layer
__device__ __host__ constexpr int qpos(int m){
    return 16*((m>>2)&3) + 8*((m>>4)>>1) + 4*((m>>4)&1) + (m&3);
}
// inverse: logical o at physical p (32-wide)
__device__ __host__ constexpr int pinv(int p){
    return 16*((p>>2)&1) + 4*(p>>3) + (p&3);
}

// Single shared allocation reachable from kernel AND noinline callees.
__device__ __forceinline__ _Float16* waveS(){
    __shared__ _Float16 S[4][4096];    // per-wave [64 rows][64 f16], swizzled
    return &S[0][0];
}
__device__ __forceinline__ half8 rd16(const _Float16* Sw, int row, int u){
    return *(const half8*)(Sw + row*64 + ((u ^ (row&7))<<3));
}
__device__ __forceinline__ void wr16(_Float16* Sw, int row, int u, half8 v){
    *(half8*)(Sw + row*64 + ((u ^ (row&7))<<3)) = v;
}

// ---- packed weights/biases in d_ws ----
#define OFF_M1_W0T 0        // [32][64]
#define OFF_M1_W1T 2048     // [32][32]
#define OFF_M1_W2T 3072     // [64][32]
#define OFF_M0_W0T 5120
#define OFF_M0_W1T 7168
#define OFF_M0_W2T 8192
#define OFF_P0_W0T 10240    // [32][32]
#define WS_F16     11264
// f32 region (byte 22528)
#define FB_M1_B0   0
#define FB_M1_B1   32
#define FB_M1_B2   64       // padded to 64, outputs 0..39 pre-scaled by LOG2E
#define FB_M0_B0   128
#define FB_M0_B1   160
#define FB_M0_B2   192
#define FB_P0_B0   256
#define FB_PW1     288      // 64 u32: p0_w1 packed h2 pairs
#define WS_BYTES   (22528 + 288*4 + 64*4)
#define PACK_ITEMS (WS_F16 + 288 + 64)

__global__ void pack_weights(const float* __restrict__ m1_w0, const float* __restrict__ m1_w1,
                             const float* __restrict__ m1_w2, const float* __restrict__ m0_w0,
                             const float* __restrict__ m0_w1, const float* __restrict__ m0_w2,
                             const float* __restrict__ p0_w0, const float* __restrict__ p0_w1,
                             const float* __restrict__ m1_b0, const float* __restrict__ m1_b1,
                             const float* __restrict__ m1_b2, const float* __restrict__ m0_b0,
                             const float* __restrict__ m0_b1, const float* __restrict__ m0_b2,
                             const float* __restrict__ p0_b0, _Float16* __restrict__ ws)
{
    int idx = blockIdx.x*256 + threadIdx.x;
    if (idx >= PACK_ITEMS) return;
    if (idx < WS_F16) {
        float v = 0.0f;
        if (idx < 2048 || (idx >= 5120 && idx < 7168)) {          // W0T [32][64], k logical
            const float* W = (idx < 2048) ? m1_w0 : m0_w0;
            int r = (idx < 2048) ? idx : idx - 5120;
            int o = r >> 6, k = r & 63;
            if (k < 30)                 v = W[(9+k)*32 + o];
            else if (k >= 32 && k < 41) v = W[(k-32)*32 + o];
        } else if (idx < 3072 || (idx >= 7168 && idx < 8192)) {   // W1T [32][32], k permuted
            const float* W = (idx < 3072) ? m1_w1 : m0_w1;
            int r = (idx < 3072) ? idx - 2048 : idx - 7168;
            int o = r >> 5, p = r & 31;
            v = W[pinv(p)*32 + o];
        } else if (idx < 5120 || (idx >= 8192 && idx < 10240)) {  // W2T [64][32], k permuted, rows<40 scaled
            const float* W = (idx < 5120) ? m1_w2 : m0_w2;
            int r = (idx < 5120) ? idx - 3072 : idx - 8192;
            int o = r >> 5, p = r & 31;
            if (o < 59) {
                v = W[pinv(p)*59 + o];
                if (o < 40) v *= LOG2E;
            }
        } else {                                                  // p0 W0T [32][32], k logical
            int r = idx - 10240;
            int o = r >> 5, k = r & 31;
            if (k < 30) v = p0_w0[k*32 + o];
        }
        ws[idx] = (_Float16)v;
        return;
    }
    float* wsf = (float*)(ws + WS_F16);
    int bi = idx - WS_F16;
    if (bi < 288) {
        float v = 0.0f;
        if      (bi < 32)  v = m1_b0[bi];
        else if (bi < 64)  v = m1_b1[bi-32];
        else if (bi < 128) { int o = bi-64;  if (o < 59) { v = m1_b2[o]; if (o < 40) v *= LOG2E; } }
        else if (bi < 160) v = m0_b0[bi-128];
        else if (bi < 192) v = m0_b1[bi-160];
        else if (bi < 256) { int o = bi-192; if (o < 59) { v = m0_b2[o]; if (o < 40) v *= LOG2E; } }
        else               v = p0_b0[bi-256];
        wsf[bi] = v;
        return;
    }
    int pi = bi - 288;            // 0..63 : p0_w1 packed pairs
    int k2 = pi >> 2, j = pi & 3;
    union{ _Float16 h; unsigned short s; } a, b;
    a.h = (_Float16)p0_w1[(2*k2)*4 + j];
    b.h = (_Float16)p0_w1[(2*k2+1)*4 + j];
    ((u32*)(wsf + FB_PW1))[pi] = (u32)a.s | ((u32)b.s << 16);
}

// ---------- one transform MLP (noinline, emitted once), swapped-operand MFMA ----------
// Inter-layer activations stay IN REGISTERS: lane l's D-output (physical 8g..8g+7
// of point 16t+(l&15)) is identical to its next-layer B-fragment. Only L2's
// output goes to LDS (spline needs cross-lane gather).
__device__ __noinline__ void mlp_lds(int tid,
    const _Float16* __restrict__ W0, const _Float16* __restrict__ W1,
    const _Float16* __restrict__ W2,
    const float* __restrict__ B0p, const float* __restrict__ B1p,
    const float* __restrict__ B2p)
{
    _Float16* Sw = waveS() + (tid>>6)*4096;
    const int l = tid & 63, mrow = l & 15, g = (l >> 4) & 3;

    half8 hB[4];   // packed activations: physical 8g..8g+7 of point 16t+mrow

    // ---- L0: K=64 (2 ksteps), OUT=32; xin from LDS ----
    {
        half8 aW[2][2], bX[4][2];
#pragma unroll
        for (int n=0;n<2;++n)
#pragma unroll
            for (int s=0;s<2;++s)
                aW[n][s] = *(const half8*)(W0 + (16*n+mrow)*64 + 32*s + 8*g);
#pragma unroll
        for (int t=0;t<4;++t){
            int pt = 16*t + mrow;
#pragma unroll
            for (int s=0;s<2;++s) bX[t][s] = rd16(Sw, pt, 4*s+g);
        }
        float4v b0 = *(const float4v*)(B0p + 4*g);
        float4v b1 = *(const float4v*)(B0p + 16 + 4*g);
#pragma unroll
        for (int t=0;t<4;++t){
            float4v a0 = b0, a1 = b1;
            a0 = MFMA16(aW[0][0], bX[t][0], a0, 0,0,0);
            a0 = MFMA16(aW[0][1], bX[t][1], a0, 0,0,0);
            a1 = MFMA16(aW[1][0], bX[t][0], a1, 0,0,0);
            a1 = MFMA16(aW[1][1], bX[t][1], a1, 0,0,0);
            hB[t] = join8(pack4_lrelu(a0[0], a0[1], a0[2], a0[3]),
                          pack4_lrelu(a1[0], a1[1], a1[2], a1[3]));
        }
    }
    // ---- L1: K=32, OUT=32; B from regs, result back to regs (no LDS, no fence) ----
    {
        half8 aW[2];
#pragma unroll
        for (int n=0;n<2;++n) aW[n] = *(const half8*)(W1 + (16*n+mrow)*32 + 8*g);
        float4v b0 = *(const float4v*)(B1p + 4*g);
        float4v b1 = *(const float4v*)(B1p + 16 + 4*g);
#pragma unroll
        for (int t=0;t<4;++t){
            float4v a0 = b0, a1 = b1;
            a0 = MFMA16(aW[0], hB[t], a0, 0,0,0);
            a1 = MFMA16(aW[1], hB[t], a1, 0,0,0);
            hB[t] = join8(pack4_lrelu(a0[0], a0[1], a0[2], a0[3]),
                          pack4_lrelu(a1[0], a1[1], a1[2], a1[3]));
        }
    }
    // ---- L2: K=32, OUT=64 (59 real; outputs 0..39 pre-scaled by LOG2E); to LDS ----
    {
        half8 aW[4];
#pragma unroll
        for (int n=0;n<4;++n) aW[n] = *(const half8*)(W2 + (16*n+mrow)*32 + 8*g);
        float4v bb[4];
#pragma unroll
        for (int n=0;n<4;++n) bb[n] = *(const float4v*)(B2p + 16*n + 4*g);
#pragma unroll
        for (int t=0;t<4;++t){
            float4v a0=bb[0], a1=bb[1], a2=bb[2], a3=bb[3];
            a0 = MFMA16(aW[0], hB[t], a0, 0,0,0);
            a1 = MFMA16(aW[1], hB[t], a1, 0,0,0);
            a2 = MFMA16(aW[2], hB[t], a2, 0,0,0);
            a3 = MFMA16(aW[3], hB[t], a3, 0,0,0);
            int row = 16*t + mrow;
            wr16(Sw, row, 2*g,   join8(pack4(a0[0],a0[1],a0[2],a0[3]),
                                       pack4(a1[0],a1[1],a1[2],a1[3])));
            wr16(Sw, row, 2*g+1, join8(pack4(a2[0],a2[1],a2[2],a2[3]),
                                       pack4(a3[0],a3[1],a3[2],a3[3])));
        }
    }
    __threadfence_block();
}

// ---------- spline (noinline, emitted once) ----------
// uw/uh arrive pre-scaled by LOG2E -> exp2 direct, NO max subtraction.
// Single merged walk: both (cum,wv) and (hcum,hv) selected under u01>=cum.
__device__ __noinline__ float2 rqs_lds(float x, int tid)
{
    const int l = tid & 63;
    const int swz = l & 7;
    const _Float16* Sw = waveS() + (tid>>6)*4096;

    // widths+heights live in units {0,1,2,3,4,6}; derivs read dynamically below.
    half8 R[8];
    R[0]=rd16(Sw,l,0); R[1]=rd16(Sw,l,1); R[2]=rd16(Sw,l,2);
    R[3]=rd16(Sw,l,3); R[4]=rd16(Sw,l,4); R[6]=rd16(Sw,l,6);
    R[5]=R[4]; R[7]=R[6];   // dead (q never hits 5/7 for m<40); avoids UB

    float xc = fminf(fmaxf(x,-1.0f),1.0f);
    float u01 = fmaf(xc, 0.5f, 0.5f);       // walk in normalized cum-space

    float w[20], h[20];
#pragma unroll
    for (int i=0;i<20;++i){ int q = qpos(i);    w[i] = exp2fast((float)R[q>>3][q&7]); }
#pragma unroll
    for (int i=0;i<20;++i){ int q = qpos(20+i); h[i] = exp2fast((float)R[q>>3][q&7]); }
    float sw = 0.f, sh = 0.f;
#pragma unroll
    for (int i=0;i<20;++i){ sw += w[i]; sh += h[i]; }
    float invw = 0.98f / sw;
    float invh = 0.98f / sh;

    int idx = 0;
    float cumL = 0.0f, wvL = 1.0f, hcumL = 0.0f, hvL = 1.0f;
    float cum = 0.f, hcum = 0.f;
#pragma unroll
    for (int i=0;i<20;++i){
        float wv = fmaf(invw, w[i], 0.001f);
        float hv = fmaf(invh, h[i], 0.001f);
        if (u01 >= cum){ idx = i; cumL = cum; wvL = wv; hcumL = hcum; hvL = hv; }
        cum += wv; hcum += hv;
    }

    // derivs: udl = idx>0 ? tp[39+idx] : TAILC ; udr = idx<19 ? tp[40+idx] : TAILC
    auto rdq = [&](int m)->float{
        int q = 16*((m>>2)&3) + 8*((m>>4)>>1) + 4*((m>>4)&1) + (m&3);
        return (float)Sw[l*64 + (((q>>3) ^ swz)<<3) + (q&7)];
    };
    float dl = rdq(39+idx);
    float dr = rdq(40+idx);
    float udl = (idx>0)  ? dl : TAILC;
    float udr = (idx<19) ? dr : TAILC;

    float inD   = 0.001f + softplus_(udl);
    float inDp1 = 0.001f + softplus_(udr);
    float inDelta = hvL / wvL;              // (2hvL)/(2wvL)
    float inH  = 2.0f * hvL;
    float inCh = fmaf(2.0f, hcumL, -1.0f);
    float th  = (u01 - cumL) / wvL;         // == (xc - inCw)/inW
    float omt = 1.0f - th;
    float t1  = th * omt;
    float num = inH * (inDelta*th*th + inD*t1);
    float den = inDelta + (inD + inDp1 - 2.0f*inDelta)*t1;
    float y = inCh + num/den;
    float dnum = inDelta*inDelta*(inDp1*th*th + 2.0f*inDelta*t1 + inD*omt*omt);
    float lad = LN2 * (log2fast(dnum) - 2.0f*log2fast(den));
    bool inside = (x >= -1.0f) && (x <= 1.0f);
    return make_float2(inside ? y : x, inside ? lad : 0.0f);
}

__global__ __launch_bounds__(256,4) void nsf_mfma(
    const float* __restrict__ wi, const float* __restrict__ cond,
    const _Float16* __restrict__ wsp,
    const float* __restrict__ p0_b1,
    float* __restrict__ out)
{
    const int tid = threadIdx.x;
    const int l = tid & 63, wid = tid >> 6;
    const int i = blockIdx.x*256 + wid*64 + l;
    _Float16* Sw = waveS() + wid*4096;
    const int mrow = l & 15, g = (l >> 4) & 3;
    const float* wsf = (const float*)(wsp + WS_F16);

    float2 wv2 = reinterpret_cast<const float2*>(wi)[i];
    float w0v = wv2.x, w1v = wv2.y;
    float c[10];
    {
        const float2* cp2 = reinterpret_cast<const float2*>(cond + (size_t)i*10);
#pragma unroll
        for (int k=0;k<5;++k){ float2 t2 = cp2[k]; c[2*k]=t2.x; c[2*k+1]=t2.y; }
    }

    // cond_e -> f16 chunks A0..A3 (cols 0..31, incl. 2 zero pads)
    half8 A0, A1, A2, A3, Z;
#pragma unroll
    for (int j=0;j<8;++j) Z[j] = (_Float16)0.0f;
    {
        _Float16 ce[30];
        ce[0] = (_Float16)c[8];
        ce[1] = (_Float16)c[9];
        float f = 1.0f;
#pragma unroll
        for (int fi=0; fi<5; ++fi){
            float s8,c8v,s9,c9v;
            __sincosf(c[8]*f, &s8, &c8v);
            __sincosf(c[9]*f, &s9, &c9v);
            ce[2+4*fi+0]=(_Float16)s8;  ce[2+4*fi+1]=(_Float16)s9;
            ce[2+4*fi+2]=(_Float16)c8v; ce[2+4*fi+3]=(_Float16)c9v;
            f *= 2.0f;
        }
#pragma unroll
        for (int k=0;k<8;++k) ce[22+k] = (_Float16)c[k];
#pragma unroll
        for (int j=0;j<8;++j){ A0[j]=ce[j]; A1[j]=ce[8+j]; A2[j]=ce[16+j]; }
#pragma unroll
        for (int j=0;j<8;++j) A3[j] = (j<6) ? ce[24+j] : (_Float16)0.0f;
    }

    auto mkPE = [&](float t, half8& P0, half8& P1){
        float s1,c1v,s2,c2v,s3,c3v,s4,c4v;
        __sincosf(t*1.0f,       &s1,&c1v);
        __sincosf(t*3.3333333f, &s2,&c2v);
        __sincosf(t*5.6666665f, &s3,&c3v);
        __sincosf(t*8.0f,       &s4,&c4v);
        P0[0]=(_Float16)t;   P0[1]=(_Float16)s1; P0[2]=(_Float16)c1v; P0[3]=(_Float16)s2;
        P0[4]=(_Float16)c2v; P0[5]=(_Float16)s3; P0[6]=(_Float16)c3v; P0[7]=(_Float16)s4;
        P1 = Z; P1[0] = (_Float16)c4v;
    };

    // ---- m1: stage xin(w1v), MLP, spline on w0 ----
    half8 P0, P1;
    mkPE(w1v, P0, P1);
    wr16(Sw,l,0,A0); wr16(Sw,l,1,A1); wr16(Sw,l,2,A2); wr16(Sw,l,3,A3);
    wr16(Sw,l,4,P0); wr16(Sw,l,5,P1); wr16(Sw,l,6,Z);  wr16(Sw,l,7,Z);
    __threadfence_block();
    mlp_lds(tid, wsp+OFF_M1_W0T, wsp+OFF_M1_W1T, wsp+OFF_M1_W2T,
            wsf+FB_M1_B0, wsf+FB_M1_B1, wsf+FB_M1_B2);
    float2 r0 = rqs_lds(w0v, tid);
    float y0 = r0.x, ld0 = r0.y;

    // ---- m0: stage xin(y0), MLP, spline on w1 ----
    mkPE(y0, P0, P1);
    wr16(Sw,l,0,A0); wr16(Sw,l,1,A1); wr16(Sw,l,2,A2); wr16(Sw,l,3,A3);
    wr16(Sw,l,4,P0); wr16(Sw,l,5,P1); wr16(Sw,l,6,Z);  wr16(Sw,l,7,Z);
    __threadfence_block();
    mlp_lds(tid, wsp+OFF_M0_W0T, wsp+OFF_M0_W1T, wsp+OFF_M0_W2T,
            wsf+FB_M0_B0, wsf+FB_M0_B1, wsf+FB_M0_B2);
    float2 r1 = rqs_lds(w1v, tid);
    float y1 = r1.x, ld1 = r1.y;

    // ---- p0: cond_e(30,+2pad) -> 32 (lrelu) via swapped MFMA ----
    wr16(Sw,l,0,A0); wr16(Sw,l,1,A1); wr16(Sw,l,2,A2); wr16(Sw,l,3,A3);
    __threadfence_block();
    {
        half8 aW[2], bC[4];
#pragma unroll
        for (int n=0;n<2;++n) aW[n] = *(const half8*)(wsp + OFF_P0_W0T + (16*n+mrow)*32 + 8*g);
#pragma unroll
        for (int t=0;t<4;++t) bC[t] = rd16(Sw, 16*t+mrow, g);
        const float* PB = wsf + FB_P0_B0;
        float4v b0 = *(const float4v*)(PB + 4*g);
        float4v b1 = *(const float4v*)(PB + 16 + 4*g);
#pragma unroll
        for (int t=0;t<4;++t){
            float4v a0 = b0, a1 = b1;
            a0 = MFMA16(aW[0], bC[t], a0, 0,0,0);
            a1 = MFMA16(aW[1], bC[t], a1, 0,0,0);
            wr16(Sw, 16*t+mrow, g, join8(
                pack4_lrelu(a0[0], a0[1], a0[2], a0[3]),
                pack4_lrelu(a1[0], a1[1], a1[2], a1[3])));
        }
    }
    __threadfence_block();

    // ---- tail: per-thread 32 -> 4 via fdot2 (permuted unpack) ----
    float r4[4] = {p0_b1[0], p0_b1[1], p0_b1[2], p0_b1[3]};
    {
        half8 Tq[4];
#pragma unroll
        for (int u=0;u<4;++u) Tq[u] = rd16(Sw, l, u);
        const u32* pw = (const u32*)(wsf + FB_PW1);
#pragma unroll
        for (int k2=0;k2<16;++k2){
            int p = ppos(2*k2);                 // pair (2k2, 2k2+1) is position-adjacent
            h2 x; x[0] = Tq[p>>3][p&7]; x[1] = Tq[(p+1)>>3][(p+1)&7];
#pragma unroll
            for (int j=0;j<4;++j) r4[j] = fdot2(x, u2h2(pw[k2*4+j]), r4[j]);
        }
    }

    float mu0=r4[0], mu1=r4[1], ls0=r4[2], ls1=r4[3];
    float is0 = __expf(-ls0), is1 = __expf(-ls1);
    float e0 = (y0-mu0)*is0, e1 = (y1-mu1)*is1;
    float rr = e0*e0 + e1*e1;
    float lp = -(ls0+ls1) - 1.8378770664093453f - 0.5f*rr + ld0 + ld1;

    reinterpret_cast<float2*>(out)[i] = make_float2(y0, y1);
    out[2*(size_t)N_PTS + i] = lp;
}

// ---------------- fallback all-f32 kernel (known-good R1) ----------------
__device__ __forceinline__ float softplus_ref(float x){
    return fmaxf(x, 0.0f) + log1pf(__expf(-fabsf(x)));
}
__device__ __forceinline__ void rqs_f32(float x, float* tp, float& yo, float& lado)
{
    float mw = tp[0];
#pragma unroll
    for (int i=1;i<20;++i) mw = fmaxf(mw, tp[i]);
    float sw = 0.f;
#pragma unroll
    for (int i=0;i<20;++i){ tp[i] = __expf(tp[i]-mw); sw += tp[i]; }
    float invw = 0.98f / sw;
    float mh = tp[20];
#pragma unroll
    for (int i=1;i<20;++i) mh = fmaxf(mh, tp[20+i]);
    float sh = 0.f;
#pragma unroll
    for (int i=0;i<20;++i){ tp[20+i] = __expf(tp[20+i]-mh); sh += tp[20+i]; }
    float invh = 0.98f / sh;
    float xc = fminf(fmaxf(x,-1.0f),1.0f);
    float cum = 0.f; int idx = 0;
    float inCw = -1.0f, inW = 1.0f;
#pragma unroll
    for (int i=0;i<20;++i){
        float wv = fmaf(invw, tp[i], 0.001f);
        float cwL = (i==0) ? -1.0f : fmaf(2.0f, cum, -1.0f);
        float cumN = cum + wv;
        float cwR = (i==19) ? 1.0f : fmaf(2.0f, cumN, -1.0f);
        if (xc >= cwL){ idx = i; inCw = cwL; inW = cwR - cwL; }
        cum = cumN;
    }
    float hcum = 0.f; float inCh = -1.0f, inH = 1.0f;
#pragma unroll
    for (int i=0;i<20;++i){
        float hv = fmaf(invh, tp[20+i], 0.001f);
        float chL = (i==0) ? -1.0f : fmaf(2.0f, hcum, -1.0f);
        float hcumN = hcum + hv;
        float chR = (i==19) ? 1.0f : fmaf(2.0f, hcumN, -1.0f);
        if (i == idx){ inCh = chL; inH = chR - chL; }
        hcum = hcumN;
    }
    float udl = TAILC, udr = TAILC;
#pragma unroll
    for (int t=0;t<19;++t){
        if (idx == t+1) udl = tp[40+t];
        if (idx == t)   udr = tp[40+t];
    }
    float inD   = 0.001f + softplus_ref(udl);
    float inDp1 = 0.001f + softplus_ref(udr);
    float inDelta = inH / inW;
    float th  = (xc - inCw) / inW;
    float omt = 1.0f - th;
    float t1  = th * omt;
    float num = inH * (inDelta*th*th + inD*t1);
    float den = inDelta + (inD + inDp1 - 2.0f*inDelta)*t1;
    float y = inCh + num/den;
    float dnum = inDelta*inDelta*(inDp1*th*th + 2.0f*inDelta*t1 + inD*omt*omt);
    float lad = __logf(dnum) - 2.0f*__logf(den);
    bool inside = (x >= -1.0f) && (x <= 1.0f);
    yo   = inside ? y   : x;
    lado = inside ? lad : 0.0f;
}
template<int OUTW>
__device__ __forceinline__ void addrow(float v, const float* __restrict__ Wrow, float* acc){
#pragma unroll
    for (int j=0;j<OUTW;++j) acc[j] = fmaf(v, Wrow[j], acc[j]);
}
template<int KIN, int OUT>
__device__ __forceinline__ void dense(const float* x, const float* __restrict__ W,
        const float* __restrict__ B, float* acc){
#pragma unroll
    for (int j=0;j<OUT;++j) acc[j] = B[j];
#pragma unroll
    for (int k=0;k<KIN;++k){
#pragma unroll
        for (int j=0;j<OUT;++j) acc[j] = fmaf(x[k], W[k*OUT+j], acc[j]);
    }
}
__device__ __forceinline__ void mlp_layer0(float t, const float* c,
        const float* __restrict__ W0, const float* __restrict__ B0, float* h)
{
#pragma unroll
    for (int j=0;j<32;++j) h[j] = B0[j];
    addrow<32>(t, W0 + 0*32, h);
    float s, co;
    __sincosf(t*1.0f,       &s,&co); addrow<32>(s, W0+1*32, h); addrow<32>(co, W0+2*32, h);
    __sincosf(t*3.3333333f, &s,&co); addrow<32>(s, W0+3*32, h); addrow<32>(co, W0+4*32, h);
    __sincosf(t*5.6666665f, &s,&co); addrow<32>(s, W0+5*32, h); addrow<32>(co, W0+6*32, h);
    __sincosf(t*8.0f,       &s,&co); addrow<32>(s, W0+7*32, h); addrow<32>(co, W0+8*32, h);
    addrow<32>(c[8], W0 + 9*32, h);
    addrow<32>(c[9], W0 +10*32, h);
    float f = 1.0f;
#pragma unroll
    for (int fi=0; fi<5; ++fi){
        float s8,c8v,s9,c9v;
        __sincosf(c[8]*f, &s8, &c8v);
        __sincosf(c[9]*f, &s9, &c9v);
        addrow<32>(s8,  W0 + (11+4*fi)*32, h);
        addrow<32>(s9,  W0 + (12+4*fi)*32, h);
        addrow<32>(c8v, W0 + (13+4*fi)*32, h);
        addrow<32>(c9v, W0 + (14+4*fi)*32, h);
        f *= 2.0f;
    }
#pragma unroll
    for (int k=0;k<8;++k) addrow<32>(c[k], W0 + (31+k)*32, h);
#pragma unroll
    for (int j=0;j<32;++j) h[j] = lrelu(h[j]);
}
__global__ __launch_bounds__(256,3) void nsf_kernel_f32(
    const float* __restrict__ wi, const float* __restrict__ cond,
    const float* __restrict__ p0_w0, const float* __restrict__ p0_b0,
    const float* __restrict__ p0_w1, const float* __restrict__ p0_b1,
    const float* __restrict__ m1_w0, const float* __restrict__ m1_b0,
    const float* __restrict__ m1_w1, const float* __restrict__ m1_b1,
    const float* __restrict__ m1_w2, const float* __restrict__ m1_b2,
    const float* __restrict__ m0_w0, const float* __restrict__ m0_b0,
    const float* __restrict__ m0_w1, const float* __restrict__ m0_b1,
    const float* __restrict__ m0_w2, const float* __restrict__ m0_b2,
    float* __restrict__ out)
{
    const int i = blockIdx.x*256 + threadIdx.x;
    float2 wv2 = reinterpret_cast<const float2*>(wi)[i];
    float w0v = wv2.x, w1v = wv2.y;
    const float* cp = cond + (size_t)i*10;
    float c[10];
#pragma unroll
    for (int k=0;k<10;++k) c[k] = cp[k];

    float tp[59];
    {
        float h[32], gg[32];
        mlp_layer0(w1v, c, m1_w0, m1_b0, h);
        dense<32,32>(h, m1_w1, m1_b1, gg);
#pragma unroll
        for (int j=0;j<32;++j) gg[j] = lrelu(gg[j]);
        dense<32,59>(gg, m1_w2, m1_b2, tp);
    }
    float y0, ld0; rqs_f32(w0v, tp, y0, ld0);
    {
        float h[32], gg[32];
        mlp_layer0(y0, c, m0_w0, m0_b0, h);
        dense<32,32>(h, m0_w1, m0_b1, gg);
#pragma unroll
        for (int j=0;j<32;++j) gg[j] = lrelu(gg[j]);
        dense<32,59>(gg, m0_w2, m0_b2, tp);
    }
    float y1, ld1; rqs_f32(w1v, tp, y1, ld1);

    float r[4];
    {
        float ph[32];
#pragma unroll
        for (int j=0;j<32;++j) ph[j] = p0_b0[j];
        addrow<32>(c[8], p0_w0 + 0*32, ph);
        addrow<32>(c[9], p0_w0 + 1*32, ph);
        float f = 1.0f;
#pragma unroll
        for (int fi=0; fi<5; ++fi){
            float s8,c8v,s9,c9v;
            __sincosf(c[8]*f, &s8, &c8v);
            __sincosf(c[9]*f, &s9, &c9v);
            addrow<32>(s8,  p0_w0 + (2+4*fi)*32, ph);
            addrow<32>(s9,  p0_w0 + (3+4*fi)*32, ph);
            addrow<32>(c8v, p0_w0 + (4+4*fi)*32, ph);
            addrow<32>(c9v, p0_w0 + (5+4*fi)*32, ph);
            f *= 2.0f;
        }
#pragma unroll
        for (int k=0;k<8;++k) addrow<32>(c[k], p0_w0 + (22+k)*32, ph);
#pragma unroll
        for (int j=0;j<32;++j) ph[j] = lrelu(ph[j]);
        dense<32,4>(ph, p0_w1, p0_b1, r);
    }

    float mu0=r[0], mu1=r[1], ls0=r[2], ls1=r[3];
    float is0 = __expf(-ls0), is1 = __expf(-ls1);
    float e0 = (y0-mu0)*is0, e1 = (y1-mu1)*is1;
    float rr = e0*e0 + e1*e1;
    float lp = -(ls0+ls1) - 1.8378770664093453f - 0.5f*rr + ld0 + ld1;

    reinterpret_cast<float2*>(out)[i] = make_float2(y0, y1);
    out[2*(size_t)N_PTS + i] = lp;
}

extern "C" void kernel_launch(void* const* d_in, const int* in_sizes, int n_in,
                              void* d_out, int out_size, void* d_ws, size_t ws_size,
                              hipStream_t stream)
{
    const float* wi    = (const float*)d_in[0];
    const float* cond  = (const float*)d_in[1];
    const float* p0_w0 = (const float*)d_in[2];
    const float* p0_b0 = (const float*)d_in[3];
    const float* p0_w1 = (const float*)d_in[4];
    const float* p0_b1 = (const float*)d_in[5];
    const float* m1_w0 = (const float*)d_in[6];
    const float* m1_b0 = (const float*)d_in[7];
    const float* m1_w1 = (const float*)d_in[8];
    const float* m1_b1 = (const float*)d_in[9];
    const float* m1_w2 = (const float*)d_in[10];
    const float* m1_b2 = (const float*)d_in[11];
    const float* m0_w0 = (const float*)d_in[12];
    const float* m0_b0 = (const float*)d_in[13];
    const float* m0_w1 = (const float*)d_in[14];
    const float* m0_b1 = (const float*)d_in[15];
    const float* m0_w2 = (const float*)d_in[16];
    const float* m0_b2 = (const float*)d_in[17];
    float* out = (float*)d_out;

    dim3 block(256);
    if (ws_size >= (size_t)WS_BYTES) {
        _Float16* wsp = (_Float16*)d_ws;
        hipLaunchKernelGGL(pack_weights, dim3((PACK_ITEMS+255)/256), block, 0, stream,
            m1_w0, m1_w1, m1_w2, m0_w0, m0_w1, m0_w2, p0_w0, p0_w1,
            m1_b0, m1_b1, m1_b2, m0_b0, m0_b1, m0_b2, p0_b0, wsp);
        hipLaunchKernelGGL(nsf_mfma, dim3(N_PTS/256), block, 0, stream,
            wi, cond, wsp, p0_b1, out);
    } else {
        hipLaunchKernelGGL(nsf_kernel_f32, dim3(N_PTS/256), block, 0, stream,
            wi, cond, p0_w0, p0_b0, p0_w1, p0_b1,
            m1_w0, m1_b0, m1_w1, m1_b1, m1_w2, m1_b2,
            m0_w0, m0_b0, m0_w1, m0_b1, m0_w2, m0_b2, out);
    }
}